// Round 12
// baseline (550.061 us; speedup 1.0000x reference)
//
#include <hip/hip_runtime.h>
#include <hip/hip_bf16.h>
#include <stdint.h>

#define B_  32
#define E_  512
#define WN  2048
#define D_  1024

typedef __attribute__((ext_vector_type(8))) short short8;
typedef __attribute__((ext_vector_type(4))) float f32x4;

__device__ int g_mask_is_int;   // 1 if mask buffer is int32 per element, 0 if uint8

__device__ __forceinline__ unsigned short f2bf(float f) {
  unsigned int u = __float_as_uint(f);
  u += 0x7fffu + ((u >> 16) & 1u);   // round-to-nearest-even
  return (unsigned short)(u >> 16);
}
__device__ __forceinline__ float bf2f(unsigned short s) {
  return __uint_as_float(((unsigned int)s) << 16);
}
__device__ __forceinline__ float ftanh(float x) {
  float e = __expf(2.0f * x);
  return 1.0f - 2.0f / (e + 1.0f);
}
// XOR-swizzled byte offset within a [rows][128B] LDS plane
__device__ __forceinline__ int swz(int row, int kb) {
  return row * 128 + (kb ^ ((row & 7) << 4));
}
// 64B-row swizzle: F(X) = X ^ ((X>>6 & 7) << 4)
__device__ __forceinline__ int swz64x(int row, int kb) {
  const int X = row * 64 + kb;
  return X ^ (((X >> 6) & 7) << 4);
}
__device__ __forceinline__ uint4 pack8(unsigned short a0, unsigned short a1,
                                       unsigned short a2, unsigned short a3,
                                       unsigned short a4, unsigned short a5,
                                       unsigned short a6, unsigned short a7) {
  uint4 v;
  v.x = (unsigned int)a0 | ((unsigned int)a1 << 16);
  v.y = (unsigned int)a2 | ((unsigned int)a3 << 16);
  v.z = (unsigned int)a4 | ((unsigned int)a5 << 16);
  v.w = (unsigned int)a6 | ((unsigned int)a7 << 16);
  return v;
}
// async global->LDS, 16B per lane; LDS dst is wave-uniform base (+lane*16 HW)
__device__ __forceinline__ void gload_lds16(const void* g, void* l) {
  __builtin_amdgcn_global_load_lds(
      (const __attribute__((address_space(1))) unsigned int*)g,
      (__attribute__((address_space(3))) unsigned int*)l, 16, 0, 0);
}

// ---------------------------------------------------------------------------
// K0: detect mask dtype. int32 0/1 data => bytes at offset %4 != 0 are all 0.
// ---------------------------------------------------------------------------
__global__ void k_detect(const unsigned char* __restrict__ m) {
  if (threadIdx.x == 0) {
    int nz = 0;
    for (int i = 0; i < 1024; ++i)
      if ((i & 3) && m[i]) nz++;
    g_mask_is_int = (nz == 0) ? 1 : 0;
  }
}

// ===========================================================================
// FAST PATH
// ===========================================================================

// ---------------------------------------------------------------------------
// k_split: src f32 -> hi/lo bf16 blobs in proj's swizzled LDS-image layout.
// (unchanged, verified round 11)
// ---------------------------------------------------------------------------
__global__ __launch_bounds__(256) void k_split(const float* __restrict__ src,
                                               unsigned short* __restrict__ hi,
                                               unsigned short* __restrict__ lo) {
#pragma unroll
  for (int j = 0; j < 4; ++j) {
    const size_t Lg = ((size_t)blockIdx.x * 1024 + j * 256 + threadIdx.x) * 16;
    const int Lloc = (int)(Lg & 16383);
    const int TS = (int)(Lg >> 14);
    const int T = TS >> 4, s = TS & 15;
    const int row = Lloc >> 7;
    const int kb = (Lloc & 127) ^ ((row & 7) << 4);
    const int kk = kb >> 1;
    const float* sp = src + ((size_t)(T * 128 + row)) * 1024 + s * 64 + kk;
    const f32x4 v0 = *(const f32x4*)(sp);
    const f32x4 v1 = *(const f32x4*)(sp + 4);
    unsigned short h[8], l[8];
#pragma unroll
    for (int i = 0; i < 4; ++i) {
      unsigned short hh = f2bf(v0[i]);
      h[i] = hh;
      l[i] = f2bf(v0[i] - bf2f(hh));
      unsigned short h2 = f2bf(v1[i]);
      h[4 + i] = h2;
      l[4 + i] = f2bf(v1[i] - bf2f(h2));
    }
    *(uint4*)((char*)hi + Lg) = pack8(h[0], h[1], h[2], h[3], h[4], h[5], h[6], h[7]);
    *(uint4*)((char*)lo + Lg) = pack8(l[0], l[1], l[2], l[3], l[4], l[5], l[6], l[7]);
  }
}

// ---------------------------------------------------------------------------
// k_proj_dma: proj = tanh(ems @ W^T + bias), pure-DMA dbuf (verified r11).
// ---------------------------------------------------------------------------
__global__ __launch_bounds__(512) void k_proj_dma(
    const unsigned short* __restrict__ eHi, const unsigned short* __restrict__ eLo,
    const unsigned short* __restrict__ wHi, const unsigned short* __restrict__ wLo,
    const float* __restrict__ bias,
    unsigned short* __restrict__ outHi, unsigned short* __restrict__ outLo) {
  __shared__ uint4 lds4[8192];   // 128KB
  char* pAhi_c = (char*)lds4;
  char* pAlo_c = (char*)lds4 + 16384;
  char* pBhi_c = (char*)lds4 + 32768;
  char* pBlo_c = (char*)lds4 + 49152;
  char* pAhi_n = (char*)lds4 + 65536;
  char* pAlo_n = (char*)lds4 + 81920;
  char* pBhi_n = (char*)lds4 + 98304;
  char* pBlo_n = (char*)lds4 + 114688;

  const int Tm = blockIdx.x >> 3;   // 0..127 m-tile
  const int Tn = blockIdx.x & 7;    // 0..7  n-tile
  const int t = threadIdx.x, l = t & 63, wv = t >> 6;
  const int wm2 = wv >> 1;   // 0..3 -> rows wm2*32
  const int wn2 = wv & 1;    // 0..1 -> cols wn2*64

  f32x4 acc[2][4];
#pragma unroll
  for (int i = 0; i < 2; ++i)
#pragma unroll
    for (int j = 0; j < 4; ++j) acc[i][j] = (f32x4){0.f, 0.f, 0.f, 0.f};

  auto dma_stage = [&](int s, char* pAh, char* pAl, char* pBh, char* pBl) {
#pragma unroll
    for (int j = 0; j < 2; ++j) {
      const size_t ga = (size_t)Tm * 262144 + (size_t)s * 16384 + j * 8192 +
                        wv * 1024 + l * 16;
      gload_lds16((const char*)eHi + ga, pAh + j * 8192 + wv * 1024);
      gload_lds16((const char*)eLo + ga, pAl + j * 8192 + wv * 1024);
      const size_t gb = (size_t)Tn * 262144 + (size_t)s * 16384 + j * 8192 +
                        wv * 1024 + l * 16;
      gload_lds16((const char*)wHi + gb, pBh + j * 8192 + wv * 1024);
      gload_lds16((const char*)wLo + gb, pBl + j * 8192 + wv * 1024);
    }
  };

  auto compute_stage = [&](const char* pAh, const char* pAl,
                           const char* pBh, const char* pBl) {
#pragma unroll
    for (int ks = 0; ks < 2; ++ks) {
      const int kb = ks * 64 + (l >> 4) * 16;
      short8 ah[2], al[2], bh[4], bl[4];
#pragma unroll
      for (int f = 0; f < 2; ++f) {
        const int o = swz(wm2 * 32 + f * 16 + (l & 15), kb);
        ah[f] = *(const short8*)(pAh + o);
        al[f] = *(const short8*)(pAl + o);
      }
#pragma unroll
      for (int f = 0; f < 4; ++f) {
        const int o = swz(wn2 * 64 + f * 16 + (l & 15), kb);
        bh[f] = *(const short8*)(pBh + o);
        bl[f] = *(const short8*)(pBl + o);
      }
#pragma unroll
      for (int fm = 0; fm < 2; ++fm)
#pragma unroll
        for (int fn = 0; fn < 4; ++fn) {
          acc[fm][fn] = __builtin_amdgcn_mfma_f32_16x16x32_bf16(ah[fm], bh[fn], acc[fm][fn], 0, 0, 0);
          acc[fm][fn] = __builtin_amdgcn_mfma_f32_16x16x32_bf16(al[fm], bh[fn], acc[fm][fn], 0, 0, 0);
          acc[fm][fn] = __builtin_amdgcn_mfma_f32_16x16x32_bf16(ah[fm], bl[fn], acc[fm][fn], 0, 0, 0);
        }
    }
  };

  dma_stage(0, pAhi_c, pAlo_c, pBhi_c, pBlo_c);
  __syncthreads();
  for (int s = 0; s < 16; ++s) {
    if (s < 15) dma_stage(s + 1, pAhi_n, pAlo_n, pBhi_n, pBlo_n);
    compute_stage(pAhi_c, pAlo_c, pBhi_c, pBlo_c);
    __syncthreads();
    char* x;
    x = pAhi_c; pAhi_c = pAhi_n; pAhi_n = x;
    x = pAlo_c; pAlo_c = pAlo_n; pAlo_n = x;
    x = pBhi_c; pBhi_c = pBhi_n; pBhi_n = x;
    x = pBlo_c; pBlo_c = pBlo_n; pBlo_n = x;
  }

  float bcol[4];
#pragma unroll
  for (int fn = 0; fn < 4; ++fn)
    bcol[fn] = bias[Tn * 128 + wn2 * 64 + fn * 16 + (l & 15)];
#pragma unroll
  for (int fm = 0; fm < 2; ++fm)
#pragma unroll
    for (int fn = 0; fn < 4; ++fn)
#pragma unroll
      for (int q = 0; q < 4; ++q)
        acc[fm][fn][q] = ftanh(acc[fm][fn][q] + bcol[fn]);

  unsigned short* ldsT = (unsigned short*)lds4;  // [128][136]
  __syncthreads();
#pragma unroll
  for (int fm = 0; fm < 2; ++fm)
#pragma unroll
    for (int fn = 0; fn < 4; ++fn)
#pragma unroll
      for (int q = 0; q < 4; ++q) {
        const int rl = wm2 * 32 + fm * 16 + (l >> 4) * 4 + q;
        const int cl = wn2 * 64 + fn * 16 + (l & 15);
        ldsT[rl * 136 + cl] = f2bf(acc[fm][fn][q]);
      }
  __syncthreads();
#pragma unroll
  for (int sb = 0; sb < 4; ++sb) {
    const int L = t * 16;
    const int x6 = ((L >> 6) ^ (L >> 8)) & 1;
    const int x5 = ((L >> 5) ^ (L >> 7)) & 1;
    const int x4 = ((L >> 4) ^ (L >> 6) ^ (L >> 8)) & 1;
    const int X = (L & ~0x70) | (x6 << 6) | (x5 << 5) | (x4 << 4);
    const int row = X >> 6;
    const int cl = sb * 32 + ((X & 63) >> 1);
    uint4 v = *(const uint4*)(ldsT + row * 136 + cl);
    *(uint4*)((char*)outHi + (size_t)Tm * 262144 +
              (size_t)(Tn * 4 + sb) * 8192 + L) = v;
  }
  __syncthreads();
#pragma unroll
  for (int fm = 0; fm < 2; ++fm)
#pragma unroll
    for (int fn = 0; fn < 4; ++fn)
#pragma unroll
      for (int q = 0; q < 4; ++q) {
        const int rl = wm2 * 32 + fm * 16 + (l >> 4) * 4 + q;
        const int cl = wn2 * 64 + fn * 16 + (l & 15);
        const float x = acc[fm][fn][q];
        const unsigned short hh2 = f2bf(x);
        ldsT[rl * 136 + cl] = f2bf(x - bf2f(hh2));
      }
  __syncthreads();
#pragma unroll
  for (int sb = 0; sb < 4; ++sb) {
    const int L = t * 16;
    const int x6 = ((L >> 6) ^ (L >> 8)) & 1;
    const int x5 = ((L >> 5) ^ (L >> 7)) & 1;
    const int x4 = ((L >> 4) ^ (L >> 6) ^ (L >> 8)) & 1;
    const int X = (L & ~0x70) | (x6 << 6) | (x5 << 5) | (x4 << 4);
    const int row = X >> 6;
    const int cl = sb * 32 + ((X & 63) >> 1);
    uint4 v = *(const uint4*)(ldsT + row * 136 + cl);
    *(uint4*)((char*)outLo + (size_t)Tm * 262144 +
              (size_t)(Tn * 4 + sb) * 8192 + L) = v;
  }
}

// ---------------------------------------------------------------------------
// k_scores_mfma v4: 256x256 tile, BK=32, 8 waves (2m x 4n).
// A: 3-deep DMA pipeline (counted vmcnt(4), raw barriers); B: reg-staged
// dbuf. LDS = 3*32K (A) + 2*32K (B) = 160KB. Traffic: A x8 + B x2 = 1.0GB
// (was 1.28). XCD-pinned by b.
// ---------------------------------------------------------------------------
__global__ __launch_bounds__(512) void k_scores_mfma(
    const unsigned short* __restrict__ pHi, const unsigned short* __restrict__ pLo,
    const float* __restrict__ words, float* __restrict__ sc) {
  __shared__ uint4 lds4[10240];  // 160KB
  // A buffers: hi at +0, lo at +16384 within each 32KB buf
  char* A0 = (char*)lds4;
  char* A1 = (char*)lds4 + 32768;
  char* A2 = (char*)lds4 + 65536;
  // B buffers: hi at +0, lo at +16384 within each 32KB buf
  char* Bc = (char*)lds4 + 98304;
  char* Bn = (char*)lds4 + 131072;

  const int g = blockIdx.x;
  const int b = (g & 7) + 8 * (g >> 7);   // XCD-pinned batch (bijective)
  const int tile = (g >> 3) & 15;
  const int n0 = (tile & 7) * 256;
  const int m0 = (tile >> 3) * 256;       // 0 or 256

  const int t = threadIdx.x, l = t & 63, wv = t >> 6;
  const int wm2 = wv >> 2;    // 0..1 -> row base wm2*128
  const int wn4 = wv & 3;     // 0..3 -> col base wn4*64
  const int Tbase = b * 4 + (m0 >> 7);    // first 128-row blob tile

  f32x4 acc[8][4];
#pragma unroll
  for (int i = 0; i < 8; ++i)
#pragma unroll
    for (int j = 0; j < 4; ++j) acc[i][j] = (f32x4){0.f, 0.f, 0.f, 0.f};

  f32x4 br[4];
  const int bn = t >> 1;          // B n-row 0..255
  const int bh16 = (t & 1) * 16;  // f32 col base (0 or 16) within 32

  auto load_B = [&](int s) {
    const float* bs = words + (size_t)b * WN * D_ + (size_t)(n0 + bn) * 1024 +
                      s * 32 + bh16;
#pragma unroll
    for (int i = 0; i < 4; ++i) br[i] = *(const f32x4*)(bs + i * 4);
  };

  auto dma_A = [&](int s, char* pA) {
#pragma unroll
    for (int j = 0; j < 2; ++j) {
      const size_t gb = (size_t)(Tbase + j) * 262144 + (size_t)s * 8192 +
                        wv * 1024 + l * 16;
      gload_lds16((const char*)pHi + gb, pA + j * 8192 + wv * 1024);
      gload_lds16((const char*)pLo + gb, pA + 16384 + j * 8192 + wv * 1024);
    }
  };

  auto write_B = [&](char* pB) {
    unsigned short hB[16], lB[16];
#pragma unroll
    for (int i = 0; i < 4; ++i)
#pragma unroll
      for (int j = 0; j < 4; ++j) {
        const float y = br[i][j];
        const unsigned short hh = f2bf(y);
        hB[i * 4 + j] = hh;
        lB[i * 4 + j] = f2bf(y - bf2f(hh));
      }
    const int o0 = swz64x(bn, bh16 * 2);
    const int o1 = swz64x(bn, bh16 * 2 + 16);
    *(uint4*)(pB + o0) = pack8(hB[0], hB[1], hB[2], hB[3], hB[4], hB[5], hB[6], hB[7]);
    *(uint4*)(pB + o1) = pack8(hB[8], hB[9], hB[10], hB[11], hB[12], hB[13], hB[14], hB[15]);
    *(uint4*)(pB + 16384 + o0) = pack8(lB[0], lB[1], lB[2], lB[3], lB[4], lB[5], lB[6], lB[7]);
    *(uint4*)(pB + 16384 + o1) = pack8(lB[8], lB[9], lB[10], lB[11], lB[12], lB[13], lB[14], lB[15]);
  };

  auto compute_stage = [&](const char* pA, const char* pB) {
    const int kb0 = (l >> 4) * 16;
    short8 bh[4], bl[4];
#pragma unroll
    for (int f = 0; f < 4; ++f) {
      const int n = wn4 * 64 + f * 16 + (l & 15);
      const int o = swz64x(n, kb0);
      bh[f] = *(const short8*)(pB + o);
      bl[f] = *(const short8*)(pB + 16384 + o);
    }
#pragma unroll
    for (int fm = 0; fm < 8; ++fm) {
      const int r = wm2 * 128 + fm * 16 + (l & 15);
      const int oa = (r >> 7) * 8192 + swz64x(r & 127, kb0);
      const short8 ah = *(const short8*)(pA + oa);
      const short8 al = *(const short8*)(pA + 16384 + oa);
#pragma unroll
      for (int fn = 0; fn < 4; ++fn) {
        acc[fm][fn] = __builtin_amdgcn_mfma_f32_16x16x32_bf16(ah, bh[fn], acc[fm][fn], 0, 0, 0);
        acc[fm][fn] = __builtin_amdgcn_mfma_f32_16x16x32_bf16(al, bh[fn], acc[fm][fn], 0, 0, 0);
        acc[fm][fn] = __builtin_amdgcn_mfma_f32_16x16x32_bf16(ah, bl[fn], acc[fm][fn], 0, 0, 0);
      }
    }
  };

  // prologue: loadB(0) first (so its consumer wait leaves DMAs in flight)
  load_B(0);
  dma_A(0, A0);
  dma_A(1, A1);
  write_B(Bc);
  asm volatile("s_waitcnt vmcnt(4) lgkmcnt(0)" ::: "memory");  // dma(0) done
  __builtin_amdgcn_sched_barrier(0);
  __builtin_amdgcn_s_barrier();
  __builtin_amdgcn_sched_barrier(0);

  for (int s = 0; s < 32; ++s) {
    if (s < 31) load_B(s + 1);
    __builtin_amdgcn_sched_barrier(0);
    if (s < 30) dma_A(s + 2, A2);
    __builtin_amdgcn_sched_barrier(0);
    compute_stage(A0, Bc);
    if (s < 31) write_B(Bn);
    if (s < 30) {
      // write_B's implicit wait already retired dma(s+1) (older than load_B);
      // assert <=4 outstanding (= dma(s+2)) and drain LDS writes.
      asm volatile("s_waitcnt vmcnt(4) lgkmcnt(0)" ::: "memory");
    } else {
      asm volatile("s_waitcnt vmcnt(0) lgkmcnt(0)" ::: "memory");
    }
    __builtin_amdgcn_sched_barrier(0);
    __builtin_amdgcn_s_barrier();
    __builtin_amdgcn_sched_barrier(0);
    char* x = A0; A0 = A1; A1 = A2; A2 = x;
    x = Bc; Bc = Bn; Bn = x;
  }

  // store f32 scores
#pragma unroll
  for (int fm = 0; fm < 8; ++fm)
#pragma unroll
    for (int fn = 0; fn < 4; ++fn)
#pragma unroll
      for (int q = 0; q < 4; ++q) {
        const int row = m0 + wm2 * 128 + fm * 16 + (l >> 4) * 4 + q;
        const int col = n0 + wn4 * 64 + fn * 16 + (l & 15);
        sc[((size_t)b * 512 + row) * 2048 + col] = acc[fm][fn][q];
      }
}

// ---------------------------------------------------------------------------
// k_softmax: unchanged (verified round 9/10).
// ---------------------------------------------------------------------------
__global__ __launch_bounds__(256) void k_softmax(const float* __restrict__ ws,
                                                 const void* __restrict__ mask,
                                                 unsigned short* __restrict__ blob) {
  __shared__ float red[8];
  const int row = blockIdx.x;
  const int t = threadIdx.x;
  const int wave = t >> 6;
  const float* rp = ws + (size_t)row * 2048;
  float v[8];
  {
    f32x4 v0 = *(const f32x4*)(rp + t * 8);
    f32x4 v1 = *(const f32x4*)(rp + t * 8 + 4);
#pragma unroll
    for (int i = 0; i < 4; ++i) { v[i] = v0[i]; v[4 + i] = v1[i]; }
  }
  if (g_mask_is_int) {
    const int* mp = (const int*)mask + (size_t)row * 2048 + t * 8;
    const int4 m0 = *(const int4*)mp;
    const int4 m1 = *(const int4*)(mp + 4);
    if (m0.x) v[0] = -INFINITY;
    if (m0.y) v[1] = -INFINITY;
    if (m0.z) v[2] = -INFINITY;
    if (m0.w) v[3] = -INFINITY;
    if (m1.x) v[4] = -INFINITY;
    if (m1.y) v[5] = -INFINITY;
    if (m1.z) v[6] = -INFINITY;
    if (m1.w) v[7] = -INFINITY;
  } else {
    const unsigned char* mp = (const unsigned char*)mask + (size_t)row * 2048 + t * 8;
    const uchar4 m0 = *(const uchar4*)mp;
    const uchar4 m1 = *(const uchar4*)(mp + 4);
    if (m0.x) v[0] = -INFINITY;
    if (m0.y) v[1] = -INFINITY;
    if (m0.z) v[2] = -INFINITY;
    if (m0.w) v[3] = -INFINITY;
    if (m1.x) v[4] = -INFINITY;
    if (m1.y) v[5] = -INFINITY;
    if (m1.z) v[6] = -INFINITY;
    if (m1.w) v[7] = -INFINITY;
  }
  float mx = v[0];
#pragma unroll
  for (int i = 1; i < 8; ++i) mx = fmaxf(mx, v[i]);
#pragma unroll
  for (int off = 32; off > 0; off >>= 1) mx = fmaxf(mx, __shfl_xor(mx, off));
  if ((t & 63) == 0) red[wave] = mx;
  __syncthreads();
  mx = fmaxf(fmaxf(red[0], red[1]), fmaxf(red[2], red[3]));
  float e[8];
  float sum = 0.0f;
#pragma unroll
  for (int i = 0; i < 8; ++i) {
    e[i] = __expf(v[i] - mx);
    sum += e[i];
  }
#pragma unroll
  for (int off = 32; off > 0; off >>= 1) sum += __shfl_xor(sum, off);
  if ((t & 63) == 0) red[4 + wave] = sum;
  __syncthreads();
  const float tot = (red[4] + red[5]) + (red[6] + red[7]);
  const float rinv = 1.0f / tot;

  const int b = row >> 9, ee = row & 511;
  const uint4 pk = pack8(f2bf(e[0] * rinv), f2bf(e[1] * rinv),
                         f2bf(e[2] * rinv), f2bf(e[3] * rinv),
                         f2bf(e[4] * rinv), f2bf(e[5] * rinv),
                         f2bf(e[6] * rinv), f2bf(e[7] * rinv));
  char* dst = (char*)blob + (size_t)b * 2097152 + (size_t)(t >> 3) * 65536 +
              ee * 128 + (((t & 7) * 16) ^ ((ee & 7) << 4));
  *(uint4*)dst = pk;
}

// ---------------------------------------------------------------------------
// k_pv: ctx = att @ words (unchanged, verified round 9).
// ---------------------------------------------------------------------------
__global__ __launch_bounds__(512) void k_pv(
    const unsigned short* __restrict__ blob, const float* __restrict__ words,
    float* __restrict__ ctx) {
  __shared__ uint4 lds4[10240];           // 160KB
  char* pAc = (char*)lds4;
  char* pAn = (char*)lds4 + 65536;
  char* pBc = (char*)lds4 + 131072;
  char* pBn = (char*)lds4 + 147456;

  const int g = blockIdx.x;
  const int b = (g & 7) + 8 * (g >> 6);   // XCD-pinned batch
  const int wt = (g >> 3) & 7;
  const int w0 = wt * 128;

  const int t = threadIdx.x, l = t & 63, wv = t >> 6;
  const int wm4 = wv >> 1;
  const int wn2 = wv & 1;

  const char* blobB = (const char*)blob + (size_t)b * 2097152;

  f32x4 acc[8][4];
#pragma unroll
  for (int i = 0; i < 8; ++i)
#pragma unroll
    for (int j = 0; j < 4; ++j) acc[i][j] = (f32x4){0.f, 0.f, 0.f, 0.f};

  f32x4 bv0a, bv0b, bv1a, bv1b;
  const int np2 = (t & 31) * 2;
  const int wc = (t >> 5) * 8;

  auto dma_A = [&](int s, char* pA) {
    const char* gp = blobB + (size_t)s * 65536 + wv * 8192 + l * 16;
#pragma unroll
    for (int j = 0; j < 8; ++j)
      gload_lds16(gp + j * 1024, pA + wv * 8192 + j * 1024);
  };

  auto load_B = [&](int s) {
    const float* wp = words + (size_t)b * WN * D_ +
                      (size_t)(s * 64 + np2) * 1024 + w0 + wc;
    bv0a = *(const f32x4*)(wp);
    bv0b = *(const f32x4*)(wp + 4);
    bv1a = *(const f32x4*)(wp + 1024);
    bv1b = *(const f32x4*)(wp + 1028);
  };

  auto write_B = [&](char* pB) {
#pragma unroll
    for (int i = 0; i < 8; ++i) {
      const int w = wc + i;
      const float x0 = (i < 4) ? bv0a[i & 3] : bv0b[i & 3];
      const float x1 = (i < 4) ? bv1a[i & 3] : bv1b[i & 3];
      const unsigned int pk =
          (unsigned int)f2bf(x0) | ((unsigned int)f2bf(x1) << 16);
      *(unsigned int*)(pB + w * 128 + ((np2 * 2) ^ ((w & 7) << 4))) = pk;
    }
  };

  auto compute_stage = [&](const char* pA, const char* pB) {
#pragma unroll
    for (int ks = 0; ks < 2; ++ks) {
      short8 a[8];
      const int kb = ks * 64 + (l >> 4) * 16;
#pragma unroll
      for (int f = 0; f < 8; ++f) {
        const int row = wm4 * 128 + f * 16 + (l & 15);
        a[f] = *(const short8*)(pA + swz(row, kb));
      }
      short8 bb[4];
#pragma unroll
      for (int f = 0; f < 4; ++f) {
        const int row = wn2 * 64 + f * 16 + (l & 15);
        bb[f] = *(const short8*)(pB + swz(row, kb));
      }
#pragma unroll
      for (int fm = 0; fm < 8; ++fm)
#pragma unroll
        for (int fn = 0; fn < 4; ++fn)
          acc[fm][fn] = __builtin_amdgcn_mfma_f32_16x16x32_bf16(a[fm], bb[fn], acc[fm][fn], 0, 0, 0);
    }
  };

  load_B(0);
  dma_A(0, pAc);
  write_B(pBc);
  __syncthreads();

  for (int s = 0; s < 32; ++s) {
    if (s < 31) {
      load_B(s + 1);
      dma_A(s + 1, pAn);
    }
    compute_stage(pAc, pBc);
    if (s < 31) write_B(pBn);
    __syncthreads();
    char* t1 = pAc; pAc = pAn; pAn = t1;
    char* t2 = pBc; pBc = pBn; pBn = t2;
  }

#pragma unroll
  for (int fm = 0; fm < 8; ++fm)
#pragma unroll
    for (int fn = 0; fn < 4; ++fn)
#pragma unroll
      for (int q = 0; q < 4; ++q) {
        const int row = wm4 * 128 + fm * 16 + (l >> 4) * 4 + q;
        const int col = w0 + wn2 * 64 + fn * 16 + (l & 15);
        ctx[((size_t)b * 512 + row) * 1024 + col] = acc[fm][fn][q];
      }
}

// ---------------------------------------------------------------------------
// k_copy: ctx (ws) -> d_out, float4 grid-stride.
// ---------------------------------------------------------------------------
__global__ __launch_bounds__(256) void k_copy(const float4* __restrict__ src,
                                              float4* __restrict__ dst) {
  const int n4 = 16384 * 1024 / 4;
  int i = blockIdx.x * 256 + threadIdx.x;
  const int stride = gridDim.x * 256;
  for (; i < n4; i += stride) dst[i] = src[i];
}

// ===========================================================================
// FALLBACK PATH (round-2 verified kernels; used if ws too small)
// ===========================================================================
__global__ __launch_bounds__(256, 4) void k_proj(const float* __restrict__ A,
                                                 const float* __restrict__ W,
                                                 const float* __restrict__ bias,
                                                 float* __restrict__ out) {
  __shared__ float As[32][132];
  __shared__ float Bs[32][132];
  const int t = threadIdx.x;
  const int m0 = blockIdx.x * 128;
  const int n0 = blockIdx.y * 128;
  const int tm = t >> 4;
  const int tn = t & 15;
  const int lrow = t >> 1;
  const int lk = (t & 1) * 16;

  float acc[8][8];
#pragma unroll
  for (int i = 0; i < 8; ++i)
#pragma unroll
    for (int j = 0; j < 8; ++j) acc[i][j] = 0.0f;

  const float* Arow = A + (size_t)(m0 + lrow) * D_ + lk;
  const float* Wrow = W + (size_t)(n0 + lrow) * D_ + lk;

  for (int k0 = 0; k0 < D_; k0 += 32) {
    __syncthreads();
#pragma unroll
    for (int j = 0; j < 4; ++j) {
      const float4 va = *(const float4*)(Arow + k0 + j * 4);
      As[lk + j * 4 + 0][lrow] = va.x;
      As[lk + j * 4 + 1][lrow] = va.y;
      As[lk + j * 4 + 2][lrow] = va.z;
      As[lk + j * 4 + 3][lrow] = va.w;
      const float4 vb = *(const float4*)(Wrow + k0 + j * 4);
      Bs[lk + j * 4 + 0][lrow] = vb.x;
      Bs[lk + j * 4 + 1][lrow] = vb.y;
      Bs[lk + j * 4 + 2][lrow] = vb.z;
      Bs[lk + j * 4 + 3][lrow] = vb.w;
    }
    __syncthreads();
#pragma unroll 8
    for (int k = 0; k < 32; ++k) {
      float a[8], bb[8];
      *(float4*)(a + 0) = *(const float4*)&As[k][tm * 4];
      *(float4*)(a + 4) = *(const float4*)&As[k][tm * 4 + 64];
      *(float4*)(bb + 0) = *(const float4*)&Bs[k][tn * 4];
      *(float4*)(bb + 4) = *(const float4*)&Bs[k][tn * 4 + 64];
#pragma unroll
      for (int i = 0; i < 8; ++i)
#pragma unroll
        for (int j = 0; j < 8; ++j) acc[i][j] = fmaf(a[i], bb[j], acc[i][j]);
    }
  }

  float bn[8];
#pragma unroll
  for (int j = 0; j < 8; ++j) bn[j] = bias[n0 + tn * 4 + (j & 3) + (j >> 2) * 64];
#pragma unroll
  for (int i = 0; i < 8; ++i) {
    const int m = m0 + tm * 4 + (i & 3) + (i >> 2) * 64;
    float4 v0, v1;
    v0.x = tanhf(acc[i][0] + bn[0]);
    v0.y = tanhf(acc[i][1] + bn[1]);
    v0.z = tanhf(acc[i][2] + bn[2]);
    v0.w = tanhf(acc[i][3] + bn[3]);
    v1.x = tanhf(acc[i][4] + bn[4]);
    v1.y = tanhf(acc[i][5] + bn[5]);
    v1.z = tanhf(acc[i][6] + bn[6]);
    v1.w = tanhf(acc[i][7] + bn[7]);
    *(float4*)(out + (size_t)m * D_ + n0 + tn * 4) = v0;
    *(float4*)(out + (size_t)m * D_ + n0 + tn * 4 + 64) = v1;
  }
}

__global__ __launch_bounds__(256) void k_scores(const float* __restrict__ words,
                                                const void* __restrict__ mask,
                                                float* __restrict__ pa) {
  __shared__ float Pt[1024][18];
  __shared__ float Ws[64][268];
  const int t = threadIdx.x;
  const int b = blockIdx.x >> 5;
  const int et = blockIdx.x & 31;
  const int e0 = et * 16;
  const int eg = t >> 5;
  const int ng = t & 31;
  const int mask_is_int = g_mask_is_int;
  const float* wbase = words + (size_t)b * WN * D_;

  {
    const int row = t >> 4;
    const int dj = (t & 15) * 4;
    const float* pr = pa + (size_t)(b * E_ + e0 + row) * D_;
#pragma unroll
    for (int rr = 0; rr < 16; ++rr) {
      const float4 v = *(const float4*)(pr + dj + rr * 64);
      Pt[dj + rr * 64 + 0][row] = v.x;
      Pt[dj + rr * 64 + 1][row] = v.y;
      Pt[dj + rr * 64 + 2][row] = v.z;
      Pt[dj + rr * 64 + 3][row] = v.w;
    }
  }

  float s[2][64];
#pragma unroll
  for (int i = 0; i < 2; ++i)
#pragma unroll
    for (int u = 0; u < 64; ++u) s[i][u] = 0.0f;

  const int nl = t >> 3;
  const int d4 = (t & 7) * 4;

  for (int dk = 0; dk < D_; dk += 64) {
#pragma unroll
    for (int nb = 0; nb < 8; ++nb) {
      __syncthreads();
#pragma unroll
      for (int rr = 0; rr < 8; ++rr) {
#pragma unroll
        for (int hh = 0; hh < 2; ++hh) {
          const int n = nl + rr * 32;
          const int d = d4 + hh * 32;
          const float4 v = *(const float4*)(wbase + (size_t)(nb * 256 + n) * D_ + dk + d);
          Ws[d + 0][n] = v.x;
          Ws[d + 1][n] = v.y;
          Ws[d + 2][n] = v.z;
          Ws[d + 3][n] = v.w;
        }
      }
      __syncthreads();
#pragma unroll 2
      for (int k = 0; k < 64; ++k) {
        const float2 a = *(const float2*)&Pt[dk + k][eg * 2];
        const float4 b0 = *(const float4*)&Ws[k][ng * 4];
        const float4 b1 = *(const float4*)&Ws[k][128 + ng * 4];
        const float aa[2] = {a.x, a.y};
        const float bb[8] = {b0.x, b0.y, b0.z, b0.w, b1.x, b1.y, b1.z, b1.w};
#pragma unroll
        for (int i = 0; i < 2; ++i)
#pragma unroll
          for (int u = 0; u < 8; ++u)
            s[i][nb * 8 + u] = fmaf(aa[i], bb[u], s[i][nb * 8 + u]);
      }
    }
  }

#pragma unroll
  for (int i = 0; i < 2; ++i) {
    const int e = e0 + eg * 2 + i;
#pragma unroll
    for (int nb = 0; nb < 8; ++nb)
#pragma unroll
      for (int q = 0; q < 2; ++q) {
        const size_t moff = (size_t)(b * E_ + e) * WN + nb * 256 + q * 128 + ng * 4;
        int mx, my, mz, mw;
        if (mask_is_int) {
          const int4 mv = *(const int4*)((const int*)mask + moff);
          mx = mv.x; my = mv.y; mz = mv.z; mw = mv.w;
        } else {
          const uchar4 mv = *(const uchar4*)((const unsigned char*)mask + moff);
          mx = mv.x; my = mv.y; mz = mv.z; mw = mv.w;
        }
        if (mx) s[i][nb * 8 + q * 4 + 0] = -1e30f;
        if (my) s[i][nb * 8 + q * 4 + 1] = -1e30f;
        if (mz) s[i][nb * 8 + q * 4 + 2] = -1e30f;
        if (mw) s[i][nb * 8 + q * 4 + 3] = -1e30f;
      }
    float m = -1e30f;
#pragma unroll
    for (int u = 0; u < 64; ++u) m = fmaxf(m, s[i][u]);
#pragma unroll
    for (int off = 16; off > 0; off >>= 1) m = fmaxf(m, __shfl_xor(m, off));
    float sum = 0.0f;
#pragma unroll
    for (int u = 0; u < 64; ++u) {
      const float p = __expf(s[i][u] - m);
      s[i][u] = p;
      sum += p;
    }
#pragma unroll
    for (int off = 16; off > 0; off >>= 1) sum += __shfl_xor(sum, off);
    const float rinv = 1.0f / sum;

    unsigned short* ar2 = (unsigned short*)(pa + (size_t)(b * E_ + e) * WN / 2);
#pragma unroll
    for (int nb = 0; nb < 8; ++nb)
#pragma unroll
      for (int q = 0; q < 2; ++q) {
        ushort4 pk;
        pk.x = f2bf(s[i][nb * 8 + q * 4 + 0] * rinv);
        pk.y = f2bf(s[i][nb * 8 + q * 4 + 1] * rinv);
        pk.z = f2bf(s[i][nb * 8 + q * 4 + 2] * rinv);
        pk.w = f2bf(s[i][nb * 8 + q * 4 + 3] * rinv);
        *(ushort4*)(ar2 + nb * 256 + q * 128 + ng * 4) = pk;
      }
  }
}

__global__ __launch_bounds__(256) void k_ctx(const float* __restrict__ words,
                                             float* __restrict__ pa) {
  __shared__ unsigned short att_s[16][2048];
  __shared__ unsigned short Wb[256][132];
  const int t = threadIdx.x;
  const int b = blockIdx.x >> 5;
  const int et = blockIdx.x & 31;
  const int e0 = et * 16;
  const int eg = t >> 5;
  const int wg = t & 31;
  const float* wbase = words + (size_t)b * WN * D_;

  {
    const int row = t >> 4;
    const int cj = t & 15;
    const uint4* pr = (const uint4*)(pa + (size_t)(b * E_ + e0 + row) * D_);
#pragma unroll
    for (int rr = 0; rr < 16; ++rr) {
      const int c = cj + rr * 16;
      const uint4 v = pr[c];
      *(uint4*)&att_s[row][c * 8] = v;
    }
  }

  float acc[2][32];
#pragma unroll
  for (int i = 0; i < 2; ++i)
#pragma unroll
    for (int u = 0; u < 32; ++u) acc[i][u] = 0.0f;

  const int nlg = t >> 5;
  const int w4 = (t & 31) * 4;

  for (int nb = 0; nb < 8; ++nb) {
#pragma unroll
    for (int q = 0; q < 8; ++q) {
      __syncthreads();
#pragma unroll
      for (int rr = 0; rr < 32; ++rr) {
        const int n = nlg + rr * 8;
        const float4 v = *(const float4*)(wbase + (size_t)(nb * 256 + n) * D_ + q * 128 + w4);
        ushort4 pk;
        pk.x = f2bf(v.x);
        pk.y = f2bf(v.y);
        pk.z = f2bf(v.z);
        pk.w = f2bf(v.w);
        *(ushort4*)&Wb[n][w4] = pk;
      }
      __syncthreads();
#pragma unroll 4
      for (int n2 = 0; n2 < 128; ++n2) {
        const int n = n2 * 2;
        const ushort4 r0 = *(const ushort4*)&Wb[n][wg * 4];
        const ushort4 r1 = *(const ushort4*)&Wb[n + 1][wg * 4];
        const float w0[4] = {bf2f(r0.x), bf2f(r0.y), bf2f(r0.z), bf2f(r0.w)};
        const float w1[4] = {bf2f(r1.x), bf2f(r1.y), bf2f(r1.z), bf2f(r1.w)};
#pragma unroll
        for (int i = 0; i < 2; ++i) {
          const unsigned int aw = *(const unsigned int*)&att_s[eg * 2 + i][nb * 256 + n];
          const float a0 = bf2f((unsigned short)(aw & 0xffffu));
          const float a1 = bf2f((unsigned short)(aw >> 16));
#pragma unroll
          for (int j = 0; j < 4; ++j)
            acc[i][q * 4 + j] = fmaf(a0, w0[j], fmaf(a1, w1[j], acc[i][q * 4 + j]));
        }
      }
    }
  }

#pragma unroll
  for (int i = 0; i < 2; ++i) {
    float* orow = pa + (size_t)(b * E_ + e0 + eg * 2 + i) * D_;
#pragma unroll
    for (int q = 0; q < 8; ++q) {
      float4 v;
      v.x = acc[i][q * 4 + 0];
      v.y = acc[i][q * 4 + 1];
      v.z = acc[i][q * 4 + 2];
      v.w = acc[i][q * 4 + 3];
      *(float4*)(orow + q * 128 + wg * 4) = v;
    }
  }
}

extern "C" void kernel_launch(void* const* d_in, const int* in_sizes, int n_in,
                              void* d_out, int out_size, void* d_ws, size_t ws_size,
                              hipStream_t stream) {
  const float* ems = (const float*)d_in[0];
  const float* words = (const float*)d_in[1];
  const void* mask = d_in[2];
  const float* w_weight = (const float*)d_in[3];
  const float* w_bias = (const float*)d_in[4];

  k_detect<<<1, 64, 0, stream>>>((const unsigned char*)mask);

  const size_t ws_need = (size_t)16384 * 2048 * 4;
  if (ws_size >= ws_need) {
    unsigned short* hiP = (unsigned short*)d_out;
    unsigned short* loP = hiP + (size_t)16384 * 1024;
    float* ws = (float*)d_ws;
    unsigned short* eHi = (unsigned short*)d_ws;                    // 32MB
    unsigned short* eLo = eHi + (size_t)16384 * 1024;               // 32MB
    unsigned short* wHi = eLo + (size_t)16384 * 1024;               // 2MB
    unsigned short* wLo = wHi + (size_t)1024 * 1024;                // 2MB
    // 0. pre-split ems (128 tiles) and W (8 tiles) into swizzled blobs
    k_split<<<dim3(2048), 256, 0, stream>>>(ems, eHi, eLo);
    k_split<<<dim3(128), 256, 0, stream>>>(w_weight, wHi, wLo);
    // 1. proj (pure-DMA dbuf) -> proj planes (32k-stage blob) in d_out
    k_proj_dma<<<dim3(1024), 512, 0, stream>>>(eHi, eLo, wHi, wLo, w_bias,
                                               hiP, loP);
    // 2. scores (f32) -> ws (256x256 tile, 3-deep counted-vmcnt pipeline)
    k_scores_mfma<<<dim3(512), 512, 0, stream>>>(hiP, loP, words, ws);
    // 3. softmax: ws scores -> att blob in d_out (planes dead)
    k_softmax<<<dim3(16384), 256, 0, stream>>>(ws, mask, (unsigned short*)d_out);
    // 4. pv: att blob (d_out) @ words -> ctx in ws (scores dead)
    k_pv<<<dim3(256), 512, 0, stream>>>((const unsigned short*)d_out, words, ws);
    // 5. ctx ws -> d_out
    k_copy<<<dim3(2048), 256, 0, stream>>>((const float4*)d_ws, (float4*)d_out);
  } else {
    float* out = (float*)d_out;
    k_proj<<<dim3(128, 8), 256, 0, stream>>>(ems, w_weight, w_bias, out);
    k_scores<<<dim3(B_ * (E_ / 16)), 256, 0, stream>>>(words, mask, out);
    k_ctx<<<dim3(B_ * (E_ / 16)), 256, 0, stream>>>(words, out);
  }
}

// Round 13
// 493.185 us; speedup vs baseline: 1.1153x; 1.1153x over previous
//
#include <hip/hip_runtime.h>
#include <hip/hip_bf16.h>
#include <stdint.h>

#define B_  32
#define E_  512
#define WN  2048
#define D_  1024

typedef __attribute__((ext_vector_type(8))) short short8;
typedef __attribute__((ext_vector_type(4))) float f32x4;

__device__ int g_mask_is_int;   // 1 if mask buffer is int32 per element, 0 if uint8

__device__ __forceinline__ unsigned short f2bf(float f) {
  unsigned int u = __float_as_uint(f);
  u += 0x7fffu + ((u >> 16) & 1u);   // round-to-nearest-even
  return (unsigned short)(u >> 16);
}
__device__ __forceinline__ float bf2f(unsigned short s) {
  return __uint_as_float(((unsigned int)s) << 16);
}
__device__ __forceinline__ float ftanh(float x) {
  float e = __expf(2.0f * x);
  return 1.0f - 2.0f / (e + 1.0f);
}
// XOR-swizzled byte offset within a [rows][128B] LDS plane
__device__ __forceinline__ int swz(int row, int kb) {
  return row * 128 + (kb ^ ((row & 7) << 4));
}
// 64B-row swizzle: F(X) = X ^ ((X>>6 & 7) << 4)
__device__ __forceinline__ int swz64x(int row, int kb) {
  const int X = row * 64 + kb;
  return X ^ (((X >> 6) & 7) << 4);
}
__device__ __forceinline__ uint4 pack8(unsigned short a0, unsigned short a1,
                                       unsigned short a2, unsigned short a3,
                                       unsigned short a4, unsigned short a5,
                                       unsigned short a6, unsigned short a7) {
  uint4 v;
  v.x = (unsigned int)a0 | ((unsigned int)a1 << 16);
  v.y = (unsigned int)a2 | ((unsigned int)a3 << 16);
  v.z = (unsigned int)a4 | ((unsigned int)a5 << 16);
  v.w = (unsigned int)a6 | ((unsigned int)a7 << 16);
  return v;
}
// async global->LDS, 16B per lane; LDS dst is wave-uniform base (+lane*16 HW)
__device__ __forceinline__ void gload_lds16(const void* g, void* l) {
  __builtin_amdgcn_global_load_lds(
      (const __attribute__((address_space(1))) unsigned int*)g,
      (__attribute__((address_space(3))) unsigned int*)l, 16, 0, 0);
}

// ---------------------------------------------------------------------------
// K0: detect mask dtype. int32 0/1 data => bytes at offset %4 != 0 are all 0.
// ---------------------------------------------------------------------------
__global__ void k_detect(const unsigned char* __restrict__ m) {
  if (threadIdx.x == 0) {
    int nz = 0;
    for (int i = 0; i < 1024; ++i)
      if ((i & 3) && m[i]) nz++;
    g_mask_is_int = (nz == 0) ? 1 : 0;
  }
}

// ===========================================================================
// FAST PATH
// ===========================================================================

// ---------------------------------------------------------------------------
// k_split: src f32 -> hi/lo bf16 blobs in proj's swizzled LDS-image layout.
// (unchanged, verified round 11)
// ---------------------------------------------------------------------------
__global__ __launch_bounds__(256) void k_split(const float* __restrict__ src,
                                               unsigned short* __restrict__ hi,
                                               unsigned short* __restrict__ lo) {
#pragma unroll
  for (int j = 0; j < 4; ++j) {
    const size_t Lg = ((size_t)blockIdx.x * 1024 + j * 256 + threadIdx.x) * 16;
    const int Lloc = (int)(Lg & 16383);
    const int TS = (int)(Lg >> 14);
    const int T = TS >> 4, s = TS & 15;
    const int row = Lloc >> 7;
    const int kb = (Lloc & 127) ^ ((row & 7) << 4);
    const int kk = kb >> 1;
    const float* sp = src + ((size_t)(T * 128 + row)) * 1024 + s * 64 + kk;
    const f32x4 v0 = *(const f32x4*)(sp);
    const f32x4 v1 = *(const f32x4*)(sp + 4);
    unsigned short h[8], l[8];
#pragma unroll
    for (int i = 0; i < 4; ++i) {
      unsigned short hh = f2bf(v0[i]);
      h[i] = hh;
      l[i] = f2bf(v0[i] - bf2f(hh));
      unsigned short h2 = f2bf(v1[i]);
      h[4 + i] = h2;
      l[4 + i] = f2bf(v1[i] - bf2f(h2));
    }
    *(uint4*)((char*)hi + Lg) = pack8(h[0], h[1], h[2], h[3], h[4], h[5], h[6], h[7]);
    *(uint4*)((char*)lo + Lg) = pack8(l[0], l[1], l[2], l[3], l[4], l[5], l[6], l[7]);
  }
}

// ---------------------------------------------------------------------------
// k_proj_dma: proj = tanh(ems @ W^T + bias), pure-DMA dbuf (verified r11).
// NEW: XCD-pinned grid map -- blocks sharing an A (ems) tile colocate on
// one XCD so the A blob tile is L2-resident (was fetched by all 8 XCDs).
// ---------------------------------------------------------------------------
__global__ __launch_bounds__(512) void k_proj_dma(
    const unsigned short* __restrict__ eHi, const unsigned short* __restrict__ eLo,
    const unsigned short* __restrict__ wHi, const unsigned short* __restrict__ wLo,
    const float* __restrict__ bias,
    unsigned short* __restrict__ outHi, unsigned short* __restrict__ outLo) {
  __shared__ uint4 lds4[8192];   // 128KB
  char* pAhi_c = (char*)lds4;
  char* pAlo_c = (char*)lds4 + 16384;
  char* pBhi_c = (char*)lds4 + 32768;
  char* pBlo_c = (char*)lds4 + 49152;
  char* pAhi_n = (char*)lds4 + 65536;
  char* pAlo_n = (char*)lds4 + 81920;
  char* pBhi_n = (char*)lds4 + 98304;
  char* pBlo_n = (char*)lds4 + 114688;

  const int g = blockIdx.x;
  const int xcd = g & 7;
  const int slot = g >> 3;               // 0..127
  const int Tm = xcd + 8 * (slot >> 3);  // 0..127, pinned to XCD
  const int Tn = slot & 7;               // 0..7
  const int t = threadIdx.x, l = t & 63, wv = t >> 6;
  const int wm2 = wv >> 1;   // 0..3 -> rows wm2*32
  const int wn2 = wv & 1;    // 0..1 -> cols wn2*64

  f32x4 acc[2][4];
#pragma unroll
  for (int i = 0; i < 2; ++i)
#pragma unroll
    for (int j = 0; j < 4; ++j) acc[i][j] = (f32x4){0.f, 0.f, 0.f, 0.f};

  auto dma_stage = [&](int s, char* pAh, char* pAl, char* pBh, char* pBl) {
#pragma unroll
    for (int j = 0; j < 2; ++j) {
      const size_t ga = (size_t)Tm * 262144 + (size_t)s * 16384 + j * 8192 +
                        wv * 1024 + l * 16;
      gload_lds16((const char*)eHi + ga, pAh + j * 8192 + wv * 1024);
      gload_lds16((const char*)eLo + ga, pAl + j * 8192 + wv * 1024);
      const size_t gb = (size_t)Tn * 262144 + (size_t)s * 16384 + j * 8192 +
                        wv * 1024 + l * 16;
      gload_lds16((const char*)wHi + gb, pBh + j * 8192 + wv * 1024);
      gload_lds16((const char*)wLo + gb, pBl + j * 8192 + wv * 1024);
    }
  };

  auto compute_stage = [&](const char* pAh, const char* pAl,
                           const char* pBh, const char* pBl) {
#pragma unroll
    for (int ks = 0; ks < 2; ++ks) {
      const int kb = ks * 64 + (l >> 4) * 16;
      short8 ah[2], al[2], bh[4], bl[4];
#pragma unroll
      for (int f = 0; f < 2; ++f) {
        const int o = swz(wm2 * 32 + f * 16 + (l & 15), kb);
        ah[f] = *(const short8*)(pAh + o);
        al[f] = *(const short8*)(pAl + o);
      }
#pragma unroll
      for (int f = 0; f < 4; ++f) {
        const int o = swz(wn2 * 64 + f * 16 + (l & 15), kb);
        bh[f] = *(const short8*)(pBh + o);
        bl[f] = *(const short8*)(pBl + o);
      }
#pragma unroll
      for (int fm = 0; fm < 2; ++fm)
#pragma unroll
        for (int fn = 0; fn < 4; ++fn) {
          acc[fm][fn] = __builtin_amdgcn_mfma_f32_16x16x32_bf16(ah[fm], bh[fn], acc[fm][fn], 0, 0, 0);
          acc[fm][fn] = __builtin_amdgcn_mfma_f32_16x16x32_bf16(al[fm], bh[fn], acc[fm][fn], 0, 0, 0);
          acc[fm][fn] = __builtin_amdgcn_mfma_f32_16x16x32_bf16(ah[fm], bl[fn], acc[fm][fn], 0, 0, 0);
        }
    }
  };

  dma_stage(0, pAhi_c, pAlo_c, pBhi_c, pBlo_c);
  __syncthreads();
  for (int s = 0; s < 16; ++s) {
    if (s < 15) dma_stage(s + 1, pAhi_n, pAlo_n, pBhi_n, pBlo_n);
    compute_stage(pAhi_c, pAlo_c, pBhi_c, pBlo_c);
    __syncthreads();
    char* x;
    x = pAhi_c; pAhi_c = pAhi_n; pAhi_n = x;
    x = pAlo_c; pAlo_c = pAlo_n; pAlo_n = x;
    x = pBhi_c; pBhi_c = pBhi_n; pBhi_n = x;
    x = pBlo_c; pBlo_c = pBlo_n; pBlo_n = x;
  }

  float bcol[4];
#pragma unroll
  for (int fn = 0; fn < 4; ++fn)
    bcol[fn] = bias[Tn * 128 + wn2 * 64 + fn * 16 + (l & 15)];
#pragma unroll
  for (int fm = 0; fm < 2; ++fm)
#pragma unroll
    for (int fn = 0; fn < 4; ++fn)
#pragma unroll
      for (int q = 0; q < 4; ++q)
        acc[fm][fn][q] = ftanh(acc[fm][fn][q] + bcol[fn]);

  unsigned short* ldsT = (unsigned short*)lds4;  // [128][136]
  __syncthreads();
#pragma unroll
  for (int fm = 0; fm < 2; ++fm)
#pragma unroll
    for (int fn = 0; fn < 4; ++fn)
#pragma unroll
      for (int q = 0; q < 4; ++q) {
        const int rl = wm2 * 32 + fm * 16 + (l >> 4) * 4 + q;
        const int cl = wn2 * 64 + fn * 16 + (l & 15);
        ldsT[rl * 136 + cl] = f2bf(acc[fm][fn][q]);
      }
  __syncthreads();
#pragma unroll
  for (int sb = 0; sb < 4; ++sb) {
    const int L = t * 16;
    const int x6 = ((L >> 6) ^ (L >> 8)) & 1;
    const int x5 = ((L >> 5) ^ (L >> 7)) & 1;
    const int x4 = ((L >> 4) ^ (L >> 6) ^ (L >> 8)) & 1;
    const int X = (L & ~0x70) | (x6 << 6) | (x5 << 5) | (x4 << 4);
    const int row = X >> 6;
    const int cl = sb * 32 + ((X & 63) >> 1);
    uint4 v = *(const uint4*)(ldsT + row * 136 + cl);
    *(uint4*)((char*)outHi + (size_t)Tm * 262144 +
              (size_t)(Tn * 4 + sb) * 8192 + L) = v;
  }
  __syncthreads();
#pragma unroll
  for (int fm = 0; fm < 2; ++fm)
#pragma unroll
    for (int fn = 0; fn < 4; ++fn)
#pragma unroll
      for (int q = 0; q < 4; ++q) {
        const int rl = wm2 * 32 + fm * 16 + (l >> 4) * 4 + q;
        const int cl = wn2 * 64 + fn * 16 + (l & 15);
        const float x = acc[fm][fn][q];
        const unsigned short hh2 = f2bf(x);
        ldsT[rl * 136 + cl] = f2bf(x - bf2f(hh2));
      }
  __syncthreads();
#pragma unroll
  for (int sb = 0; sb < 4; ++sb) {
    const int L = t * 16;
    const int x6 = ((L >> 6) ^ (L >> 8)) & 1;
    const int x5 = ((L >> 5) ^ (L >> 7)) & 1;
    const int x4 = ((L >> 4) ^ (L >> 6) ^ (L >> 8)) & 1;
    const int X = (L & ~0x70) | (x6 << 6) | (x5 << 5) | (x4 << 4);
    const int row = X >> 6;
    const int cl = sb * 32 + ((X & 63) >> 1);
    uint4 v = *(const uint4*)(ldsT + row * 136 + cl);
    *(uint4*)((char*)outLo + (size_t)Tm * 262144 +
              (size_t)(Tn * 4 + sb) * 8192 + L) = v;
  }
}

// ---------------------------------------------------------------------------
// k_scores_mfma: scores = proj @ words^T (split-bf16 3-term), f32 -> ws.
// REVERTED to round-11-verified v3 (214 us): BM=512 x BN=128, BK=32,
// dbuf 160KB, one barrier/stage, A via DMA from blob planes.
// ---------------------------------------------------------------------------
__global__ __launch_bounds__(512) void k_scores_mfma(
    const unsigned short* __restrict__ pHi, const unsigned short* __restrict__ pLo,
    const float* __restrict__ words, float* __restrict__ sc) {
  __shared__ uint4 lds4[10240];  // 160KB
  char* pAhi_c = (char*)lds4;             // 32KB: [4 tiles][8KB swz64x]
  char* pAlo_c = (char*)lds4 + 32768;
  char* pAhi_n = (char*)lds4 + 65536;
  char* pAlo_n = (char*)lds4 + 98304;
  char* pBhi_c = (char*)lds4 + 131072;    // 8KB: [128 n][64B swz64x]
  char* pBlo_c = (char*)lds4 + 139264;
  char* pBhi_n = (char*)lds4 + 147456;
  char* pBlo_n = (char*)lds4 + 155648;

  const int g = blockIdx.x;
  const int b = (g & 7) + 8 * (g >> 7);   // XCD-pinned batch (bijective)
  const int n0 = ((g >> 3) & 15) * 128;

  const int t = threadIdx.x, l = t & 63, wv = t >> 6;
  const int wm4 = wv >> 1;    // 0..3 -> m tile (128 rows each)
  const int wn2 = wv & 1;     // 0..1 -> n base local = wn2*64

  f32x4 acc[8][4];
#pragma unroll
  for (int i = 0; i < 8; ++i)
#pragma unroll
    for (int j = 0; j < 4; ++j) acc[i][j] = (f32x4){0.f, 0.f, 0.f, 0.f};

  f32x4 br0, br1;
  const int bn = t >> 2;          // B n-row 0..127
  const int bc = (t & 3) * 8;     // f32 col base within 32

  auto dma_A = [&](int s, char* pH, char* pL) {
#pragma unroll
    for (int j = 0; j < 4; ++j) {
      const size_t gb = (size_t)(b * 4 + j) * 262144 + (size_t)s * 8192 +
                        wv * 1024 + l * 16;
      gload_lds16((const char*)pHi + gb, pH + j * 8192 + wv * 1024);
      gload_lds16((const char*)pLo + gb, pL + j * 8192 + wv * 1024);
    }
  };

  auto load_B = [&](int s) {
    const float* bs = words + (size_t)b * WN * D_ + (size_t)(n0 + bn) * 1024 +
                      s * 32 + bc;
    br0 = *(const f32x4*)(bs);
    br1 = *(const f32x4*)(bs + 4);
  };

  auto write_B = [&](char* pH, char* pL) {
    unsigned short hB[8], lB[8];
#pragma unroll
    for (int j = 0; j < 4; ++j) {
      float y0 = br0[j];
      unsigned short h0 = f2bf(y0);
      hB[j] = h0;
      lB[j] = f2bf(y0 - bf2f(h0));
      float y1 = br1[j];
      unsigned short h1 = f2bf(y1);
      hB[4 + j] = h1;
      lB[4 + j] = f2bf(y1 - bf2f(h1));
    }
    const int o = swz64x(bn, (t & 3) * 16);
    *(uint4*)(pH + o) = pack8(hB[0], hB[1], hB[2], hB[3], hB[4], hB[5], hB[6], hB[7]);
    *(uint4*)(pL + o) = pack8(lB[0], lB[1], lB[2], lB[3], lB[4], lB[5], lB[6], lB[7]);
  };

  auto compute_stage = [&](const char* pAh, const char* pAl,
                           const char* pBh, const char* pBl) {
    const int kb0 = (l >> 4) * 16;
    short8 bh[4], bl[4];
#pragma unroll
    for (int f = 0; f < 4; ++f) {
      const int n = wn2 * 64 + f * 16 + (l & 15);
      const int o = swz64x(n, kb0);
      bh[f] = *(const short8*)(pBh + o);
      bl[f] = *(const short8*)(pBl + o);
    }
#pragma unroll
    for (int fm = 0; fm < 8; ++fm) {
      const int row = fm * 16 + (l & 15);
      const int oa = wm4 * 8192 + swz64x(row, kb0);
      const short8 ah = *(const short8*)(pAh + oa);
      const short8 al = *(const short8*)(pAl + oa);
#pragma unroll
      for (int fn = 0; fn < 4; ++fn) {
        acc[fm][fn] = __builtin_amdgcn_mfma_f32_16x16x32_bf16(ah, bh[fn], acc[fm][fn], 0, 0, 0);
        acc[fm][fn] = __builtin_amdgcn_mfma_f32_16x16x32_bf16(al, bh[fn], acc[fm][fn], 0, 0, 0);
        acc[fm][fn] = __builtin_amdgcn_mfma_f32_16x16x32_bf16(ah, bl[fn], acc[fm][fn], 0, 0, 0);
      }
    }
  };

  // prologue
  load_B(0);
  dma_A(0, pAhi_c, pAlo_c);
  write_B(pBhi_c, pBlo_c);
  __syncthreads();

  for (int s = 0; s < 32; ++s) {
    if (s < 31) {
      load_B(s + 1);
      dma_A(s + 1, pAhi_n, pAlo_n);
    }
    compute_stage(pAhi_c, pAlo_c, pBhi_c, pBlo_c);
    if (s < 31) write_B(pBhi_n, pBlo_n);
    __syncthreads();  // drains DMA (vmcnt) + ds_writes (lgkm)
    char* x;
    x = pAhi_c; pAhi_c = pAhi_n; pAhi_n = x;
    x = pAlo_c; pAlo_c = pAlo_n; pAlo_n = x;
    x = pBhi_c; pBhi_c = pBhi_n; pBhi_n = x;
    x = pBlo_c; pBlo_c = pBlo_n; pBlo_n = x;
  }

  // store f32 scores
#pragma unroll
  for (int fm = 0; fm < 8; ++fm)
#pragma unroll
    for (int fn = 0; fn < 4; ++fn)
#pragma unroll
      for (int q = 0; q < 4; ++q) {
        const int row = wm4 * 128 + fm * 16 + (l >> 4) * 4 + q;
        const int col = n0 + wn2 * 64 + fn * 16 + (l & 15);
        sc[((size_t)b * 512 + row) * 2048 + col] = acc[fm][fn][q];
      }
}

// ---------------------------------------------------------------------------
// k_softmax: unchanged (verified round 9/10). blob pointer is a parameter.
// ---------------------------------------------------------------------------
__global__ __launch_bounds__(256) void k_softmax(const float* __restrict__ ws,
                                                 const void* __restrict__ mask,
                                                 unsigned short* __restrict__ blob) {
  __shared__ float red[8];
  const int row = blockIdx.x;
  const int t = threadIdx.x;
  const int wave = t >> 6;
  const float* rp = ws + (size_t)row * 2048;
  float v[8];
  {
    f32x4 v0 = *(const f32x4*)(rp + t * 8);
    f32x4 v1 = *(const f32x4*)(rp + t * 8 + 4);
#pragma unroll
    for (int i = 0; i < 4; ++i) { v[i] = v0[i]; v[4 + i] = v1[i]; }
  }
  if (g_mask_is_int) {
    const int* mp = (const int*)mask + (size_t)row * 2048 + t * 8;
    const int4 m0 = *(const int4*)mp;
    const int4 m1 = *(const int4*)(mp + 4);
    if (m0.x) v[0] = -INFINITY;
    if (m0.y) v[1] = -INFINITY;
    if (m0.z) v[2] = -INFINITY;
    if (m0.w) v[3] = -INFINITY;
    if (m1.x) v[4] = -INFINITY;
    if (m1.y) v[5] = -INFINITY;
    if (m1.z) v[6] = -INFINITY;
    if (m1.w) v[7] = -INFINITY;
  } else {
    const unsigned char* mp = (const unsigned char*)mask + (size_t)row * 2048 + t * 8;
    const uchar4 m0 = *(const uchar4*)mp;
    const uchar4 m1 = *(const uchar4*)(mp + 4);
    if (m0.x) v[0] = -INFINITY;
    if (m0.y) v[1] = -INFINITY;
    if (m0.z) v[2] = -INFINITY;
    if (m0.w) v[3] = -INFINITY;
    if (m1.x) v[4] = -INFINITY;
    if (m1.y) v[5] = -INFINITY;
    if (m1.z) v[6] = -INFINITY;
    if (m1.w) v[7] = -INFINITY;
  }
  float mx = v[0];
#pragma unroll
  for (int i = 1; i < 8; ++i) mx = fmaxf(mx, v[i]);
#pragma unroll
  for (int off = 32; off > 0; off >>= 1) mx = fmaxf(mx, __shfl_xor(mx, off));
  if ((t & 63) == 0) red[wave] = mx;
  __syncthreads();
  mx = fmaxf(fmaxf(red[0], red[1]), fmaxf(red[2], red[3]));
  float e[8];
  float sum = 0.0f;
#pragma unroll
  for (int i = 0; i < 8; ++i) {
    e[i] = __expf(v[i] - mx);
    sum += e[i];
  }
#pragma unroll
  for (int off = 32; off > 0; off >>= 1) sum += __shfl_xor(sum, off);
  if ((t & 63) == 0) red[4 + wave] = sum;
  __syncthreads();
  const float tot = (red[4] + red[5]) + (red[6] + red[7]);
  const float rinv = 1.0f / tot;

  const int b = row >> 9, ee = row & 511;
  const uint4 pk = pack8(f2bf(e[0] * rinv), f2bf(e[1] * rinv),
                         f2bf(e[2] * rinv), f2bf(e[3] * rinv),
                         f2bf(e[4] * rinv), f2bf(e[5] * rinv),
                         f2bf(e[6] * rinv), f2bf(e[7] * rinv));
  char* dst = (char*)blob + (size_t)b * 2097152 + (size_t)(t >> 3) * 65536 +
              ee * 128 + (((t & 7) * 16) ^ ((ee & 7) << 4));
  *(uint4*)dst = pk;
}

// ---------------------------------------------------------------------------
// k_pv: ctx = att @ words (unchanged, verified round 9). blob/ctx pointers
// are parameters (big-ws path: blob in ws, ctx -> d_out directly).
// ---------------------------------------------------------------------------
__global__ __launch_bounds__(512) void k_pv(
    const unsigned short* __restrict__ blob, const float* __restrict__ words,
    float* __restrict__ ctx) {
  __shared__ uint4 lds4[10240];           // 160KB
  char* pAc = (char*)lds4;
  char* pAn = (char*)lds4 + 65536;
  char* pBc = (char*)lds4 + 131072;
  char* pBn = (char*)lds4 + 147456;

  const int g = blockIdx.x;
  const int b = (g & 7) + 8 * (g >> 6);   // XCD-pinned batch
  const int wt = (g >> 3) & 7;
  const int w0 = wt * 128;

  const int t = threadIdx.x, l = t & 63, wv = t >> 6;
  const int wm4 = wv >> 1;
  const int wn2 = wv & 1;

  const char* blobB = (const char*)blob + (size_t)b * 2097152;

  f32x4 acc[8][4];
#pragma unroll
  for (int i = 0; i < 8; ++i)
#pragma unroll
    for (int j = 0; j < 4; ++j) acc[i][j] = (f32x4){0.f, 0.f, 0.f, 0.f};

  f32x4 bv0a, bv0b, bv1a, bv1b;
  const int np2 = (t & 31) * 2;
  const int wc = (t >> 5) * 8;

  auto dma_A = [&](int s, char* pA) {
    const char* gp = blobB + (size_t)s * 65536 + wv * 8192 + l * 16;
#pragma unroll
    for (int j = 0; j < 8; ++j)
      gload_lds16(gp + j * 1024, pA + wv * 8192 + j * 1024);
  };

  auto load_B = [&](int s) {
    const float* wp = words + (size_t)b * WN * D_ +
                      (size_t)(s * 64 + np2) * 1024 + w0 + wc;
    bv0a = *(const f32x4*)(wp);
    bv0b = *(const f32x4*)(wp + 4);
    bv1a = *(const f32x4*)(wp + 1024);
    bv1b = *(const f32x4*)(wp + 1028);
  };

  auto write_B = [&](char* pB) {
#pragma unroll
    for (int i = 0; i < 8; ++i) {
      const int w = wc + i;
      const float x0 = (i < 4) ? bv0a[i & 3] : bv0b[i & 3];
      const float x1 = (i < 4) ? bv1a[i & 3] : bv1b[i & 3];
      const unsigned int pk =
          (unsigned int)f2bf(x0) | ((unsigned int)f2bf(x1) << 16);
      *(unsigned int*)(pB + w * 128 + ((np2 * 2) ^ ((w & 7) << 4))) = pk;
    }
  };

  auto compute_stage = [&](const char* pA, const char* pB) {
#pragma unroll
    for (int ks = 0; ks < 2; ++ks) {
      short8 a[8];
      const int kb = ks * 64 + (l >> 4) * 16;
#pragma unroll
      for (int f = 0; f < 8; ++f) {
        const int row = wm4 * 128 + f * 16 + (l & 15);
        a[f] = *(const short8*)(pA + swz(row, kb));
      }
      short8 bb[4];
#pragma unroll
      for (int f = 0; f < 4; ++f) {
        const int row = wn2 * 64 + f * 16 + (l & 15);
        bb[f] = *(const short8*)(pB + swz(row, kb));
      }
#pragma unroll
      for (int fm = 0; fm < 8; ++fm)
#pragma unroll
        for (int fn = 0; fn < 4; ++fn)
          acc[fm][fn] = __builtin_amdgcn_mfma_f32_16x16x32_bf16(a[fm], bb[fn], acc[fm][fn], 0, 0, 0);
    }
  };

  load_B(0);
  dma_A(0, pAc);
  write_B(pBc);
  __syncthreads();

  for (int s = 0; s < 32; ++s) {
    if (s < 31) {
      load_B(s + 1);
      dma_A(s + 1, pAn);
    }
    compute_stage(pAc, pBc);
    if (s < 31) write_B(pBn);
    __syncthreads();
    char* t1 = pAc; pAc = pAn; pAn = t1;
    char* t2 = pBc; pBc = pBn; pBn = t2;
  }

#pragma unroll
  for (int fm = 0; fm < 8; ++fm)
#pragma unroll
    for (int fn = 0; fn < 4; ++fn)
#pragma unroll
      for (int q = 0; q < 4; ++q) {
        const int row = wm4 * 128 + fm * 16 + (l >> 4) * 4 + q;
        const int col = w0 + wn2 * 64 + fn * 16 + (l & 15);
        ctx[((size_t)b * 512 + row) * 1024 + col] = acc[fm][fn][q];
      }
}

// ---------------------------------------------------------------------------
// k_copy: ctx (ws) -> d_out, float4 grid-stride. (small-ws fallback only)
// ---------------------------------------------------------------------------
__global__ __launch_bounds__(256) void k_copy(const float4* __restrict__ src,
                                              float4* __restrict__ dst) {
  const int n4 = 16384 * 1024 / 4;
  int i = blockIdx.x * 256 + threadIdx.x;
  const int stride = gridDim.x * 256;
  for (; i < n4; i += stride) dst[i] = src[i];
}

// ===========================================================================
// FALLBACK PATH (round-2 verified kernels; used if ws too small)
// ===========================================================================
__global__ __launch_bounds__(256, 4) void k_proj(const float* __restrict__ A,
                                                 const float* __restrict__ W,
                                                 const float* __restrict__ bias,
                                                 float* __restrict__ out) {
  __shared__ float As[32][132];
  __shared__ float Bs[32][132];
  const int t = threadIdx.x;
  const int m0 = blockIdx.x * 128;
  const int n0 = blockIdx.y * 128;
  const int tm = t >> 4;
  const int tn = t & 15;
  const int lrow = t >> 1;
  const int lk = (t & 1) * 16;

  float acc[8][8];
#pragma unroll
  for (int i = 0; i < 8; ++i)
#pragma unroll
    for (int j = 0; j < 8; ++j) acc[i][j] = 0.0f;

  const float* Arow = A + (size_t)(m0 + lrow) * D_ + lk;
  const float* Wrow = W + (size_t)(n0 + lrow) * D_ + lk;

  for (int k0 = 0; k0 < D_; k0 += 32) {
    __syncthreads();
#pragma unroll
    for (int j = 0; j < 4; ++j) {
      const float4 va = *(const float4*)(Arow + k0 + j * 4);
      As[lk + j * 4 + 0][lrow] = va.x;
      As[lk + j * 4 + 1][lrow] = va.y;
      As[lk + j * 4 + 2][lrow] = va.z;
      As[lk + j * 4 + 3][lrow] = va.w;
      const float4 vb = *(const float4*)(Wrow + k0 + j * 4);
      Bs[lk + j * 4 + 0][lrow] = vb.x;
      Bs[lk + j * 4 + 1][lrow] = vb.y;
      Bs[lk + j * 4 + 2][lrow] = vb.z;
      Bs[lk + j * 4 + 3][lrow] = vb.w;
    }
    __syncthreads();
#pragma unroll 8
    for (int k = 0; k < 32; ++k) {
      float a[8], bb[8];
      *(float4*)(a + 0) = *(const float4*)&As[k][tm * 4];
      *(float4*)(a + 4) = *(const float4*)&As[k][tm * 4 + 64];
      *(float4*)(bb + 0) = *(const float4*)&Bs[k][tn * 4];
      *(float4*)(bb + 4) = *(const float4*)&Bs[k][tn * 4 + 64];
#pragma unroll
      for (int i = 0; i < 8; ++i)
#pragma unroll
        for (int j = 0; j < 8; ++j) acc[i][j] = fmaf(a[i], bb[j], acc[i][j]);
    }
  }

  float bn[8];
#pragma unroll
  for (int j = 0; j < 8; ++j) bn[j] = bias[n0 + tn * 4 + (j & 3) + (j >> 2) * 64];
#pragma unroll
  for (int i = 0; i < 8; ++i) {
    const int m = m0 + tm * 4 + (i & 3) + (i >> 2) * 64;
    float4 v0, v1;
    v0.x = tanhf(acc[i][0] + bn[0]);
    v0.y = tanhf(acc[i][1] + bn[1]);
    v0.z = tanhf(acc[i][2] + bn[2]);
    v0.w = tanhf(acc[i][3] + bn[3]);
    v1.x = tanhf(acc[i][4] + bn[4]);
    v1.y = tanhf(acc[i][5] + bn[5]);
    v1.z = tanhf(acc[i][6] + bn[6]);
    v1.w = tanhf(acc[i][7] + bn[7]);
    *(float4*)(out + (size_t)m * D_ + n0 + tn * 4) = v0;
    *(float4*)(out + (size_t)m * D_ + n0 + tn * 4 + 64) = v1;
  }
}

__global__ __launch_bounds__(256) void k_scores(const float* __restrict__ words,
                                                const void* __restrict__ mask,
                                                float* __restrict__ pa) {
  __shared__ float Pt[1024][18];
  __shared__ float Ws[64][268];
  const int t = threadIdx.x;
  const int b = blockIdx.x >> 5;
  const int et = blockIdx.x & 31;
  const int e0 = et * 16;
  const int eg = t >> 5;
  const int ng = t & 31;
  const int mask_is_int = g_mask_is_int;
  const float* wbase = words + (size_t)b * WN * D_;

  {
    const int row = t >> 4;
    const int dj = (t & 15) * 4;
    const float* pr = pa + (size_t)(b * E_ + e0 + row) * D_;
#pragma unroll
    for (int rr = 0; rr < 16; ++rr) {
      const float4 v = *(const float4*)(pr + dj + rr * 64);
      Pt[dj + rr * 64 + 0][row] = v.x;
      Pt[dj + rr * 64 + 1][row] = v.y;
      Pt[dj + rr * 64 + 2][row] = v.z;
      Pt[dj + rr * 64 + 3][row] = v.w;
    }
  }

  float s[2][64];
#pragma unroll
  for (int i = 0; i < 2; ++i)
#pragma unroll
    for (int u = 0; u < 64; ++u) s[i][u] = 0.0f;

  const int nl = t >> 3;
  const int d4 = (t & 7) * 4;

  for (int dk = 0; dk < D_; dk += 64) {
#pragma unroll
    for (int nb = 0; nb < 8; ++nb) {
      __syncthreads();
#pragma unroll
      for (int rr = 0; rr < 8; ++rr) {
#pragma unroll
        for (int hh = 0; hh < 2; ++hh) {
          const int n = nl + rr * 32;
          const int d = d4 + hh * 32;
          const float4 v = *(const float4*)(wbase + (size_t)(nb * 256 + n) * D_ + dk + d);
          Ws[d + 0][n] = v.x;
          Ws[d + 1][n] = v.y;
          Ws[d + 2][n] = v.z;
          Ws[d + 3][n] = v.w;
        }
      }
      __syncthreads();
#pragma unroll 2
      for (int k = 0; k < 64; ++k) {
        const float2 a = *(const float2*)&Pt[dk + k][eg * 2];
        const float4 b0 = *(const float4*)&Ws[k][ng * 4];
        const float4 b1 = *(const float4*)&Ws[k][128 + ng * 4];
        const float aa[2] = {a.x, a.y};
        const float bb[8] = {b0.x, b0.y, b0.z, b0.w, b1.x, b1.y, b1.z, b1.w};
#pragma unroll
        for (int i = 0; i < 2; ++i)
#pragma unroll
          for (int u = 0; u < 8; ++u)
            s[i][nb * 8 + u] = fmaf(aa[i], bb[u], s[i][nb * 8 + u]);
      }
    }
  }

#pragma unroll
  for (int i = 0; i < 2; ++i) {
    const int e = e0 + eg * 2 + i;
#pragma unroll
    for (int nb = 0; nb < 8; ++nb)
#pragma unroll
      for (int q = 0; q < 2; ++q) {
        const size_t moff = (size_t)(b * E_ + e) * WN + nb * 256 + q * 128 + ng * 4;
        int mx, my, mz, mw;
        if (mask_is_int) {
          const int4 mv = *(const int4*)((const int*)mask + moff);
          mx = mv.x; my = mv.y; mz = mv.z; mw = mv.w;
        } else {
          const uchar4 mv = *(const uchar4*)((const unsigned char*)mask + moff);
          mx = mv.x; my = mv.y; mz = mv.z; mw = mv.w;
        }
        if (mx) s[i][nb * 8 + q * 4 + 0] = -1e30f;
        if (my) s[i][nb * 8 + q * 4 + 1] = -1e30f;
        if (mz) s[i][nb * 8 + q * 4 + 2] = -1e30f;
        if (mw) s[i][nb * 8 + q * 4 + 3] = -1e30f;
      }
    float m = -1e30f;
#pragma unroll
    for (int u = 0; u < 64; ++u) m = fmaxf(m, s[i][u]);
#pragma unroll
    for (int off = 16; off > 0; off >>= 1) m = fmaxf(m, __shfl_xor(m, off));
    float sum = 0.0f;
#pragma unroll
    for (int u = 0; u < 64; ++u) {
      const float p = __expf(s[i][u] - m);
      s[i][u] = p;
      sum += p;
    }
#pragma unroll
    for (int off = 16; off > 0; off >>= 1) sum += __shfl_xor(sum, off);
    const float rinv = 1.0f / sum;

    unsigned short* ar2 = (unsigned short*)(pa + (size_t)(b * E_ + e) * WN / 2);
#pragma unroll
    for (int nb = 0; nb < 8; ++nb)
#pragma unroll
      for (int q = 0; q < 2; ++q) {
        ushort4 pk;
        pk.x = f2bf(s[i][nb * 8 + q * 4 + 0] * rinv);
        pk.y = f2bf(s[i][nb * 8 + q * 4 + 1] * rinv);
        pk.z = f2bf(s[i][nb * 8 + q * 4 + 2] * rinv);
        pk.w = f2bf(s[i][nb * 8 + q * 4 + 3] * rinv);
        *(ushort4*)(ar2 + nb * 256 + q * 128 + ng * 4) = pk;
      }
  }
}

__global__ __launch_bounds__(256) void k_ctx(const float* __restrict__ words,
                                             float* __restrict__ pa) {
  __shared__ unsigned short att_s[16][2048];
  __shared__ unsigned short Wb[256][132];
  const int t = threadIdx.x;
  const int b = blockIdx.x >> 5;
  const int et = blockIdx.x & 31;
  const int e0 = et * 16;
  const int eg = t >> 5;
  const int wg = t & 31;
  const float* wbase = words + (size_t)b * WN * D_;

  {
    const int row = t >> 4;
    const int cj = t & 15;
    const uint4* pr = (const uint4*)(pa + (size_t)(b * E_ + e0 + row) * D_);
#pragma unroll
    for (int rr = 0; rr < 16; ++rr) {
      const int c = cj + rr * 16;
      const uint4 v = pr[c];
      *(uint4*)&att_s[row][c * 8] = v;
    }
  }

  float acc[2][32];
#pragma unroll
  for (int i = 0; i < 2; ++i)
#pragma unroll
    for (int u = 0; u < 32; ++u) acc[i][u] = 0.0f;

  const int nlg = t >> 5;
  const int w4 = (t & 31) * 4;

  for (int nb = 0; nb < 8; ++nb) {
#pragma unroll
    for (int q = 0; q < 8; ++q) {
      __syncthreads();
#pragma unroll
      for (int rr = 0; rr < 32; ++rr) {
        const int n = nlg + rr * 8;
        const float4 v = *(const float4*)(wbase + (size_t)(nb * 256 + n) * D_ + q * 128 + w4);
        ushort4 pk;
        pk.x = f2bf(v.x);
        pk.y = f2bf(v.y);
        pk.z = f2bf(v.z);
        pk.w = f2bf(v.w);
        *(ushort4*)&Wb[n][w4] = pk;
      }
      __syncthreads();
#pragma unroll 4
      for (int n2 = 0; n2 < 128; ++n2) {
        const int n = n2 * 2;
        const ushort4 r0 = *(const ushort4*)&Wb[n][wg * 4];
        const ushort4 r1 = *(const ushort4*)&Wb[n + 1][wg * 4];
        const float w0[4] = {bf2f(r0.x), bf2f(r0.y), bf2f(r0.z), bf2f(r0.w)};
        const float w1[4] = {bf2f(r1.x), bf2f(r1.y), bf2f(r1.z), bf2f(r1.w)};
#pragma unroll
        for (int i = 0; i < 2; ++i) {
          const unsigned int aw = *(const unsigned int*)&att_s[eg * 2 + i][nb * 256 + n];
          const float a0 = bf2f((unsigned short)(aw & 0xffffu));
          const float a1 = bf2f((unsigned short)(aw >> 16));
#pragma unroll
          for (int j = 0; j < 4; ++j)
            acc[i][q * 4 + j] = fmaf(a0, w0[j], fmaf(a1, w1[j], acc[i][q * 4 + j]));
        }
      }
    }
  }

#pragma unroll
  for (int i = 0; i < 2; ++i) {
    float* orow = pa + (size_t)(b * E_ + e0 + eg * 2 + i) * D_;
#pragma unroll
    for (int q = 0; q < 8; ++q) {
      float4 v;
      v.x = acc[i][q * 4 + 0];
      v.y = acc[i][q * 4 + 1];
      v.z = acc[i][q * 4 + 2];
      v.w = acc[i][q * 4 + 3];
      *(float4*)(orow + q * 128 + wg * 4) = v;
    }
  }
}

extern "C" void kernel_launch(void* const* d_in, const int* in_sizes, int n_in,
                              void* d_out, int out_size, void* d_ws, size_t ws_size,
                              hipStream_t stream) {
  const float* ems = (const float*)d_in[0];
  const float* words = (const float*)d_in[1];
  const void* mask = d_in[2];
  const float* w_weight = (const float*)d_in[3];
  const float* w_bias = (const float*)d_in[4];

  k_detect<<<1, 64, 0, stream>>>((const unsigned char*)mask);

  const size_t ws_need = (size_t)16384 * 2048 * 4;          // 128 MB
  const size_t ws_big = ws_need + (size_t)32 * 2097152;     // +64 MB blob
  if (ws_size >= ws_need) {
    unsigned short* hiP = (unsigned short*)d_out;
    unsigned short* loP = hiP + (size_t)16384 * 1024;
    float* ws = (float*)d_ws;
    unsigned short* eHi = (unsigned short*)d_ws;                    // 32MB
    unsigned short* eLo = eHi + (size_t)16384 * 1024;               // 32MB
    unsigned short* wHi = eLo + (size_t)16384 * 1024;               // 2MB
    unsigned short* wLo = wHi + (size_t)1024 * 1024;                // 2MB
    // 0. pre-split ems (128 tiles) and W (8 tiles) into swizzled blobs
    k_split<<<dim3(2048), 256, 0, stream>>>(ems, eHi, eLo);
    k_split<<<dim3(128), 256, 0, stream>>>(w_weight, wHi, wLo);
    // 1. proj (pure-DMA dbuf, XCD-pinned) -> proj planes in d_out
    k_proj_dma<<<dim3(1024), 512, 0, stream>>>(eHi, eLo, wHi, wLo, w_bias,
                                               hiP, loP);
    // 2. scores (f32) -> ws (R11-verified BM=512 structure)
    k_scores_mfma<<<dim3(512), 512, 0, stream>>>(hiP, loP, words, ws);
    if (ws_size >= ws_big) {
      // big-ws path: att blob lives in ws after scores; ctx -> d_out direct
      unsigned short* blob = (unsigned short*)((char*)d_ws + ws_need);
      k_softmax<<<dim3(16384), 256, 0, stream>>>(ws, mask, blob);
      k_pv<<<dim3(256), 512, 0, stream>>>(blob, words, (float*)d_out);
    } else {
      // small-ws path (verified rounds 9-11): blob in d_out, ctx via copy
      k_softmax<<<dim3(16384), 256, 0, stream>>>(ws, mask, (unsigned short*)d_out);
      k_pv<<<dim3(256), 512, 0, stream>>>((const unsigned short*)d_out, words, ws);
      k_copy<<<dim3(2048), 256, 0, stream>>>((const float4*)d_ws, (float4*)d_out);
    }
  } else {
    float* out = (float*)d_out;
    k_proj<<<dim3(128, 8), 256, 0, stream>>>(ems, w_weight, w_bias, out);
    k_scores<<<dim3(B_ * (E_ / 16)), 256, 0, stream>>>(words, mask, out);
    k_ctx<<<dim3(B_ * (E_ / 16)), 256, 0, stream>>>(words, out);
  }
}

// Round 14
// 422.023 us; speedup vs baseline: 1.3034x; 1.1686x over previous
//
#include <hip/hip_runtime.h>
#include <hip/hip_bf16.h>
#include <hip/hip_fp16.h>
#include <stdint.h>

#define B_  32
#define E_  512
#define WN  2048
#define D_  1024

typedef __attribute__((ext_vector_type(8))) short short8;
typedef __attribute__((ext_vector_type(8))) _Float16 half8;
typedef __attribute__((ext_vector_type(4))) float f32x4;

__device__ int g_mask_is_int;   // 1 if mask buffer is int32 per element, 0 if uint8

__device__ __forceinline__ unsigned short f2bf(float f) {
  unsigned int u = __float_as_uint(f);
  u += 0x7fffu + ((u >> 16) & 1u);   // round-to-nearest-even
  return (unsigned short)(u >> 16);
}
__device__ __forceinline__ float bf2f(unsigned short s) {
  return __uint_as_float(((unsigned int)s) << 16);
}
__device__ __forceinline__ unsigned short f2h(float f) {
  return __half_as_ushort(__float2half(f));   // RTNE f32->f16
}
__device__ __forceinline__ float ftanh(float x) {
  float e = __expf(2.0f * x);
  return 1.0f - 2.0f / (e + 1.0f);
}
// XOR-swizzled byte offset within a [rows][128B] LDS plane
__device__ __forceinline__ int swz(int row, int kb) {
  return row * 128 + (kb ^ ((row & 7) << 4));
}
// 64B-row swizzle: F(X) = X ^ ((X>>6 & 7) << 4)
__device__ __forceinline__ int swz64x(int row, int kb) {
  const int X = row * 64 + kb;
  return X ^ (((X >> 6) & 7) << 4);
}
__device__ __forceinline__ uint4 pack8(unsigned short a0, unsigned short a1,
                                       unsigned short a2, unsigned short a3,
                                       unsigned short a4, unsigned short a5,
                                       unsigned short a6, unsigned short a7) {
  uint4 v;
  v.x = (unsigned int)a0 | ((unsigned int)a1 << 16);
  v.y = (unsigned int)a2 | ((unsigned int)a3 << 16);
  v.z = (unsigned int)a4 | ((unsigned int)a5 << 16);
  v.w = (unsigned int)a6 | ((unsigned int)a7 << 16);
  return v;
}
// async global->LDS, 16B per lane; LDS dst is wave-uniform base (+lane*16 HW)
__device__ __forceinline__ void gload_lds16(const void* g, void* l) {
  __builtin_amdgcn_global_load_lds(
      (const __attribute__((address_space(1))) unsigned int*)g,
      (__attribute__((address_space(3))) unsigned int*)l, 16, 0, 0);
}

// ---------------------------------------------------------------------------
// K0: detect mask dtype. int32 0/1 data => bytes at offset %4 != 0 are all 0.
// ---------------------------------------------------------------------------
__global__ void k_detect(const unsigned char* __restrict__ m) {
  if (threadIdx.x == 0) {
    int nz = 0;
    for (int i = 0; i < 1024; ++i)
      if ((i & 3) && m[i]) nz++;
    g_mask_is_int = (nz == 0) ? 1 : 0;
  }
}

// ===========================================================================
// FAST PATH
// ===========================================================================

// ---------------------------------------------------------------------------
// k_split: src f32 -> hi/lo bf16 blobs in proj's swizzled LDS-image layout.
// (unchanged, verified round 11)
// ---------------------------------------------------------------------------
__global__ __launch_bounds__(256) void k_split(const float* __restrict__ src,
                                               unsigned short* __restrict__ hi,
                                               unsigned short* __restrict__ lo) {
#pragma unroll
  for (int j = 0; j < 4; ++j) {
    const size_t Lg = ((size_t)blockIdx.x * 1024 + j * 256 + threadIdx.x) * 16;
    const int Lloc = (int)(Lg & 16383);
    const int TS = (int)(Lg >> 14);
    const int T = TS >> 4, s = TS & 15;
    const int row = Lloc >> 7;
    const int kb = (Lloc & 127) ^ ((row & 7) << 4);
    const int kk = kb >> 1;
    const float* sp = src + ((size_t)(T * 128 + row)) * 1024 + s * 64 + kk;
    const f32x4 v0 = *(const f32x4*)(sp);
    const f32x4 v1 = *(const f32x4*)(sp + 4);
    unsigned short h[8], l[8];
#pragma unroll
    for (int i = 0; i < 4; ++i) {
      unsigned short hh = f2bf(v0[i]);
      h[i] = hh;
      l[i] = f2bf(v0[i] - bf2f(hh));
      unsigned short h2 = f2bf(v1[i]);
      h[4 + i] = h2;
      l[4 + i] = f2bf(v1[i] - bf2f(h2));
    }
    *(uint4*)((char*)hi + Lg) = pack8(h[0], h[1], h[2], h[3], h[4], h[5], h[6], h[7]);
    *(uint4*)((char*)lo + Lg) = pack8(l[0], l[1], l[2], l[3], l[4], l[5], l[6], l[7]);
  }
}

// ---------------------------------------------------------------------------
// k_proj_dma: proj = tanh(ems @ W^T + bias), split-bf16 3-term compute
// (verified r11-13), XCD-pinned. NEW epilogue: stores ONE f16 plane in the
// 32-k-stage swz64x blob layout (scores now consumes f16, not hi/lo bf16).
// ---------------------------------------------------------------------------
__global__ __launch_bounds__(512) void k_proj_dma(
    const unsigned short* __restrict__ eHi, const unsigned short* __restrict__ eLo,
    const unsigned short* __restrict__ wHi, const unsigned short* __restrict__ wLo,
    const float* __restrict__ bias,
    unsigned short* __restrict__ outF) {
  __shared__ uint4 lds4[8192];   // 128KB
  char* pAhi_c = (char*)lds4;
  char* pAlo_c = (char*)lds4 + 16384;
  char* pBhi_c = (char*)lds4 + 32768;
  char* pBlo_c = (char*)lds4 + 49152;
  char* pAhi_n = (char*)lds4 + 65536;
  char* pAlo_n = (char*)lds4 + 81920;
  char* pBhi_n = (char*)lds4 + 98304;
  char* pBlo_n = (char*)lds4 + 114688;

  const int g = blockIdx.x;
  const int xcd = g & 7;
  const int slot = g >> 3;               // 0..127
  const int Tm = xcd + 8 * (slot >> 3);  // 0..127, pinned to XCD
  const int Tn = slot & 7;               // 0..7
  const int t = threadIdx.x, l = t & 63, wv = t >> 6;
  const int wm2 = wv >> 1;   // 0..3 -> rows wm2*32
  const int wn2 = wv & 1;    // 0..1 -> cols wn2*64

  f32x4 acc[2][4];
#pragma unroll
  for (int i = 0; i < 2; ++i)
#pragma unroll
    for (int j = 0; j < 4; ++j) acc[i][j] = (f32x4){0.f, 0.f, 0.f, 0.f};

  auto dma_stage = [&](int s, char* pAh, char* pAl, char* pBh, char* pBl) {
#pragma unroll
    for (int j = 0; j < 2; ++j) {
      const size_t ga = (size_t)Tm * 262144 + (size_t)s * 16384 + j * 8192 +
                        wv * 1024 + l * 16;
      gload_lds16((const char*)eHi + ga, pAh + j * 8192 + wv * 1024);
      gload_lds16((const char*)eLo + ga, pAl + j * 8192 + wv * 1024);
      const size_t gb = (size_t)Tn * 262144 + (size_t)s * 16384 + j * 8192 +
                        wv * 1024 + l * 16;
      gload_lds16((const char*)wHi + gb, pBh + j * 8192 + wv * 1024);
      gload_lds16((const char*)wLo + gb, pBl + j * 8192 + wv * 1024);
    }
  };

  auto compute_stage = [&](const char* pAh, const char* pAl,
                           const char* pBh, const char* pBl) {
#pragma unroll
    for (int ks = 0; ks < 2; ++ks) {
      const int kb = ks * 64 + (l >> 4) * 16;
      short8 ah[2], al[2], bh[4], bl[4];
#pragma unroll
      for (int f = 0; f < 2; ++f) {
        const int o = swz(wm2 * 32 + f * 16 + (l & 15), kb);
        ah[f] = *(const short8*)(pAh + o);
        al[f] = *(const short8*)(pAl + o);
      }
#pragma unroll
      for (int f = 0; f < 4; ++f) {
        const int o = swz(wn2 * 64 + f * 16 + (l & 15), kb);
        bh[f] = *(const short8*)(pBh + o);
        bl[f] = *(const short8*)(pBl + o);
      }
#pragma unroll
      for (int fm = 0; fm < 2; ++fm)
#pragma unroll
        for (int fn = 0; fn < 4; ++fn) {
          acc[fm][fn] = __builtin_amdgcn_mfma_f32_16x16x32_bf16(ah[fm], bh[fn], acc[fm][fn], 0, 0, 0);
          acc[fm][fn] = __builtin_amdgcn_mfma_f32_16x16x32_bf16(al[fm], bh[fn], acc[fm][fn], 0, 0, 0);
          acc[fm][fn] = __builtin_amdgcn_mfma_f32_16x16x32_bf16(ah[fm], bl[fn], acc[fm][fn], 0, 0, 0);
        }
    }
  };

  dma_stage(0, pAhi_c, pAlo_c, pBhi_c, pBlo_c);
  __syncthreads();
  for (int s = 0; s < 16; ++s) {
    if (s < 15) dma_stage(s + 1, pAhi_n, pAlo_n, pBhi_n, pBlo_n);
    compute_stage(pAhi_c, pAlo_c, pBhi_c, pBlo_c);
    __syncthreads();
    char* x;
    x = pAhi_c; pAhi_c = pAhi_n; pAhi_n = x;
    x = pAlo_c; pAlo_c = pAlo_n; pAlo_n = x;
    x = pBhi_c; pBhi_c = pBhi_n; pBhi_n = x;
    x = pBlo_c; pBlo_c = pBlo_n; pBlo_n = x;
  }

  float bcol[4];
#pragma unroll
  for (int fn = 0; fn < 4; ++fn)
    bcol[fn] = bias[Tn * 128 + wn2 * 64 + fn * 16 + (l & 15)];
#pragma unroll
  for (int fm = 0; fm < 2; ++fm)
#pragma unroll
    for (int fn = 0; fn < 4; ++fn)
#pragma unroll
      for (int q = 0; q < 4; ++q)
        acc[fm][fn][q] = ftanh(acc[fm][fn][q] + bcol[fn]);

  // epilogue: LDS transpose (f16 bits) then 32-k-stage blob store (one plane)
  unsigned short* ldsT = (unsigned short*)lds4;  // [128][136]
  __syncthreads();
#pragma unroll
  for (int fm = 0; fm < 2; ++fm)
#pragma unroll
    for (int fn = 0; fn < 4; ++fn)
#pragma unroll
      for (int q = 0; q < 4; ++q) {
        const int rl = wm2 * 32 + fm * 16 + (l >> 4) * 4 + q;
        const int cl = wn2 * 64 + fn * 16 + (l & 15);
        ldsT[rl * 136 + cl] = f2h(acc[fm][fn][q]);
      }
  __syncthreads();
#pragma unroll
  for (int sb = 0; sb < 4; ++sb) {
    const int L = t * 16;
    const int x6 = ((L >> 6) ^ (L >> 8)) & 1;
    const int x5 = ((L >> 5) ^ (L >> 7)) & 1;
    const int x4 = ((L >> 4) ^ (L >> 6) ^ (L >> 8)) & 1;
    const int X = (L & ~0x70) | (x6 << 6) | (x5 << 5) | (x4 << 4);
    const int row = X >> 6;
    const int cl = sb * 32 + ((X & 63) >> 1);
    uint4 v = *(const uint4*)(ldsT + row * 136 + cl);
    *(uint4*)((char*)outF + (size_t)Tm * 262144 +
              (size_t)(Tn * 4 + sb) * 8192 + L) = v;
  }
}

// ---------------------------------------------------------------------------
// k_scores_mfma v6: scores = proj @ words^T via SINGLE f16 MFMA (inputs
// accurate to 2^-11 -> score err ~0.01, analysis in round log). Structure =
// R11-verified v3 skeleton: BM=512 x BN=128, BK=32, dbuf, 1 barrier/stage,
// A via DMA from f16 blob. LDS 80KB (was 160): A dbuf 64K + B dbuf 16K.
// ---------------------------------------------------------------------------
__global__ __launch_bounds__(512) void k_scores_mfma(
    const unsigned short* __restrict__ pF,
    const float* __restrict__ words, float* __restrict__ sc) {
  __shared__ uint4 lds4[5120];  // 80KB
  char* pA_c = (char*)lds4;              // 32KB: [4 tiles][8KB swz64x]
  char* pA_n = (char*)lds4 + 32768;
  char* pB_c = (char*)lds4 + 65536;      // 8KB: [128 n][64B swz64x]
  char* pB_n = (char*)lds4 + 73728;

  const int g = blockIdx.x;
  const int b = (g & 7) + 8 * (g >> 7);   // XCD-pinned batch (bijective)
  const int n0 = ((g >> 3) & 15) * 128;

  const int t = threadIdx.x, l = t & 63, wv = t >> 6;
  const int wm4 = wv >> 1;    // 0..3 -> m tile (128 rows each)
  const int wn2 = wv & 1;     // 0..1 -> n base local = wn2*64

  f32x4 acc[8][4];
#pragma unroll
  for (int i = 0; i < 8; ++i)
#pragma unroll
    for (int j = 0; j < 4; ++j) acc[i][j] = (f32x4){0.f, 0.f, 0.f, 0.f};

  f32x4 br0, br1;
  const int bn = t >> 2;          // B n-row 0..127
  const int bc = (t & 3) * 8;     // f32 col base within 32

  auto dma_A = [&](int s, char* pA) {
#pragma unroll
    for (int j = 0; j < 4; ++j) {
      const size_t gb = (size_t)(b * 4 + j) * 262144 + (size_t)s * 8192 +
                        wv * 1024 + l * 16;
      gload_lds16((const char*)pF + gb, pA + j * 8192 + wv * 1024);
    }
  };

  auto load_B = [&](int s) {
    const float* bs = words + (size_t)b * WN * D_ + (size_t)(n0 + bn) * 1024 +
                      s * 32 + bc;
    br0 = *(const f32x4*)(bs);
    br1 = *(const f32x4*)(bs + 4);
  };

  auto write_B = [&](char* pB) {
    unsigned short hB[8];
#pragma unroll
    for (int j = 0; j < 4; ++j) {
      hB[j] = f2h(br0[j]);
      hB[4 + j] = f2h(br1[j]);
    }
    const int o = swz64x(bn, (t & 3) * 16);
    *(uint4*)(pB + o) = pack8(hB[0], hB[1], hB[2], hB[3], hB[4], hB[5], hB[6], hB[7]);
  };

  auto compute_stage = [&](const char* pA, const char* pB) {
    const int kb0 = (l >> 4) * 16;
    half8 bf[4];
#pragma unroll
    for (int f = 0; f < 4; ++f) {
      const int n = wn2 * 64 + f * 16 + (l & 15);
      bf[f] = *(const half8*)(pB + swz64x(n, kb0));
    }
#pragma unroll
    for (int fm = 0; fm < 8; ++fm) {
      const int row = fm * 16 + (l & 15);
      const half8 a = *(const half8*)(pA + wm4 * 8192 + swz64x(row, kb0));
#pragma unroll
      for (int fn = 0; fn < 4; ++fn)
        acc[fm][fn] = __builtin_amdgcn_mfma_f32_16x16x32_f16(a, bf[fn], acc[fm][fn], 0, 0, 0);
    }
  };

  // prologue
  load_B(0);
  dma_A(0, pA_c);
  write_B(pB_c);
  __syncthreads();

  for (int s = 0; s < 32; ++s) {
    if (s < 31) {
      load_B(s + 1);
      dma_A(s + 1, pA_n);
    }
    compute_stage(pA_c, pB_c);
    if (s < 31) write_B(pB_n);
    __syncthreads();  // drains DMA (vmcnt) + ds_writes (lgkm)
    char* x;
    x = pA_c; pA_c = pA_n; pA_n = x;
    x = pB_c; pB_c = pB_n; pB_n = x;
  }

  // store f32 scores
#pragma unroll
  for (int fm = 0; fm < 8; ++fm)
#pragma unroll
    for (int fn = 0; fn < 4; ++fn)
#pragma unroll
      for (int q = 0; q < 4; ++q) {
        const int row = wm4 * 128 + fm * 16 + (l >> 4) * 4 + q;
        const int col = n0 + wn2 * 64 + fn * 16 + (l & 15);
        sc[((size_t)b * 512 + row) * 2048 + col] = acc[fm][fn][q];
      }
}

// ---------------------------------------------------------------------------
// k_softmax: unchanged (verified round 9/10). blob pointer is a parameter.
// ---------------------------------------------------------------------------
__global__ __launch_bounds__(256) void k_softmax(const float* __restrict__ ws,
                                                 const void* __restrict__ mask,
                                                 unsigned short* __restrict__ blob) {
  __shared__ float red[8];
  const int row = blockIdx.x;
  const int t = threadIdx.x;
  const int wave = t >> 6;
  const float* rp = ws + (size_t)row * 2048;
  float v[8];
  {
    f32x4 v0 = *(const f32x4*)(rp + t * 8);
    f32x4 v1 = *(const f32x4*)(rp + t * 8 + 4);
#pragma unroll
    for (int i = 0; i < 4; ++i) { v[i] = v0[i]; v[4 + i] = v1[i]; }
  }
  if (g_mask_is_int) {
    const int* mp = (const int*)mask + (size_t)row * 2048 + t * 8;
    const int4 m0 = *(const int4*)mp;
    const int4 m1 = *(const int4*)(mp + 4);
    if (m0.x) v[0] = -INFINITY;
    if (m0.y) v[1] = -INFINITY;
    if (m0.z) v[2] = -INFINITY;
    if (m0.w) v[3] = -INFINITY;
    if (m1.x) v[4] = -INFINITY;
    if (m1.y) v[5] = -INFINITY;
    if (m1.z) v[6] = -INFINITY;
    if (m1.w) v[7] = -INFINITY;
  } else {
    const unsigned char* mp = (const unsigned char*)mask + (size_t)row * 2048 + t * 8;
    const uchar4 m0 = *(const uchar4*)mp;
    const uchar4 m1 = *(const uchar4*)(mp + 4);
    if (m0.x) v[0] = -INFINITY;
    if (m0.y) v[1] = -INFINITY;
    if (m0.z) v[2] = -INFINITY;
    if (m0.w) v[3] = -INFINITY;
    if (m1.x) v[4] = -INFINITY;
    if (m1.y) v[5] = -INFINITY;
    if (m1.z) v[6] = -INFINITY;
    if (m1.w) v[7] = -INFINITY;
  }
  float mx = v[0];
#pragma unroll
  for (int i = 1; i < 8; ++i) mx = fmaxf(mx, v[i]);
#pragma unroll
  for (int off = 32; off > 0; off >>= 1) mx = fmaxf(mx, __shfl_xor(mx, off));
  if ((t & 63) == 0) red[wave] = mx;
  __syncthreads();
  mx = fmaxf(fmaxf(red[0], red[1]), fmaxf(red[2], red[3]));
  float e[8];
  float sum = 0.0f;
#pragma unroll
  for (int i = 0; i < 8; ++i) {
    e[i] = __expf(v[i] - mx);
    sum += e[i];
  }
#pragma unroll
  for (int off = 32; off > 0; off >>= 1) sum += __shfl_xor(sum, off);
  if ((t & 63) == 0) red[4 + wave] = sum;
  __syncthreads();
  const float tot = (red[4] + red[5]) + (red[6] + red[7]);
  const float rinv = 1.0f / tot;

  const int b = row >> 9, ee = row & 511;
  const uint4 pk = pack8(f2bf(e[0] * rinv), f2bf(e[1] * rinv),
                         f2bf(e[2] * rinv), f2bf(e[3] * rinv),
                         f2bf(e[4] * rinv), f2bf(e[5] * rinv),
                         f2bf(e[6] * rinv), f2bf(e[7] * rinv));
  char* dst = (char*)blob + (size_t)b * 2097152 + (size_t)(t >> 3) * 65536 +
              ee * 128 + (((t & 7) * 16) ^ ((ee & 7) << 4));
  *(uint4*)dst = pk;
}

// ---------------------------------------------------------------------------
// k_pv: ctx = att @ words (unchanged, verified round 9).
// ---------------------------------------------------------------------------
__global__ __launch_bounds__(512) void k_pv(
    const unsigned short* __restrict__ blob, const float* __restrict__ words,
    float* __restrict__ ctx) {
  __shared__ uint4 lds4[10240];           // 160KB
  char* pAc = (char*)lds4;
  char* pAn = (char*)lds4 + 65536;
  char* pBc = (char*)lds4 + 131072;
  char* pBn = (char*)lds4 + 147456;

  const int g = blockIdx.x;
  const int b = (g & 7) + 8 * (g >> 6);   // XCD-pinned batch
  const int wt = (g >> 3) & 7;
  const int w0 = wt * 128;

  const int t = threadIdx.x, l = t & 63, wv = t >> 6;
  const int wm4 = wv >> 1;
  const int wn2 = wv & 1;

  const char* blobB = (const char*)blob + (size_t)b * 2097152;

  f32x4 acc[8][4];
#pragma unroll
  for (int i = 0; i < 8; ++i)
#pragma unroll
    for (int j = 0; j < 4; ++j) acc[i][j] = (f32x4){0.f, 0.f, 0.f, 0.f};

  f32x4 bv0a, bv0b, bv1a, bv1b;
  const int np2 = (t & 31) * 2;
  const int wc = (t >> 5) * 8;

  auto dma_A = [&](int s, char* pA) {
    const char* gp = blobB + (size_t)s * 65536 + wv * 8192 + l * 16;
#pragma unroll
    for (int j = 0; j < 8; ++j)
      gload_lds16(gp + j * 1024, pA + wv * 8192 + j * 1024);
  };

  auto load_B = [&](int s) {
    const float* wp = words + (size_t)b * WN * D_ +
                      (size_t)(s * 64 + np2) * 1024 + w0 + wc;
    bv0a = *(const f32x4*)(wp);
    bv0b = *(const f32x4*)(wp + 4);
    bv1a = *(const f32x4*)(wp + 1024);
    bv1b = *(const f32x4*)(wp + 1028);
  };

  auto write_B = [&](char* pB) {
#pragma unroll
    for (int i = 0; i < 8; ++i) {
      const int w = wc + i;
      const float x0 = (i < 4) ? bv0a[i & 3] : bv0b[i & 3];
      const float x1 = (i < 4) ? bv1a[i & 3] : bv1b[i & 3];
      const unsigned int pk =
          (unsigned int)f2bf(x0) | ((unsigned int)f2bf(x1) << 16);
      *(unsigned int*)(pB + w * 128 + ((np2 * 2) ^ ((w & 7) << 4))) = pk;
    }
  };

  auto compute_stage = [&](const char* pA, const char* pB) {
#pragma unroll
    for (int ks = 0; ks < 2; ++ks) {
      short8 a[8];
      const int kb = ks * 64 + (l >> 4) * 16;
#pragma unroll
      for (int f = 0; f < 8; ++f) {
        const int row = wm4 * 128 + f * 16 + (l & 15);
        a[f] = *(const short8*)(pA + swz(row, kb));
      }
      short8 bb[4];
#pragma unroll
      for (int f = 0; f < 4; ++f) {
        const int row = wn2 * 64 + f * 16 + (l & 15);
        bb[f] = *(const short8*)(pB + swz(row, kb));
      }
#pragma unroll
      for (int fm = 0; fm < 8; ++fm)
#pragma unroll
        for (int fn = 0; fn < 4; ++fn)
          acc[fm][fn] = __builtin_amdgcn_mfma_f32_16x16x32_bf16(a[fm], bb[fn], acc[fm][fn], 0, 0, 0);
    }
  };

  load_B(0);
  dma_A(0, pAc);
  write_B(pBc);
  __syncthreads();

  for (int s = 0; s < 32; ++s) {
    if (s < 31) {
      load_B(s + 1);
      dma_A(s + 1, pAn);
    }
    compute_stage(pAc, pBc);
    if (s < 31) write_B(pBn);
    __syncthreads();
    char* t1 = pAc; pAc = pAn; pAn = t1;
    char* t2 = pBc; pBc = pBn; pBn = t2;
  }

#pragma unroll
  for (int fm = 0; fm < 8; ++fm)
#pragma unroll
    for (int fn = 0; fn < 4; ++fn)
#pragma unroll
      for (int q = 0; q < 4; ++q) {
        const int row = wm4 * 128 + fm * 16 + (l >> 4) * 4 + q;
        const int col = w0 + wn2 * 64 + fn * 16 + (l & 15);
        ctx[((size_t)b * 512 + row) * 1024 + col] = acc[fm][fn][q];
      }
}

// ---------------------------------------------------------------------------
// k_copy: ctx (ws) -> d_out, float4 grid-stride. (small-ws fallback only)
// ---------------------------------------------------------------------------
__global__ __launch_bounds__(256) void k_copy(const float4* __restrict__ src,
                                              float4* __restrict__ dst) {
  const int n4 = 16384 * 1024 / 4;
  int i = blockIdx.x * 256 + threadIdx.x;
  const int stride = gridDim.x * 256;
  for (; i < n4; i += stride) dst[i] = src[i];
}

// ===========================================================================
// FALLBACK PATH (round-2 verified kernels; used if ws too small)
// ===========================================================================
__global__ __launch_bounds__(256, 4) void k_proj(const float* __restrict__ A,
                                                 const float* __restrict__ W,
                                                 const float* __restrict__ bias,
                                                 float* __restrict__ out) {
  __shared__ float As[32][132];
  __shared__ float Bs[32][132];
  const int t = threadIdx.x;
  const int m0 = blockIdx.x * 128;
  const int n0 = blockIdx.y * 128;
  const int tm = t >> 4;
  const int tn = t & 15;
  const int lrow = t >> 1;
  const int lk = (t & 1) * 16;

  float acc[8][8];
#pragma unroll
  for (int i = 0; i < 8; ++i)
#pragma unroll
    for (int j = 0; j < 8; ++j) acc[i][j] = 0.0f;

  const float* Arow = A + (size_t)(m0 + lrow) * D_ + lk;
  const float* Wrow = W + (size_t)(n0 + lrow) * D_ + lk;

  for (int k0 = 0; k0 < D_; k0 += 32) {
    __syncthreads();
#pragma unroll
    for (int j = 0; j < 4; ++j) {
      const float4 va = *(const float4*)(Arow + k0 + j * 4);
      As[lk + j * 4 + 0][lrow] = va.x;
      As[lk + j * 4 + 1][lrow] = va.y;
      As[lk + j * 4 + 2][lrow] = va.z;
      As[lk + j * 4 + 3][lrow] = va.w;
      const float4 vb = *(const float4*)(Wrow + k0 + j * 4);
      Bs[lk + j * 4 + 0][lrow] = vb.x;
      Bs[lk + j * 4 + 1][lrow] = vb.y;
      Bs[lk + j * 4 + 2][lrow] = vb.z;
      Bs[lk + j * 4 + 3][lrow] = vb.w;
    }
    __syncthreads();
#pragma unroll 8
    for (int k = 0; k < 32; ++k) {
      float a[8], bb[8];
      *(float4*)(a + 0) = *(const float4*)&As[k][tm * 4];
      *(float4*)(a + 4) = *(const float4*)&As[k][tm * 4 + 64];
      *(float4*)(bb + 0) = *(const float4*)&Bs[k][tn * 4];
      *(float4*)(bb + 4) = *(const float4*)&Bs[k][tn * 4 + 64];
#pragma unroll
      for (int i = 0; i < 8; ++i)
#pragma unroll
        for (int j = 0; j < 8; ++j) acc[i][j] = fmaf(a[i], bb[j], acc[i][j]);
    }
  }

  float bn[8];
#pragma unroll
  for (int j = 0; j < 8; ++j) bn[j] = bias[n0 + tn * 4 + (j & 3) + (j >> 2) * 64];
#pragma unroll
  for (int i = 0; i < 8; ++i) {
    const int m = m0 + tm * 4 + (i & 3) + (i >> 2) * 64;
    float4 v0, v1;
    v0.x = tanhf(acc[i][0] + bn[0]);
    v0.y = tanhf(acc[i][1] + bn[1]);
    v0.z = tanhf(acc[i][2] + bn[2]);
    v0.w = tanhf(acc[i][3] + bn[3]);
    v1.x = tanhf(acc[i][4] + bn[4]);
    v1.y = tanhf(acc[i][5] + bn[5]);
    v1.z = tanhf(acc[i][6] + bn[6]);
    v1.w = tanhf(acc[i][7] + bn[7]);
    *(float4*)(out + (size_t)m * D_ + n0 + tn * 4) = v0;
    *(float4*)(out + (size_t)m * D_ + n0 + tn * 4 + 64) = v1;
  }
}

__global__ __launch_bounds__(256) void k_scores(const float* __restrict__ words,
                                                const void* __restrict__ mask,
                                                float* __restrict__ pa) {
  __shared__ float Pt[1024][18];
  __shared__ float Ws[64][268];
  const int t = threadIdx.x;
  const int b = blockIdx.x >> 5;
  const int et = blockIdx.x & 31;
  const int e0 = et * 16;
  const int eg = t >> 5;
  const int ng = t & 31;
  const int mask_is_int = g_mask_is_int;
  const float* wbase = words + (size_t)b * WN * D_;

  {
    const int row = t >> 4;
    const int dj = (t & 15) * 4;
    const float* pr = pa + (size_t)(b * E_ + e0 + row) * D_;
#pragma unroll
    for (int rr = 0; rr < 16; ++rr) {
      const float4 v = *(const float4*)(pr + dj + rr * 64);
      Pt[dj + rr * 64 + 0][row] = v.x;
      Pt[dj + rr * 64 + 1][row] = v.y;
      Pt[dj + rr * 64 + 2][row] = v.z;
      Pt[dj + rr * 64 + 3][row] = v.w;
    }
  }

  float s[2][64];
#pragma unroll
  for (int i = 0; i < 2; ++i)
#pragma unroll
    for (int u = 0; u < 64; ++u) s[i][u] = 0.0f;

  const int nl = t >> 3;
  const int d4 = (t & 7) * 4;

  for (int dk = 0; dk < D_; dk += 64) {
#pragma unroll
    for (int nb = 0; nb < 8; ++nb) {
      __syncthreads();
#pragma unroll
      for (int rr = 0; rr < 8; ++rr) {
#pragma unroll
        for (int hh = 0; hh < 2; ++hh) {
          const int n = nl + rr * 32;
          const int d = d4 + hh * 32;
          const float4 v = *(const float4*)(wbase + (size_t)(nb * 256 + n) * D_ + dk + d);
          Ws[d + 0][n] = v.x;
          Ws[d + 1][n] = v.y;
          Ws[d + 2][n] = v.z;
          Ws[d + 3][n] = v.w;
        }
      }
      __syncthreads();
#pragma unroll 2
      for (int k = 0; k < 64; ++k) {
        const float2 a = *(const float2*)&Pt[dk + k][eg * 2];
        const float4 b0 = *(const float4*)&Ws[k][ng * 4];
        const float4 b1 = *(const float4*)&Ws[k][128 + ng * 4];
        const float aa[2] = {a.x, a.y};
        const float bb[8] = {b0.x, b0.y, b0.z, b0.w, b1.x, b1.y, b1.z, b1.w};
#pragma unroll
        for (int i = 0; i < 2; ++i)
#pragma unroll
          for (int u = 0; u < 8; ++u)
            s[i][nb * 8 + u] = fmaf(aa[i], bb[u], s[i][nb * 8 + u]);
      }
    }
  }

#pragma unroll
  for (int i = 0; i < 2; ++i) {
    const int e = e0 + eg * 2 + i;
#pragma unroll
    for (int nb = 0; nb < 8; ++nb)
#pragma unroll
      for (int q = 0; q < 2; ++q) {
        const size_t moff = (size_t)(b * E_ + e) * WN + nb * 256 + q * 128 + ng * 4;
        int mx, my, mz, mw;
        if (mask_is_int) {
          const int4 mv = *(const int4*)((const int*)mask + moff);
          mx = mv.x; my = mv.y; mz = mv.z; mw = mv.w;
        } else {
          const uchar4 mv = *(const uchar4*)((const unsigned char*)mask + moff);
          mx = mv.x; my = mv.y; mz = mv.z; mw = mv.w;
        }
        if (mx) s[i][nb * 8 + q * 4 + 0] = -1e30f;
        if (my) s[i][nb * 8 + q * 4 + 1] = -1e30f;
        if (mz) s[i][nb * 8 + q * 4 + 2] = -1e30f;
        if (mw) s[i][nb * 8 + q * 4 + 3] = -1e30f;
      }
    float m = -1e30f;
#pragma unroll
    for (int u = 0; u < 64; ++u) m = fmaxf(m, s[i][u]);
#pragma unroll
    for (int off = 16; off > 0; off >>= 1) m = fmaxf(m, __shfl_xor(m, off));
    float sum = 0.0f;
#pragma unroll
    for (int u = 0; u < 64; ++u) {
      const float p = __expf(s[i][u] - m);
      s[i][u] = p;
      sum += p;
    }
#pragma unroll
    for (int off = 16; off > 0; off >>= 1) sum += __shfl_xor(sum, off);
    const float rinv = 1.0f / sum;

    unsigned short* ar2 = (unsigned short*)(pa + (size_t)(b * E_ + e) * WN / 2);
#pragma unroll
    for (int nb = 0; nb < 8; ++nb)
#pragma unroll
      for (int q = 0; q < 2; ++q) {
        ushort4 pk;
        pk.x = f2bf(s[i][nb * 8 + q * 4 + 0] * rinv);
        pk.y = f2bf(s[i][nb * 8 + q * 4 + 1] * rinv);
        pk.z = f2bf(s[i][nb * 8 + q * 4 + 2] * rinv);
        pk.w = f2bf(s[i][nb * 8 + q * 4 + 3] * rinv);
        *(ushort4*)(ar2 + nb * 256 + q * 128 + ng * 4) = pk;
      }
  }
}

__global__ __launch_bounds__(256) void k_ctx(const float* __restrict__ words,
                                             float* __restrict__ pa) {
  __shared__ unsigned short att_s[16][2048];
  __shared__ unsigned short Wb[256][132];
  const int t = threadIdx.x;
  const int b = blockIdx.x >> 5;
  const int et = blockIdx.x & 31;
  const int e0 = et * 16;
  const int eg = t >> 5;
  const int wg = t & 31;
  const float* wbase = words + (size_t)b * WN * D_;

  {
    const int row = t >> 4;
    const int cj = t & 15;
    const uint4* pr = (const uint4*)(pa + (size_t)(b * E_ + e0 + row) * D_);
#pragma unroll
    for (int rr = 0; rr < 16; ++rr) {
      const int c = cj + rr * 16;
      const uint4 v = pr[c];
      *(uint4*)&att_s[row][c * 8] = v;
    }
  }

  float acc[2][32];
#pragma unroll
  for (int i = 0; i < 2; ++i)
#pragma unroll
    for (int u = 0; u < 32; ++u) acc[i][u] = 0.0f;

  const int nlg = t >> 5;
  const int w4 = (t & 31) * 4;

  for (int nb = 0; nb < 8; ++nb) {
#pragma unroll
    for (int q = 0; q < 8; ++q) {
      __syncthreads();
#pragma unroll
      for (int rr = 0; rr < 32; ++rr) {
        const int n = nlg + rr * 8;
        const float4 v = *(const float4*)(wbase + (size_t)(nb * 256 + n) * D_ + q * 128 + w4);
        ushort4 pk;
        pk.x = f2bf(v.x);
        pk.y = f2bf(v.y);
        pk.z = f2bf(v.z);
        pk.w = f2bf(v.w);
        *(ushort4*)&Wb[n][w4] = pk;
      }
      __syncthreads();
#pragma unroll 4
      for (int n2 = 0; n2 < 128; ++n2) {
        const int n = n2 * 2;
        const ushort4 r0 = *(const ushort4*)&Wb[n][wg * 4];
        const ushort4 r1 = *(const ushort4*)&Wb[n + 1][wg * 4];
        const float w0[4] = {bf2f(r0.x), bf2f(r0.y), bf2f(r0.z), bf2f(r0.w)};
        const float w1[4] = {bf2f(r1.x), bf2f(r1.y), bf2f(r1.z), bf2f(r1.w)};
#pragma unroll
        for (int i = 0; i < 2; ++i) {
          const unsigned int aw = *(const unsigned int*)&att_s[eg * 2 + i][nb * 256 + n];
          const float a0 = bf2f((unsigned short)(aw & 0xffffu));
          const float a1 = bf2f((unsigned short)(aw >> 16));
#pragma unroll
          for (int j = 0; j < 4; ++j)
            acc[i][q * 4 + j] = fmaf(a0, w0[j], fmaf(a1, w1[j], acc[i][q * 4 + j]));
        }
      }
    }
  }

#pragma unroll
  for (int i = 0; i < 2; ++i) {
    float* orow = pa + (size_t)(b * E_ + e0 + eg * 2 + i) * D_;
#pragma unroll
    for (int q = 0; q < 8; ++q) {
      float4 v;
      v.x = acc[i][q * 4 + 0];
      v.y = acc[i][q * 4 + 1];
      v.z = acc[i][q * 4 + 2];
      v.w = acc[i][q * 4 + 3];
      *(float4*)(orow + q * 128 + wg * 4) = v;
    }
  }
}

extern "C" void kernel_launch(void* const* d_in, const int* in_sizes, int n_in,
                              void* d_out, int out_size, void* d_ws, size_t ws_size,
                              hipStream_t stream) {
  const float* ems = (const float*)d_in[0];
  const float* words = (const float*)d_in[1];
  const void* mask = d_in[2];
  const float* w_weight = (const float*)d_in[3];
  const float* w_bias = (const float*)d_in[4];

  k_detect<<<1, 64, 0, stream>>>((const unsigned char*)mask);

  const size_t ws_need = (size_t)16384 * 2048 * 4;          // 128 MB
  const size_t ws_big = ws_need + (size_t)32 * 2097152;     // +64 MB blob
  if (ws_size >= ws_need) {
    unsigned short* pF = (unsigned short*)d_out;    // 32MB f16 proj blob
    float* ws = (float*)d_ws;
    unsigned short* eHi = (unsigned short*)d_ws;                    // 32MB
    unsigned short* eLo = eHi + (size_t)16384 * 1024;               // 32MB
    unsigned short* wHi = eLo + (size_t)16384 * 1024;               // 2MB
    unsigned short* wLo = wHi + (size_t)1024 * 1024;                // 2MB
    // 0. pre-split ems (128 tiles) and W (8 tiles) into swizzled blobs
    k_split<<<dim3(2048), 256, 0, stream>>>(ems, eHi, eLo);
    k_split<<<dim3(128), 256, 0, stream>>>(w_weight, wHi, wLo);
    // 1. proj (split-bf16 compute, XCD-pinned) -> f16 plane blob in d_out
    k_proj_dma<<<dim3(1024), 512, 0, stream>>>(eHi, eLo, wHi, wLo, w_bias, pF);
    // 2. scores (single f16 MFMA) -> ws
    k_scores_mfma<<<dim3(512), 512, 0, stream>>>(pF, words, ws);
    if (ws_size >= ws_big) {
      // big-ws path: att blob lives in ws after scores; ctx -> d_out direct
      unsigned short* blob = (unsigned short*)((char*)d_ws + ws_need);
      k_softmax<<<dim3(16384), 256, 0, stream>>>(ws, mask, blob);
      k_pv<<<dim3(256), 512, 0, stream>>>(blob, words, (float*)d_out);
    } else {
      // small-ws path (verified rounds 9-11): blob in d_out, ctx via copy
      k_softmax<<<dim3(16384), 256, 0, stream>>>(ws, mask, (unsigned short*)d_out);
      k_pv<<<dim3(256), 512, 0, stream>>>((const unsigned short*)d_out, words, ws);
      k_copy<<<dim3(2048), 256, 0, stream>>>((const float4*)d_ws, (float4*)d_out);
    }
  } else {
    float* out = (float*)d_out;
    k_proj<<<dim3(128, 8), 256, 0, stream>>>(ems, w_weight, w_bias, out);
    k_scores<<<dim3(B_ * (E_ / 16)), 256, 0, stream>>>(words, mask, out);
    k_ctx<<<dim3(B_ * (E_ / 16)), 256, 0, stream>>>(words, out);
  }
}

// Round 15
// 366.473 us; speedup vs baseline: 1.5010x; 1.1516x over previous
//
#include <hip/hip_runtime.h>
#include <hip/hip_bf16.h>
#include <hip/hip_fp16.h>
#include <stdint.h>

#define B_  32
#define E_  512
#define WN  2048
#define D_  1024

typedef __attribute__((ext_vector_type(8))) short short8;
typedef __attribute__((ext_vector_type(8))) _Float16 half8;
typedef __attribute__((ext_vector_type(4))) float f32x4;

__device__ int g_mask_is_int;   // 1 if mask buffer is int32 per element, 0 if uint8

__device__ __forceinline__ unsigned short f2bf(float f) {
  unsigned int u = __float_as_uint(f);
  u += 0x7fffu + ((u >> 16) & 1u);   // round-to-nearest-even
  return (unsigned short)(u >> 16);
}
__device__ __forceinline__ float bf2f(unsigned short s) {
  return __uint_as_float(((unsigned int)s) << 16);
}
__device__ __forceinline__ unsigned short f2h(float f) {
  return __half_as_ushort(__float2half(f));   // RTNE f32->f16
}
__device__ __forceinline__ float ftanh(float x) {
  float e = __expf(2.0f * x);
  return 1.0f - 2.0f / (e + 1.0f);
}
// XOR-swizzled byte offset within a [rows][128B] LDS plane
__device__ __forceinline__ int swz(int row, int kb) {
  return row * 128 + (kb ^ ((row & 7) << 4));
}
// 64B-row swizzle: F(X) = X ^ ((X>>6 & 7) << 4)
__device__ __forceinline__ int swz64x(int row, int kb) {
  const int X = row * 64 + kb;
  return X ^ (((X >> 6) & 7) << 4);
}
__device__ __forceinline__ uint4 pack8(unsigned short a0, unsigned short a1,
                                       unsigned short a2, unsigned short a3,
                                       unsigned short a4, unsigned short a5,
                                       unsigned short a6, unsigned short a7) {
  uint4 v;
  v.x = (unsigned int)a0 | ((unsigned int)a1 << 16);
  v.y = (unsigned int)a2 | ((unsigned int)a3 << 16);
  v.z = (unsigned int)a4 | ((unsigned int)a5 << 16);
  v.w = (unsigned int)a6 | ((unsigned int)a7 << 16);
  return v;
}
// async global->LDS, 16B per lane; LDS dst is wave-uniform base (+lane*16 HW)
__device__ __forceinline__ void gload_lds16(const void* g, void* l) {
  __builtin_amdgcn_global_load_lds(
      (const __attribute__((address_space(1))) unsigned int*)g,
      (__attribute__((address_space(3))) unsigned int*)l, 16, 0, 0);
}

// ---------------------------------------------------------------------------
// K0: detect mask dtype. int32 0/1 data => bytes at offset %4 != 0 are all 0.
// ---------------------------------------------------------------------------
__global__ void k_detect(const unsigned char* __restrict__ m) {
  if (threadIdx.x == 0) {
    int nz = 0;
    for (int i = 0; i < 1024; ++i)
      if ((i & 3) && m[i]) nz++;
    g_mask_is_int = (nz == 0) ? 1 : 0;
  }
}

// ===========================================================================
// FAST PATH
// ===========================================================================

// ---------------------------------------------------------------------------
// k_split_h: src f32 -> ONE f16 blob in proj's swizzled LDS-image layout
// (same addressing as verified k_split, single plane, f2h convert).
// ---------------------------------------------------------------------------
__global__ __launch_bounds__(256) void k_split_h(const float* __restrict__ src,
                                                 unsigned short* __restrict__ out) {
#pragma unroll
  for (int j = 0; j < 4; ++j) {
    const size_t Lg = ((size_t)blockIdx.x * 1024 + j * 256 + threadIdx.x) * 16;
    const int Lloc = (int)(Lg & 16383);
    const int TS = (int)(Lg >> 14);
    const int T = TS >> 4, s = TS & 15;
    const int row = Lloc >> 7;
    const int kb = (Lloc & 127) ^ ((row & 7) << 4);
    const int kk = kb >> 1;
    const float* sp = src + ((size_t)(T * 128 + row)) * 1024 + s * 64 + kk;
    const f32x4 v0 = *(const f32x4*)(sp);
    const f32x4 v1 = *(const f32x4*)(sp + 4);
    *(uint4*)((char*)out + Lg) =
        pack8(f2h(v0[0]), f2h(v0[1]), f2h(v0[2]), f2h(v0[3]),
              f2h(v1[0]), f2h(v1[1]), f2h(v1[2]), f2h(v1[3]));
  }
}

// ---------------------------------------------------------------------------
// k_proj_dma v2: proj = tanh(ems @ W^T + bias) via SINGLE f16 MFMA.
// Inputs: f16 blobs (ems, W). LDS 64KB dbuf (A 16K + B 16K per buf) ->
// 2 blocks/CU. XCD-pinned. Epilogue: f16 plane blob store (verified r14).
// ---------------------------------------------------------------------------
__global__ __launch_bounds__(512) void k_proj_dma(
    const unsigned short* __restrict__ eF, const unsigned short* __restrict__ wF,
    const float* __restrict__ bias,
    unsigned short* __restrict__ outF) {
  __shared__ uint4 lds4[4096];   // 64KB
  char* pA_c = (char*)lds4;
  char* pB_c = (char*)lds4 + 16384;
  char* pA_n = (char*)lds4 + 32768;
  char* pB_n = (char*)lds4 + 49152;

  const int g = blockIdx.x;
  const int xcd = g & 7;
  const int slot = g >> 3;               // 0..127
  const int Tm = xcd + 8 * (slot >> 3);  // 0..127, pinned to XCD
  const int Tn = slot & 7;               // 0..7
  const int t = threadIdx.x, l = t & 63, wv = t >> 6;
  const int wm2 = wv >> 1;   // 0..3 -> rows wm2*32
  const int wn2 = wv & 1;    // 0..1 -> cols wn2*64

  f32x4 acc[2][4];
#pragma unroll
  for (int i = 0; i < 2; ++i)
#pragma unroll
    for (int j = 0; j < 4; ++j) acc[i][j] = (f32x4){0.f, 0.f, 0.f, 0.f};

  auto dma_stage = [&](int s, char* pA, char* pB) {
#pragma unroll
    for (int j = 0; j < 2; ++j) {
      const size_t ga = (size_t)Tm * 262144 + (size_t)s * 16384 + j * 8192 +
                        wv * 1024 + l * 16;
      gload_lds16((const char*)eF + ga, pA + j * 8192 + wv * 1024);
      const size_t gb = (size_t)Tn * 262144 + (size_t)s * 16384 + j * 8192 +
                        wv * 1024 + l * 16;
      gload_lds16((const char*)wF + gb, pB + j * 8192 + wv * 1024);
    }
  };

  auto compute_stage = [&](const char* pA, const char* pB) {
#pragma unroll
    for (int ks = 0; ks < 2; ++ks) {
      const int kb = ks * 64 + (l >> 4) * 16;
      half8 a[2], bf[4];
#pragma unroll
      for (int f = 0; f < 2; ++f)
        a[f] = *(const half8*)(pA + swz(wm2 * 32 + f * 16 + (l & 15), kb));
#pragma unroll
      for (int f = 0; f < 4; ++f)
        bf[f] = *(const half8*)(pB + swz(wn2 * 64 + f * 16 + (l & 15), kb));
#pragma unroll
      for (int fm = 0; fm < 2; ++fm)
#pragma unroll
        for (int fn = 0; fn < 4; ++fn)
          acc[fm][fn] = __builtin_amdgcn_mfma_f32_16x16x32_f16(a[fm], bf[fn], acc[fm][fn], 0, 0, 0);
    }
  };

  dma_stage(0, pA_c, pB_c);
  __syncthreads();
  for (int s = 0; s < 16; ++s) {
    if (s < 15) dma_stage(s + 1, pA_n, pB_n);
    compute_stage(pA_c, pB_c);
    __syncthreads();
    char* x;
    x = pA_c; pA_c = pA_n; pA_n = x;
    x = pB_c; pB_c = pB_n; pB_n = x;
  }

  float bcol[4];
#pragma unroll
  for (int fn = 0; fn < 4; ++fn)
    bcol[fn] = bias[Tn * 128 + wn2 * 64 + fn * 16 + (l & 15)];
#pragma unroll
  for (int fm = 0; fm < 2; ++fm)
#pragma unroll
    for (int fn = 0; fn < 4; ++fn)
#pragma unroll
      for (int q = 0; q < 4; ++q)
        acc[fm][fn][q] = ftanh(acc[fm][fn][q] + bcol[fn]);

  // epilogue: LDS transpose (f16 bits) then 32-k-stage blob store (one plane)
  unsigned short* ldsT = (unsigned short*)lds4;  // [128][136] = 34KB < 64KB
  __syncthreads();
#pragma unroll
  for (int fm = 0; fm < 2; ++fm)
#pragma unroll
    for (int fn = 0; fn < 4; ++fn)
#pragma unroll
      for (int q = 0; q < 4; ++q) {
        const int rl = wm2 * 32 + fm * 16 + (l >> 4) * 4 + q;
        const int cl = wn2 * 64 + fn * 16 + (l & 15);
        ldsT[rl * 136 + cl] = f2h(acc[fm][fn][q]);
      }
  __syncthreads();
#pragma unroll
  for (int sb = 0; sb < 4; ++sb) {
    const int L = t * 16;
    const int x6 = ((L >> 6) ^ (L >> 8)) & 1;
    const int x5 = ((L >> 5) ^ (L >> 7)) & 1;
    const int x4 = ((L >> 4) ^ (L >> 6) ^ (L >> 8)) & 1;
    const int X = (L & ~0x70) | (x6 << 6) | (x5 << 5) | (x4 << 4);
    const int row = X >> 6;
    const int cl = sb * 32 + ((X & 63) >> 1);
    uint4 v = *(const uint4*)(ldsT + row * 136 + cl);
    *(uint4*)((char*)outF + (size_t)Tm * 262144 +
              (size_t)(Tn * 4 + sb) * 8192 + L) = v;
  }
}

// ---------------------------------------------------------------------------
// k_scores_mfma: single f16 MFMA (verified round 14). BM=512 x BN=128,
// BK=32, dbuf 80KB, 1 barrier/stage, A via DMA from f16 blob.
// ---------------------------------------------------------------------------
__global__ __launch_bounds__(512) void k_scores_mfma(
    const unsigned short* __restrict__ pF,
    const float* __restrict__ words, float* __restrict__ sc) {
  __shared__ uint4 lds4[5120];  // 80KB
  char* pA_c = (char*)lds4;              // 32KB: [4 tiles][8KB swz64x]
  char* pA_n = (char*)lds4 + 32768;
  char* pB_c = (char*)lds4 + 65536;      // 8KB: [128 n][64B swz64x]
  char* pB_n = (char*)lds4 + 73728;

  const int g = blockIdx.x;
  const int b = (g & 7) + 8 * (g >> 7);   // XCD-pinned batch (bijective)
  const int n0 = ((g >> 3) & 15) * 128;

  const int t = threadIdx.x, l = t & 63, wv = t >> 6;
  const int wm4 = wv >> 1;    // 0..3 -> m tile (128 rows each)
  const int wn2 = wv & 1;     // 0..1 -> n base local = wn2*64

  f32x4 acc[8][4];
#pragma unroll
  for (int i = 0; i < 8; ++i)
#pragma unroll
    for (int j = 0; j < 4; ++j) acc[i][j] = (f32x4){0.f, 0.f, 0.f, 0.f};

  f32x4 br0, br1;
  const int bn = t >> 2;          // B n-row 0..127
  const int bc = (t & 3) * 8;     // f32 col base within 32

  auto dma_A = [&](int s, char* pA) {
#pragma unroll
    for (int j = 0; j < 4; ++j) {
      const size_t gb = (size_t)(b * 4 + j) * 262144 + (size_t)s * 8192 +
                        wv * 1024 + l * 16;
      gload_lds16((const char*)pF + gb, pA + j * 8192 + wv * 1024);
    }
  };

  auto load_B = [&](int s) {
    const float* bs = words + (size_t)b * WN * D_ + (size_t)(n0 + bn) * 1024 +
                      s * 32 + bc;
    br0 = *(const f32x4*)(bs);
    br1 = *(const f32x4*)(bs + 4);
  };

  auto write_B = [&](char* pB) {
    unsigned short hB[8];
#pragma unroll
    for (int j = 0; j < 4; ++j) {
      hB[j] = f2h(br0[j]);
      hB[4 + j] = f2h(br1[j]);
    }
    const int o = swz64x(bn, (t & 3) * 16);
    *(uint4*)(pB + o) = pack8(hB[0], hB[1], hB[2], hB[3], hB[4], hB[5], hB[6], hB[7]);
  };

  auto compute_stage = [&](const char* pA, const char* pB) {
    const int kb0 = (l >> 4) * 16;
    half8 bf[4];
#pragma unroll
    for (int f = 0; f < 4; ++f) {
      const int n = wn2 * 64 + f * 16 + (l & 15);
      bf[f] = *(const half8*)(pB + swz64x(n, kb0));
    }
#pragma unroll
    for (int fm = 0; fm < 8; ++fm) {
      const int row = fm * 16 + (l & 15);
      const half8 a = *(const half8*)(pA + wm4 * 8192 + swz64x(row, kb0));
#pragma unroll
      for (int fn = 0; fn < 4; ++fn)
        acc[fm][fn] = __builtin_amdgcn_mfma_f32_16x16x32_f16(a, bf[fn], acc[fm][fn], 0, 0, 0);
    }
  };

  // prologue
  load_B(0);
  dma_A(0, pA_c);
  write_B(pB_c);
  __syncthreads();

  for (int s = 0; s < 32; ++s) {
    if (s < 31) {
      load_B(s + 1);
      dma_A(s + 1, pA_n);
    }
    compute_stage(pA_c, pB_c);
    if (s < 31) write_B(pB_n);
    __syncthreads();  // drains DMA (vmcnt) + ds_writes (lgkm)
    char* x;
    x = pA_c; pA_c = pA_n; pA_n = x;
    x = pB_c; pB_c = pB_n; pB_n = x;
  }

  // store f32 scores
#pragma unroll
  for (int fm = 0; fm < 8; ++fm)
#pragma unroll
    for (int fn = 0; fn < 4; ++fn)
#pragma unroll
      for (int q = 0; q < 4; ++q) {
        const int row = wm4 * 128 + fm * 16 + (l >> 4) * 4 + q;
        const int col = n0 + wn2 * 64 + fn * 16 + (l & 15);
        sc[((size_t)b * 512 + row) * 2048 + col] = acc[fm][fn][q];
      }
}

// ---------------------------------------------------------------------------
// k_softmax: unchanged (verified round 9/10). blob pointer is a parameter.
// ---------------------------------------------------------------------------
__global__ __launch_bounds__(256) void k_softmax(const float* __restrict__ ws,
                                                 const void* __restrict__ mask,
                                                 unsigned short* __restrict__ blob) {
  __shared__ float red[8];
  const int row = blockIdx.x;
  const int t = threadIdx.x;
  const int wave = t >> 6;
  const float* rp = ws + (size_t)row * 2048;
  float v[8];
  {
    f32x4 v0 = *(const f32x4*)(rp + t * 8);
    f32x4 v1 = *(const f32x4*)(rp + t * 8 + 4);
#pragma unroll
    for (int i = 0; i < 4; ++i) { v[i] = v0[i]; v[4 + i] = v1[i]; }
  }
  if (g_mask_is_int) {
    const int* mp = (const int*)mask + (size_t)row * 2048 + t * 8;
    const int4 m0 = *(const int4*)mp;
    const int4 m1 = *(const int4*)(mp + 4);
    if (m0.x) v[0] = -INFINITY;
    if (m0.y) v[1] = -INFINITY;
    if (m0.z) v[2] = -INFINITY;
    if (m0.w) v[3] = -INFINITY;
    if (m1.x) v[4] = -INFINITY;
    if (m1.y) v[5] = -INFINITY;
    if (m1.z) v[6] = -INFINITY;
    if (m1.w) v[7] = -INFINITY;
  } else {
    const unsigned char* mp = (const unsigned char*)mask + (size_t)row * 2048 + t * 8;
    const uchar4 m0 = *(const uchar4*)mp;
    const uchar4 m1 = *(const uchar4*)(mp + 4);
    if (m0.x) v[0] = -INFINITY;
    if (m0.y) v[1] = -INFINITY;
    if (m0.z) v[2] = -INFINITY;
    if (m0.w) v[3] = -INFINITY;
    if (m1.x) v[4] = -INFINITY;
    if (m1.y) v[5] = -INFINITY;
    if (m1.z) v[6] = -INFINITY;
    if (m1.w) v[7] = -INFINITY;
  }
  float mx = v[0];
#pragma unroll
  for (int i = 1; i < 8; ++i) mx = fmaxf(mx, v[i]);
#pragma unroll
  for (int off = 32; off > 0; off >>= 1) mx = fmaxf(mx, __shfl_xor(mx, off));
  if ((t & 63) == 0) red[wave] = mx;
  __syncthreads();
  mx = fmaxf(fmaxf(red[0], red[1]), fmaxf(red[2], red[3]));
  float e[8];
  float sum = 0.0f;
#pragma unroll
  for (int i = 0; i < 8; ++i) {
    e[i] = __expf(v[i] - mx);
    sum += e[i];
  }
#pragma unroll
  for (int off = 32; off > 0; off >>= 1) sum += __shfl_xor(sum, off);
  if ((t & 63) == 0) red[4 + wave] = sum;
  __syncthreads();
  const float tot = (red[4] + red[5]) + (red[6] + red[7]);
  const float rinv = 1.0f / tot;

  const int b = row >> 9, ee = row & 511;
  const uint4 pk = pack8(f2bf(e[0] * rinv), f2bf(e[1] * rinv),
                         f2bf(e[2] * rinv), f2bf(e[3] * rinv),
                         f2bf(e[4] * rinv), f2bf(e[5] * rinv),
                         f2bf(e[6] * rinv), f2bf(e[7] * rinv));
  char* dst = (char*)blob + (size_t)b * 2097152 + (size_t)(t >> 3) * 65536 +
              ee * 128 + (((t & 7) * 16) ^ ((ee & 7) << 4));
  *(uint4*)dst = pk;
}

// ---------------------------------------------------------------------------
// k_pv: ctx = att @ words (unchanged, verified round 9).
// ---------------------------------------------------------------------------
__global__ __launch_bounds__(512) void k_pv(
    const unsigned short* __restrict__ blob, const float* __restrict__ words,
    float* __restrict__ ctx) {
  __shared__ uint4 lds4[10240];           // 160KB
  char* pAc = (char*)lds4;
  char* pAn = (char*)lds4 + 65536;
  char* pBc = (char*)lds4 + 131072;
  char* pBn = (char*)lds4 + 147456;

  const int g = blockIdx.x;
  const int b = (g & 7) + 8 * (g >> 6);   // XCD-pinned batch
  const int wt = (g >> 3) & 7;
  const int w0 = wt * 128;

  const int t = threadIdx.x, l = t & 63, wv = t >> 6;
  const int wm4 = wv >> 1;
  const int wn2 = wv & 1;

  const char* blobB = (const char*)blob + (size_t)b * 2097152;

  f32x4 acc[8][4];
#pragma unroll
  for (int i = 0; i < 8; ++i)
#pragma unroll
    for (int j = 0; j < 4; ++j) acc[i][j] = (f32x4){0.f, 0.f, 0.f, 0.f};

  f32x4 bv0a, bv0b, bv1a, bv1b;
  const int np2 = (t & 31) * 2;
  const int wc = (t >> 5) * 8;

  auto dma_A = [&](int s, char* pA) {
    const char* gp = blobB + (size_t)s * 65536 + wv * 8192 + l * 16;
#pragma unroll
    for (int j = 0; j < 8; ++j)
      gload_lds16(gp + j * 1024, pA + wv * 8192 + j * 1024);
  };

  auto load_B = [&](int s) {
    const float* wp = words + (size_t)b * WN * D_ +
                      (size_t)(s * 64 + np2) * 1024 + w0 + wc;
    bv0a = *(const f32x4*)(wp);
    bv0b = *(const f32x4*)(wp + 4);
    bv1a = *(const f32x4*)(wp + 1024);
    bv1b = *(const f32x4*)(wp + 1028);
  };

  auto write_B = [&](char* pB) {
#pragma unroll
    for (int i = 0; i < 8; ++i) {
      const int w = wc + i;
      const float x0 = (i < 4) ? bv0a[i & 3] : bv0b[i & 3];
      const float x1 = (i < 4) ? bv1a[i & 3] : bv1b[i & 3];
      const unsigned int pk =
          (unsigned int)f2bf(x0) | ((unsigned int)f2bf(x1) << 16);
      *(unsigned int*)(pB + w * 128 + ((np2 * 2) ^ ((w & 7) << 4))) = pk;
    }
  };

  auto compute_stage = [&](const char* pA, const char* pB) {
#pragma unroll
    for (int ks = 0; ks < 2; ++ks) {
      short8 a[8];
      const int kb = ks * 64 + (l >> 4) * 16;
#pragma unroll
      for (int f = 0; f < 8; ++f) {
        const int row = wm4 * 128 + f * 16 + (l & 15);
        a[f] = *(const short8*)(pA + swz(row, kb));
      }
      short8 bb[4];
#pragma unroll
      for (int f = 0; f < 4; ++f) {
        const int row = wn2 * 64 + f * 16 + (l & 15);
        bb[f] = *(const short8*)(pB + swz(row, kb));
      }
#pragma unroll
      for (int fm = 0; fm < 8; ++fm)
#pragma unroll
        for (int fn = 0; fn < 4; ++fn)
          acc[fm][fn] = __builtin_amdgcn_mfma_f32_16x16x32_bf16(a[fm], bb[fn], acc[fm][fn], 0, 0, 0);
    }
  };

  load_B(0);
  dma_A(0, pAc);
  write_B(pBc);
  __syncthreads();

  for (int s = 0; s < 32; ++s) {
    if (s < 31) {
      load_B(s + 1);
      dma_A(s + 1, pAn);
    }
    compute_stage(pAc, pBc);
    if (s < 31) write_B(pBn);
    __syncthreads();
    char* t1 = pAc; pAc = pAn; pAn = t1;
    char* t2 = pBc; pBc = pBn; pBn = t2;
  }

#pragma unroll
  for (int fm = 0; fm < 8; ++fm)
#pragma unroll
    for (int fn = 0; fn < 4; ++fn)
#pragma unroll
      for (int q = 0; q < 4; ++q) {
        const int row = wm4 * 128 + fm * 16 + (l >> 4) * 4 + q;
        const int col = w0 + wn2 * 64 + fn * 16 + (l & 15);
        ctx[((size_t)b * 512 + row) * 1024 + col] = acc[fm][fn][q];
      }
}

// ---------------------------------------------------------------------------
// k_copy: ctx (ws) -> d_out, float4 grid-stride. (small-ws fallback only)
// ---------------------------------------------------------------------------
__global__ __launch_bounds__(256) void k_copy(const float4* __restrict__ src,
                                              float4* __restrict__ dst) {
  const int n4 = 16384 * 1024 / 4;
  int i = blockIdx.x * 256 + threadIdx.x;
  const int stride = gridDim.x * 256;
  for (; i < n4; i += stride) dst[i] = src[i];
}

// ===========================================================================
// FALLBACK PATH (round-2 verified kernels; used if ws too small)
// ===========================================================================
__global__ __launch_bounds__(256, 4) void k_proj(const float* __restrict__ A,
                                                 const float* __restrict__ W,
                                                 const float* __restrict__ bias,
                                                 float* __restrict__ out) {
  __shared__ float As[32][132];
  __shared__ float Bs[32][132];
  const int t = threadIdx.x;
  const int m0 = blockIdx.x * 128;
  const int n0 = blockIdx.y * 128;
  const int tm = t >> 4;
  const int tn = t & 15;
  const int lrow = t >> 1;
  const int lk = (t & 1) * 16;

  float acc[8][8];
#pragma unroll
  for (int i = 0; i < 8; ++i)
#pragma unroll
    for (int j = 0; j < 8; ++j) acc[i][j] = 0.0f;

  const float* Arow = A + (size_t)(m0 + lrow) * D_ + lk;
  const float* Wrow = W + (size_t)(n0 + lrow) * D_ + lk;

  for (int k0 = 0; k0 < D_; k0 += 32) {
    __syncthreads();
#pragma unroll
    for (int j = 0; j < 4; ++j) {
      const float4 va = *(const float4*)(Arow + k0 + j * 4);
      As[lk + j * 4 + 0][lrow] = va.x;
      As[lk + j * 4 + 1][lrow] = va.y;
      As[lk + j * 4 + 2][lrow] = va.z;
      As[lk + j * 4 + 3][lrow] = va.w;
      const float4 vb = *(const float4*)(Wrow + k0 + j * 4);
      Bs[lk + j * 4 + 0][lrow] = vb.x;
      Bs[lk + j * 4 + 1][lrow] = vb.y;
      Bs[lk + j * 4 + 2][lrow] = vb.z;
      Bs[lk + j * 4 + 3][lrow] = vb.w;
    }
    __syncthreads();
#pragma unroll 8
    for (int k = 0; k < 32; ++k) {
      float a[8], bb[8];
      *(float4*)(a + 0) = *(const float4*)&As[k][tm * 4];
      *(float4*)(a + 4) = *(const float4*)&As[k][tm * 4 + 64];
      *(float4*)(bb + 0) = *(const float4*)&Bs[k][tn * 4];
      *(float4*)(bb + 4) = *(const float4*)&Bs[k][tn * 4 + 64];
#pragma unroll
      for (int i = 0; i < 8; ++i)
#pragma unroll
        for (int j = 0; j < 8; ++j) acc[i][j] = fmaf(a[i], bb[j], acc[i][j]);
    }
  }

  float bn[8];
#pragma unroll
  for (int j = 0; j < 8; ++j) bn[j] = bias[n0 + tn * 4 + (j & 3) + (j >> 2) * 64];
#pragma unroll
  for (int i = 0; i < 8; ++i) {
    const int m = m0 + tm * 4 + (i & 3) + (i >> 2) * 64;
    float4 v0, v1;
    v0.x = tanhf(acc[i][0] + bn[0]);
    v0.y = tanhf(acc[i][1] + bn[1]);
    v0.z = tanhf(acc[i][2] + bn[2]);
    v0.w = tanhf(acc[i][3] + bn[3]);
    v1.x = tanhf(acc[i][4] + bn[4]);
    v1.y = tanhf(acc[i][5] + bn[5]);
    v1.z = tanhf(acc[i][6] + bn[6]);
    v1.w = tanhf(acc[i][7] + bn[7]);
    *(float4*)(out + (size_t)m * D_ + n0 + tn * 4) = v0;
    *(float4*)(out + (size_t)m * D_ + n0 + tn * 4 + 64) = v1;
  }
}

__global__ __launch_bounds__(256) void k_scores(const float* __restrict__ words,
                                                const void* __restrict__ mask,
                                                float* __restrict__ pa) {
  __shared__ float Pt[1024][18];
  __shared__ float Ws[64][268];
  const int t = threadIdx.x;
  const int b = blockIdx.x >> 5;
  const int et = blockIdx.x & 31;
  const int e0 = et * 16;
  const int eg = t >> 5;
  const int ng = t & 31;
  const int mask_is_int = g_mask_is_int;
  const float* wbase = words + (size_t)b * WN * D_;

  {
    const int row = t >> 4;
    const int dj = (t & 15) * 4;
    const float* pr = pa + (size_t)(b * E_ + e0 + row) * D_;
#pragma unroll
    for (int rr = 0; rr < 16; ++rr) {
      const float4 v = *(const float4*)(pr + dj + rr * 64);
      Pt[dj + rr * 64 + 0][row] = v.x;
      Pt[dj + rr * 64 + 1][row] = v.y;
      Pt[dj + rr * 64 + 2][row] = v.z;
      Pt[dj + rr * 64 + 3][row] = v.w;
    }
  }

  float s[2][64];
#pragma unroll
  for (int i = 0; i < 2; ++i)
#pragma unroll
    for (int u = 0; u < 64; ++u) s[i][u] = 0.0f;

  const int nl = t >> 3;
  const int d4 = (t & 7) * 4;

  for (int dk = 0; dk < D_; dk += 64) {
#pragma unroll
    for (int nb = 0; nb < 8; ++nb) {
      __syncthreads();
#pragma unroll
      for (int rr = 0; rr < 8; ++rr) {
#pragma unroll
        for (int hh = 0; hh < 2; ++hh) {
          const int n = nl + rr * 32;
          const int d = d4 + hh * 32;
          const float4 v = *(const float4*)(wbase + (size_t)(nb * 256 + n) * D_ + dk + d);
          Ws[d + 0][n] = v.x;
          Ws[d + 1][n] = v.y;
          Ws[d + 2][n] = v.z;
          Ws[d + 3][n] = v.w;
        }
      }
      __syncthreads();
#pragma unroll 2
      for (int k = 0; k < 64; ++k) {
        const float2 a = *(const float2*)&Pt[dk + k][eg * 2];
        const float4 b0 = *(const float4*)&Ws[k][ng * 4];
        const float4 b1 = *(const float4*)&Ws[k][128 + ng * 4];
        const float aa[2] = {a.x, a.y};
        const float bb[8] = {b0.x, b0.y, b0.z, b0.w, b1.x, b1.y, b1.z, b1.w};
#pragma unroll
        for (int i = 0; i < 2; ++i)
#pragma unroll
          for (int u = 0; u < 8; ++u)
            s[i][nb * 8 + u] = fmaf(aa[i], bb[u], s[i][nb * 8 + u]);
      }
    }
  }

#pragma unroll
  for (int i = 0; i < 2; ++i) {
    const int e = e0 + eg * 2 + i;
#pragma unroll
    for (int nb = 0; nb < 8; ++nb)
#pragma unroll
      for (int q = 0; q < 2; ++q) {
        const size_t moff = (size_t)(b * E_ + e) * WN + nb * 256 + q * 128 + ng * 4;
        int mx, my, mz, mw;
        if (mask_is_int) {
          const int4 mv = *(const int4*)((const int*)mask + moff);
          mx = mv.x; my = mv.y; mz = mv.z; mw = mv.w;
        } else {
          const uchar4 mv = *(const uchar4*)((const unsigned char*)mask + moff);
          mx = mv.x; my = mv.y; mz = mv.z; mw = mv.w;
        }
        if (mx) s[i][nb * 8 + q * 4 + 0] = -1e30f;
        if (my) s[i][nb * 8 + q * 4 + 1] = -1e30f;
        if (mz) s[i][nb * 8 + q * 4 + 2] = -1e30f;
        if (mw) s[i][nb * 8 + q * 4 + 3] = -1e30f;
      }
    float m = -1e30f;
#pragma unroll
    for (int u = 0; u < 64; ++u) m = fmaxf(m, s[i][u]);
#pragma unroll
    for (int off = 16; off > 0; off >>= 1) m = fmaxf(m, __shfl_xor(m, off));
    float sum = 0.0f;
#pragma unroll
    for (int u = 0; u < 64; ++u) {
      const float p = __expf(s[i][u] - m);
      s[i][u] = p;
      sum += p;
    }
#pragma unroll
    for (int off = 16; off > 0; off >>= 1) sum += __shfl_xor(sum, off);
    const float rinv = 1.0f / sum;

    unsigned short* ar2 = (unsigned short*)(pa + (size_t)(b * E_ + e) * WN / 2);
#pragma unroll
    for (int nb = 0; nb < 8; ++nb)
#pragma unroll
      for (int q = 0; q < 2; ++q) {
        ushort4 pk;
        pk.x = f2bf(s[i][nb * 8 + q * 4 + 0] * rinv);
        pk.y = f2bf(s[i][nb * 8 + q * 4 + 1] * rinv);
        pk.z = f2bf(s[i][nb * 8 + q * 4 + 2] * rinv);
        pk.w = f2bf(s[i][nb * 8 + q * 4 + 3] * rinv);
        *(ushort4*)(ar2 + nb * 256 + q * 128 + ng * 4) = pk;
      }
  }
}

__global__ __launch_bounds__(256) void k_ctx(const float* __restrict__ words,
                                             float* __restrict__ pa) {
  __shared__ unsigned short att_s[16][2048];
  __shared__ unsigned short Wb[256][132];
  const int t = threadIdx.x;
  const int b = blockIdx.x >> 5;
  const int et = blockIdx.x & 31;
  const int e0 = et * 16;
  const int eg = t >> 5;
  const int wg = t & 31;
  const float* wbase = words + (size_t)b * WN * D_;

  {
    const int row = t >> 4;
    const int cj = t & 15;
    const uint4* pr = (const uint4*)(pa + (size_t)(b * E_ + e0 + row) * D_);
#pragma unroll
    for (int rr = 0; rr < 16; ++rr) {
      const int c = cj + rr * 16;
      const uint4 v = pr[c];
      *(uint4*)&att_s[row][c * 8] = v;
    }
  }

  float acc[2][32];
#pragma unroll
  for (int i = 0; i < 2; ++i)
#pragma unroll
    for (int u = 0; u < 32; ++u) acc[i][u] = 0.0f;

  const int nlg = t >> 5;
  const int w4 = (t & 31) * 4;

  for (int nb = 0; nb < 8; ++nb) {
#pragma unroll
    for (int q = 0; q < 8; ++q) {
      __syncthreads();
#pragma unroll
      for (int rr = 0; rr < 32; ++rr) {
        const int n = nlg + rr * 8;
        const float4 v = *(const float4*)(wbase + (size_t)(nb * 256 + n) * D_ + q * 128 + w4);
        ushort4 pk;
        pk.x = f2bf(v.x);
        pk.y = f2bf(v.y);
        pk.z = f2bf(v.z);
        pk.w = f2bf(v.w);
        *(ushort4*)&Wb[n][w4] = pk;
      }
      __syncthreads();
#pragma unroll 4
      for (int n2 = 0; n2 < 128; ++n2) {
        const int n = n2 * 2;
        const ushort4 r0 = *(const ushort4*)&Wb[n][wg * 4];
        const ushort4 r1 = *(const ushort4*)&Wb[n + 1][wg * 4];
        const float w0[4] = {bf2f(r0.x), bf2f(r0.y), bf2f(r0.z), bf2f(r0.w)};
        const float w1[4] = {bf2f(r1.x), bf2f(r1.y), bf2f(r1.z), bf2f(r1.w)};
#pragma unroll
        for (int i = 0; i < 2; ++i) {
          const unsigned int aw = *(const unsigned int*)&att_s[eg * 2 + i][nb * 256 + n];
          const float a0 = bf2f((unsigned short)(aw & 0xffffu));
          const float a1 = bf2f((unsigned short)(aw >> 16));
#pragma unroll
          for (int j = 0; j < 4; ++j)
            acc[i][q * 4 + j] = fmaf(a0, w0[j], fmaf(a1, w1[j], acc[i][q * 4 + j]));
        }
      }
    }
  }

#pragma unroll
  for (int i = 0; i < 2; ++i) {
    float* orow = pa + (size_t)(b * E_ + e0 + eg * 2 + i) * D_;
#pragma unroll
    for (int q = 0; q < 8; ++q) {
      float4 v;
      v.x = acc[i][q * 4 + 0];
      v.y = acc[i][q * 4 + 1];
      v.z = acc[i][q * 4 + 2];
      v.w = acc[i][q * 4 + 3];
      *(float4*)(orow + q * 128 + wg * 4) = v;
    }
  }
}

extern "C" void kernel_launch(void* const* d_in, const int* in_sizes, int n_in,
                              void* d_out, int out_size, void* d_ws, size_t ws_size,
                              hipStream_t stream) {
  const float* ems = (const float*)d_in[0];
  const float* words = (const float*)d_in[1];
  const void* mask = d_in[2];
  const float* w_weight = (const float*)d_in[3];
  const float* w_bias = (const float*)d_in[4];

  k_detect<<<1, 64, 0, stream>>>((const unsigned char*)mask);

  const size_t ws_need = (size_t)16384 * 2048 * 4;          // 128 MB
  const size_t ws_big = ws_need + (size_t)32 * 2097152;     // +64 MB blob
  if (ws_size >= ws_need) {
    unsigned short* pF = (unsigned short*)d_out;    // 32MB f16 proj blob
    float* ws = (float*)d_ws;
    unsigned short* eF = (unsigned short*)d_ws;                     // 32MB
    unsigned short* wF = eF + (size_t)16384 * 1024;                 // 2MB
    // 0. convert ems (128 tiles) and W (8 tiles) into f16 swizzled blobs
    k_split_h<<<dim3(2048), 256, 0, stream>>>(ems, eF);
    k_split_h<<<dim3(128), 256, 0, stream>>>(w_weight, wF);
    // 1. proj (single f16 MFMA, XCD-pinned, 64KB LDS) -> f16 blob in d_out
    k_proj_dma<<<dim3(1024), 512, 0, stream>>>(eF, wF, w_bias, pF);
    // 2. scores (single f16 MFMA) -> ws
    k_scores_mfma<<<dim3(512), 512, 0, stream>>>(pF, words, ws);
    if (ws_size >= ws_big) {
      // big-ws path: att blob lives in ws after scores; ctx -> d_out direct
      unsigned short* blob = (unsigned short*)((char*)d_ws + ws_need);
      k_softmax<<<dim3(16384), 256, 0, stream>>>(ws, mask, blob);
      k_pv<<<dim3(256), 512, 0, stream>>>(blob, words, (float*)d_out);
    } else {
      // small-ws path (verified rounds 9-11): blob in d_out, ctx via copy
      k_softmax<<<dim3(16384), 256, 0, stream>>>(ws, mask, (unsigned short*)d_out);
      k_pv<<<dim3(256), 512, 0, stream>>>((const unsigned short*)d_out, words, ws);
      k_copy<<<dim3(2048), 256, 0, stream>>>((const float4*)d_ws, (float4*)d_out);
    }
  } else {
    float* out = (float*)d_out;
    k_proj<<<dim3(128, 8), 256, 0, stream>>>(ems, w_weight, w_bias, out);
    k_scores<<<dim3(B_ * (E_ / 16)), 256, 0, stream>>>(words, mask, out);
    k_ctx<<<dim3(B_ * (E_ / 16)), 256, 0, stream>>>(words, out);
  }
}

// Round 16
// 343.807 us; speedup vs baseline: 1.5999x; 1.0659x over previous
//
#include <hip/hip_runtime.h>
#include <hip/hip_bf16.h>
#include <hip/hip_fp16.h>
#include <stdint.h>

#define B_  32
#define E_  512
#define WN  2048
#define D_  1024

typedef __attribute__((ext_vector_type(8))) short short8;
typedef __attribute__((ext_vector_type(8))) _Float16 half8;
typedef __attribute__((ext_vector_type(4))) float f32x4;

__device__ int g_mask_is_int;   // 1 if mask buffer is int32 per element, 0 if uint8

__device__ __forceinline__ unsigned short f2bf(float f) {
  unsigned int u = __float_as_uint(f);
  u += 0x7fffu + ((u >> 16) & 1u);   // round-to-nearest-even
  return (unsigned short)(u >> 16);
}
__device__ __forceinline__ float bf2f(unsigned short s) {
  return __uint_as_float(((unsigned int)s) << 16);
}
__device__ __forceinline__ unsigned short f2h(float f) {
  return __half_as_ushort(__float2half(f));   // RTNE f32->f16
}
__device__ __forceinline__ float h2f(unsigned short s) {
  return __half2float(__ushort_as_half(s));
}
__device__ __forceinline__ float ftanh(float x) {
  float e = __expf(2.0f * x);
  return 1.0f - 2.0f / (e + 1.0f);
}
// XOR-swizzled byte offset within a [rows][128B] LDS plane
__device__ __forceinline__ int swz(int row, int kb) {
  return row * 128 + (kb ^ ((row & 7) << 4));
}
// 64B-row swizzle: F(X) = X ^ ((X>>6 & 7) << 4)
__device__ __forceinline__ int swz64x(int row, int kb) {
  const int X = row * 64 + kb;
  return X ^ (((X >> 6) & 7) << 4);
}
__device__ __forceinline__ uint4 pack8(unsigned short a0, unsigned short a1,
                                       unsigned short a2, unsigned short a3,
                                       unsigned short a4, unsigned short a5,
                                       unsigned short a6, unsigned short a7) {
  uint4 v;
  v.x = (unsigned int)a0 | ((unsigned int)a1 << 16);
  v.y = (unsigned int)a2 | ((unsigned int)a3 << 16);
  v.z = (unsigned int)a4 | ((unsigned int)a5 << 16);
  v.w = (unsigned int)a6 | ((unsigned int)a7 << 16);
  return v;
}
// async global->LDS, 16B per lane; LDS dst is wave-uniform base (+lane*16 HW)
__device__ __forceinline__ void gload_lds16(const void* g, void* l) {
  __builtin_amdgcn_global_load_lds(
      (const __attribute__((address_space(1))) unsigned int*)g,
      (__attribute__((address_space(3))) unsigned int*)l, 16, 0, 0);
}

// ---------------------------------------------------------------------------
// K0: detect mask dtype. int32 0/1 data => bytes at offset %4 != 0 are all 0.
// ---------------------------------------------------------------------------
__global__ void k_detect(const unsigned char* __restrict__ m) {
  if (threadIdx.x == 0) {
    int nz = 0;
    for (int i = 0; i < 1024; ++i)
      if ((i & 3) && m[i]) nz++;
    g_mask_is_int = (nz == 0) ? 1 : 0;
  }
}

// ===========================================================================
// FAST PATH
// ===========================================================================

// ---------------------------------------------------------------------------
// k_split_h: src f32 -> ONE f16 blob in proj's swizzled LDS-image layout.
// (verified round 15)
// ---------------------------------------------------------------------------
__global__ __launch_bounds__(256) void k_split_h(const float* __restrict__ src,
                                                 unsigned short* __restrict__ out) {
#pragma unroll
  for (int j = 0; j < 4; ++j) {
    const size_t Lg = ((size_t)blockIdx.x * 1024 + j * 256 + threadIdx.x) * 16;
    const int Lloc = (int)(Lg & 16383);
    const int TS = (int)(Lg >> 14);
    const int T = TS >> 4, s = TS & 15;
    const int row = Lloc >> 7;
    const int kb = (Lloc & 127) ^ ((row & 7) << 4);
    const int kk = kb >> 1;
    const float* sp = src + ((size_t)(T * 128 + row)) * 1024 + s * 64 + kk;
    const f32x4 v0 = *(const f32x4*)(sp);
    const f32x4 v1 = *(const f32x4*)(sp + 4);
    *(uint4*)((char*)out + Lg) =
        pack8(f2h(v0[0]), f2h(v0[1]), f2h(v0[2]), f2h(v0[3]),
              f2h(v1[0]), f2h(v1[1]), f2h(v1[2]), f2h(v1[3]));
  }
}

// ---------------------------------------------------------------------------
// k_proj_dma: proj = tanh(ems @ W^T + bias) via single f16 MFMA.
// (verified round 15)
// ---------------------------------------------------------------------------
__global__ __launch_bounds__(512) void k_proj_dma(
    const unsigned short* __restrict__ eF, const unsigned short* __restrict__ wF,
    const float* __restrict__ bias,
    unsigned short* __restrict__ outF) {
  __shared__ uint4 lds4[4096];   // 64KB
  char* pA_c = (char*)lds4;
  char* pB_c = (char*)lds4 + 16384;
  char* pA_n = (char*)lds4 + 32768;
  char* pB_n = (char*)lds4 + 49152;

  const int g = blockIdx.x;
  const int xcd = g & 7;
  const int slot = g >> 3;               // 0..127
  const int Tm = xcd + 8 * (slot >> 3);  // 0..127, pinned to XCD
  const int Tn = slot & 7;               // 0..7
  const int t = threadIdx.x, l = t & 63, wv = t >> 6;
  const int wm2 = wv >> 1;   // 0..3 -> rows wm2*32
  const int wn2 = wv & 1;    // 0..1 -> cols wn2*64

  f32x4 acc[2][4];
#pragma unroll
  for (int i = 0; i < 2; ++i)
#pragma unroll
    for (int j = 0; j < 4; ++j) acc[i][j] = (f32x4){0.f, 0.f, 0.f, 0.f};

  auto dma_stage = [&](int s, char* pA, char* pB) {
#pragma unroll
    for (int j = 0; j < 2; ++j) {
      const size_t ga = (size_t)Tm * 262144 + (size_t)s * 16384 + j * 8192 +
                        wv * 1024 + l * 16;
      gload_lds16((const char*)eF + ga, pA + j * 8192 + wv * 1024);
      const size_t gb = (size_t)Tn * 262144 + (size_t)s * 16384 + j * 8192 +
                        wv * 1024 + l * 16;
      gload_lds16((const char*)wF + gb, pB + j * 8192 + wv * 1024);
    }
  };

  auto compute_stage = [&](const char* pA, const char* pB) {
#pragma unroll
    for (int ks = 0; ks < 2; ++ks) {
      const int kb = ks * 64 + (l >> 4) * 16;
      half8 a[2], bf[4];
#pragma unroll
      for (int f = 0; f < 2; ++f)
        a[f] = *(const half8*)(pA + swz(wm2 * 32 + f * 16 + (l & 15), kb));
#pragma unroll
      for (int f = 0; f < 4; ++f)
        bf[f] = *(const half8*)(pB + swz(wn2 * 64 + f * 16 + (l & 15), kb));
#pragma unroll
      for (int fm = 0; fm < 2; ++fm)
#pragma unroll
        for (int fn = 0; fn < 4; ++fn)
          acc[fm][fn] = __builtin_amdgcn_mfma_f32_16x16x32_f16(a[fm], bf[fn], acc[fm][fn], 0, 0, 0);
    }
  };

  dma_stage(0, pA_c, pB_c);
  __syncthreads();
  for (int s = 0; s < 16; ++s) {
    if (s < 15) dma_stage(s + 1, pA_n, pB_n);
    compute_stage(pA_c, pB_c);
    __syncthreads();
    char* x;
    x = pA_c; pA_c = pA_n; pA_n = x;
    x = pB_c; pB_c = pB_n; pB_n = x;
  }

  float bcol[4];
#pragma unroll
  for (int fn = 0; fn < 4; ++fn)
    bcol[fn] = bias[Tn * 128 + wn2 * 64 + fn * 16 + (l & 15)];
#pragma unroll
  for (int fm = 0; fm < 2; ++fm)
#pragma unroll
    for (int fn = 0; fn < 4; ++fn)
#pragma unroll
      for (int q = 0; q < 4; ++q)
        acc[fm][fn][q] = ftanh(acc[fm][fn][q] + bcol[fn]);

  // epilogue: LDS transpose (f16 bits) then 32-k-stage blob store (one plane)
  unsigned short* ldsT = (unsigned short*)lds4;  // [128][136] = 34KB < 64KB
  __syncthreads();
#pragma unroll
  for (int fm = 0; fm < 2; ++fm)
#pragma unroll
    for (int fn = 0; fn < 4; ++fn)
#pragma unroll
      for (int q = 0; q < 4; ++q) {
        const int rl = wm2 * 32 + fm * 16 + (l >> 4) * 4 + q;
        const int cl = wn2 * 64 + fn * 16 + (l & 15);
        ldsT[rl * 136 + cl] = f2h(acc[fm][fn][q]);
      }
  __syncthreads();
#pragma unroll
  for (int sb = 0; sb < 4; ++sb) {
    const int L = t * 16;
    const int x6 = ((L >> 6) ^ (L >> 8)) & 1;
    const int x5 = ((L >> 5) ^ (L >> 7)) & 1;
    const int x4 = ((L >> 4) ^ (L >> 6) ^ (L >> 8)) & 1;
    const int X = (L & ~0x70) | (x6 << 6) | (x5 << 5) | (x4 << 4);
    const int row = X >> 6;
    const int cl = sb * 32 + ((X & 63) >> 1);
    uint4 v = *(const uint4*)(ldsT + row * 136 + cl);
    *(uint4*)((char*)outF + (size_t)Tm * 262144 +
              (size_t)(Tn * 4 + sb) * 8192 + L) = v;
  }
}

// ---------------------------------------------------------------------------
// k_scores_mfma: single f16 MFMA (verified round 14/15). NEW: stores scores
// as f16 (range <~90, err |s|*2^-12 -- analysis in round log): halves the
// scores write and softmax read traffic.
// ---------------------------------------------------------------------------
__global__ __launch_bounds__(512) void k_scores_mfma(
    const unsigned short* __restrict__ pF,
    const float* __restrict__ words, unsigned short* __restrict__ sc) {
  __shared__ uint4 lds4[5120];  // 80KB
  char* pA_c = (char*)lds4;              // 32KB: [4 tiles][8KB swz64x]
  char* pA_n = (char*)lds4 + 32768;
  char* pB_c = (char*)lds4 + 65536;      // 8KB: [128 n][64B swz64x]
  char* pB_n = (char*)lds4 + 73728;

  const int g = blockIdx.x;
  const int b = (g & 7) + 8 * (g >> 7);   // XCD-pinned batch (bijective)
  const int n0 = ((g >> 3) & 15) * 128;

  const int t = threadIdx.x, l = t & 63, wv = t >> 6;
  const int wm4 = wv >> 1;    // 0..3 -> m tile (128 rows each)
  const int wn2 = wv & 1;     // 0..1 -> n base local = wn2*64

  f32x4 acc[8][4];
#pragma unroll
  for (int i = 0; i < 8; ++i)
#pragma unroll
    for (int j = 0; j < 4; ++j) acc[i][j] = (f32x4){0.f, 0.f, 0.f, 0.f};

  f32x4 br0, br1;
  const int bn = t >> 2;          // B n-row 0..127
  const int bc = (t & 3) * 8;     // f32 col base within 32

  auto dma_A = [&](int s, char* pA) {
#pragma unroll
    for (int j = 0; j < 4; ++j) {
      const size_t gb = (size_t)(b * 4 + j) * 262144 + (size_t)s * 8192 +
                        wv * 1024 + l * 16;
      gload_lds16((const char*)pF + gb, pA + j * 8192 + wv * 1024);
    }
  };

  auto load_B = [&](int s) {
    const float* bs = words + (size_t)b * WN * D_ + (size_t)(n0 + bn) * 1024 +
                      s * 32 + bc;
    br0 = *(const f32x4*)(bs);
    br1 = *(const f32x4*)(bs + 4);
  };

  auto write_B = [&](char* pB) {
    unsigned short hB[8];
#pragma unroll
    for (int j = 0; j < 4; ++j) {
      hB[j] = f2h(br0[j]);
      hB[4 + j] = f2h(br1[j]);
    }
    const int o = swz64x(bn, (t & 3) * 16);
    *(uint4*)(pB + o) = pack8(hB[0], hB[1], hB[2], hB[3], hB[4], hB[5], hB[6], hB[7]);
  };

  auto compute_stage = [&](const char* pA, const char* pB) {
    const int kb0 = (l >> 4) * 16;
    half8 bf[4];
#pragma unroll
    for (int f = 0; f < 4; ++f) {
      const int n = wn2 * 64 + f * 16 + (l & 15);
      bf[f] = *(const half8*)(pB + swz64x(n, kb0));
    }
#pragma unroll
    for (int fm = 0; fm < 8; ++fm) {
      const int row = fm * 16 + (l & 15);
      const half8 a = *(const half8*)(pA + wm4 * 8192 + swz64x(row, kb0));
#pragma unroll
      for (int fn = 0; fn < 4; ++fn)
        acc[fm][fn] = __builtin_amdgcn_mfma_f32_16x16x32_f16(a, bf[fn], acc[fm][fn], 0, 0, 0);
    }
  };

  // prologue
  load_B(0);
  dma_A(0, pA_c);
  write_B(pB_c);
  __syncthreads();

  for (int s = 0; s < 32; ++s) {
    if (s < 31) {
      load_B(s + 1);
      dma_A(s + 1, pA_n);
    }
    compute_stage(pA_c, pB_c);
    if (s < 31) write_B(pB_n);
    __syncthreads();  // drains DMA (vmcnt) + ds_writes (lgkm)
    char* x;
    x = pA_c; pA_c = pA_n; pA_n = x;
    x = pB_c; pB_c = pB_n; pB_n = x;
  }

  // store f16 scores
#pragma unroll
  for (int fm = 0; fm < 8; ++fm)
#pragma unroll
    for (int fn = 0; fn < 4; ++fn)
#pragma unroll
      for (int q = 0; q < 4; ++q) {
        const int row = wm4 * 128 + fm * 16 + (l >> 4) * 4 + q;
        const int col = n0 + wn2 * 64 + fn * 16 + (l & 15);
        sc[((size_t)b * 512 + row) * 2048 + col] = f2h(acc[fm][fn][q]);
      }
}

// ---------------------------------------------------------------------------
// k_softmax: reads f16 scores, writes f16 att blob (att in [0,1], f16 exact
// range). Blob layout unchanged (verified round 9/10).
// ---------------------------------------------------------------------------
__global__ __launch_bounds__(256) void k_softmax(const unsigned short* __restrict__ sc,
                                                 const void* __restrict__ mask,
                                                 unsigned short* __restrict__ blob) {
  __shared__ float red[8];
  const int row = blockIdx.x;
  const int t = threadIdx.x;
  const int wave = t >> 6;
  const unsigned short* rp = sc + (size_t)row * 2048;
  float v[8];
  {
    const half8 hv = *(const half8*)(rp + t * 8);
#pragma unroll
    for (int i = 0; i < 8; ++i) v[i] = (float)hv[i];
  }
  if (g_mask_is_int) {
    const int* mp = (const int*)mask + (size_t)row * 2048 + t * 8;
    const int4 m0 = *(const int4*)mp;
    const int4 m1 = *(const int4*)(mp + 4);
    if (m0.x) v[0] = -INFINITY;
    if (m0.y) v[1] = -INFINITY;
    if (m0.z) v[2] = -INFINITY;
    if (m0.w) v[3] = -INFINITY;
    if (m1.x) v[4] = -INFINITY;
    if (m1.y) v[5] = -INFINITY;
    if (m1.z) v[6] = -INFINITY;
    if (m1.w) v[7] = -INFINITY;
  } else {
    const unsigned char* mp = (const unsigned char*)mask + (size_t)row * 2048 + t * 8;
    const uchar4 m0 = *(const uchar4*)mp;
    const uchar4 m1 = *(const uchar4*)(mp + 4);
    if (m0.x) v[0] = -INFINITY;
    if (m0.y) v[1] = -INFINITY;
    if (m0.z) v[2] = -INFINITY;
    if (m0.w) v[3] = -INFINITY;
    if (m1.x) v[4] = -INFINITY;
    if (m1.y) v[5] = -INFINITY;
    if (m1.z) v[6] = -INFINITY;
    if (m1.w) v[7] = -INFINITY;
  }
  float mx = v[0];
#pragma unroll
  for (int i = 1; i < 8; ++i) mx = fmaxf(mx, v[i]);
#pragma unroll
  for (int off = 32; off > 0; off >>= 1) mx = fmaxf(mx, __shfl_xor(mx, off));
  if ((t & 63) == 0) red[wave] = mx;
  __syncthreads();
  mx = fmaxf(fmaxf(red[0], red[1]), fmaxf(red[2], red[3]));
  float e[8];
  float sum = 0.0f;
#pragma unroll
  for (int i = 0; i < 8; ++i) {
    e[i] = __expf(v[i] - mx);
    sum += e[i];
  }
#pragma unroll
  for (int off = 32; off > 0; off >>= 1) sum += __shfl_xor(sum, off);
  if ((t & 63) == 0) red[4 + wave] = sum;
  __syncthreads();
  const float tot = (red[4] + red[5]) + (red[6] + red[7]);
  const float rinv = 1.0f / tot;

  const int b = row >> 9, ee = row & 511;
  const uint4 pk = pack8(f2h(e[0] * rinv), f2h(e[1] * rinv),
                         f2h(e[2] * rinv), f2h(e[3] * rinv),
                         f2h(e[4] * rinv), f2h(e[5] * rinv),
                         f2h(e[6] * rinv), f2h(e[7] * rinv));
  char* dst = (char*)blob + (size_t)b * 2097152 + (size_t)(t >> 3) * 65536 +
              ee * 128 + (((t & 7) * 16) ^ ((ee & 7) << 4));
  *(uint4*)dst = pk;
}

// ---------------------------------------------------------------------------
// k_pv: ctx = att @ words, now f16 MFMA (att f16 blob, words f16 staged) --
// ~8x lower PV quantization error, same speed. Structure verified round 9.
// ---------------------------------------------------------------------------
__global__ __launch_bounds__(512) void k_pv(
    const unsigned short* __restrict__ blob, const float* __restrict__ words,
    float* __restrict__ ctx) {
  __shared__ uint4 lds4[10240];           // 160KB
  char* pAc = (char*)lds4;
  char* pAn = (char*)lds4 + 65536;
  char* pBc = (char*)lds4 + 131072;
  char* pBn = (char*)lds4 + 147456;

  const int g = blockIdx.x;
  const int b = (g & 7) + 8 * (g >> 6);   // XCD-pinned batch
  const int wt = (g >> 3) & 7;
  const int w0 = wt * 128;

  const int t = threadIdx.x, l = t & 63, wv = t >> 6;
  const int wm4 = wv >> 1;
  const int wn2 = wv & 1;

  const char* blobB = (const char*)blob + (size_t)b * 2097152;

  f32x4 acc[8][4];
#pragma unroll
  for (int i = 0; i < 8; ++i)
#pragma unroll
    for (int j = 0; j < 4; ++j) acc[i][j] = (f32x4){0.f, 0.f, 0.f, 0.f};

  f32x4 bv0a, bv0b, bv1a, bv1b;
  const int np2 = (t & 31) * 2;
  const int wc = (t >> 5) * 8;

  auto dma_A = [&](int s, char* pA) {
    const char* gp = blobB + (size_t)s * 65536 + wv * 8192 + l * 16;
#pragma unroll
    for (int j = 0; j < 8; ++j)
      gload_lds16(gp + j * 1024, pA + wv * 8192 + j * 1024);
  };

  auto load_B = [&](int s) {
    const float* wp = words + (size_t)b * WN * D_ +
                      (size_t)(s * 64 + np2) * 1024 + w0 + wc;
    bv0a = *(const f32x4*)(wp);
    bv0b = *(const f32x4*)(wp + 4);
    bv1a = *(const f32x4*)(wp + 1024);
    bv1b = *(const f32x4*)(wp + 1028);
  };

  auto write_B = [&](char* pB) {
#pragma unroll
    for (int i = 0; i < 8; ++i) {
      const int w = wc + i;
      const float x0 = (i < 4) ? bv0a[i & 3] : bv0b[i & 3];
      const float x1 = (i < 4) ? bv1a[i & 3] : bv1b[i & 3];
      const unsigned int pk =
          (unsigned int)f2h(x0) | ((unsigned int)f2h(x1) << 16);
      *(unsigned int*)(pB + w * 128 + ((np2 * 2) ^ ((w & 7) << 4))) = pk;
    }
  };

  auto compute_stage = [&](const char* pA, const char* pB) {
#pragma unroll
    for (int ks = 0; ks < 2; ++ks) {
      half8 a[8];
      const int kb = ks * 64 + (l >> 4) * 16;
#pragma unroll
      for (int f = 0; f < 8; ++f) {
        const int row = wm4 * 128 + f * 16 + (l & 15);
        a[f] = *(const half8*)(pA + swz(row, kb));
      }
      half8 bb[4];
#pragma unroll
      for (int f = 0; f < 4; ++f) {
        const int row = wn2 * 64 + f * 16 + (l & 15);
        bb[f] = *(const half8*)(pB + swz(row, kb));
      }
#pragma unroll
      for (int fm = 0; fm < 8; ++fm)
#pragma unroll
        for (int fn = 0; fn < 4; ++fn)
          acc[fm][fn] = __builtin_amdgcn_mfma_f32_16x16x32_f16(a[fm], bb[fn], acc[fm][fn], 0, 0, 0);
    }
  };

  load_B(0);
  dma_A(0, pAc);
  write_B(pBc);
  __syncthreads();

  for (int s = 0; s < 32; ++s) {
    if (s < 31) {
      load_B(s + 1);
      dma_A(s + 1, pAn);
    }
    compute_stage(pAc, pBc);
    if (s < 31) write_B(pBn);
    __syncthreads();
    char* t1 = pAc; pAc = pAn; pAn = t1;
    char* t2 = pBc; pBc = pBn; pBn = t2;
  }

#pragma unroll
  for (int fm = 0; fm < 8; ++fm)
#pragma unroll
    for (int fn = 0; fn < 4; ++fn)
#pragma unroll
      for (int q = 0; q < 4; ++q) {
        const int row = wm4 * 128 + fm * 16 + (l >> 4) * 4 + q;
        const int col = w0 + wn2 * 64 + fn * 16 + (l & 15);
        ctx[((size_t)b * 512 + row) * 1024 + col] = acc[fm][fn][q];
      }
}

// ---------------------------------------------------------------------------
// k_copy: ctx (ws) -> d_out, float4 grid-stride. (small-ws fallback only)
// ---------------------------------------------------------------------------
__global__ __launch_bounds__(256) void k_copy(const float4* __restrict__ src,
                                              float4* __restrict__ dst) {
  const int n4 = 16384 * 1024 / 4;
  int i = blockIdx.x * 256 + threadIdx.x;
  const int stride = gridDim.x * 256;
  for (; i < n4; i += stride) dst[i] = src[i];
}

// ===========================================================================
// FALLBACK PATH (round-2 verified kernels; used if ws too small)
// ===========================================================================
__global__ __launch_bounds__(256, 4) void k_proj(const float* __restrict__ A,
                                                 const float* __restrict__ W,
                                                 const float* __restrict__ bias,
                                                 float* __restrict__ out) {
  __shared__ float As[32][132];
  __shared__ float Bs[32][132];
  const int t = threadIdx.x;
  const int m0 = blockIdx.x * 128;
  const int n0 = blockIdx.y * 128;
  const int tm = t >> 4;
  const int tn = t & 15;
  const int lrow = t >> 1;
  const int lk = (t & 1) * 16;

  float acc[8][8];
#pragma unroll
  for (int i = 0; i < 8; ++i)
#pragma unroll
    for (int j = 0; j < 8; ++j) acc[i][j] = 0.0f;

  const float* Arow = A + (size_t)(m0 + lrow) * D_ + lk;
  const float* Wrow = W + (size_t)(n0 + lrow) * D_ + lk;

  for (int k0 = 0; k0 < D_; k0 += 32) {
    __syncthreads();
#pragma unroll
    for (int j = 0; j < 4; ++j) {
      const float4 va = *(const float4*)(Arow + k0 + j * 4);
      As[lk + j * 4 + 0][lrow] = va.x;
      As[lk + j * 4 + 1][lrow] = va.y;
      As[lk + j * 4 + 2][lrow] = va.z;
      As[lk + j * 4 + 3][lrow] = va.w;
      const float4 vb = *(const float4*)(Wrow + k0 + j * 4);
      Bs[lk + j * 4 + 0][lrow] = vb.x;
      Bs[lk + j * 4 + 1][lrow] = vb.y;
      Bs[lk + j * 4 + 2][lrow] = vb.z;
      Bs[lk + j * 4 + 3][lrow] = vb.w;
    }
    __syncthreads();
#pragma unroll 8
    for (int k = 0; k < 32; ++k) {
      float a[8], bb[8];
      *(float4*)(a + 0) = *(const float4*)&As[k][tm * 4];
      *(float4*)(a + 4) = *(const float4*)&As[k][tm * 4 + 64];
      *(float4*)(bb + 0) = *(const float4*)&Bs[k][tn * 4];
      *(float4*)(bb + 4) = *(const float4*)&Bs[k][tn * 4 + 64];
#pragma unroll
      for (int i = 0; i < 8; ++i)
#pragma unroll
        for (int j = 0; j < 8; ++j) acc[i][j] = fmaf(a[i], bb[j], acc[i][j]);
    }
  }

  float bn[8];
#pragma unroll
  for (int j = 0; j < 8; ++j) bn[j] = bias[n0 + tn * 4 + (j & 3) + (j >> 2) * 64];
#pragma unroll
  for (int i = 0; i < 8; ++i) {
    const int m = m0 + tm * 4 + (i & 3) + (i >> 2) * 64;
    float4 v0, v1;
    v0.x = tanhf(acc[i][0] + bn[0]);
    v0.y = tanhf(acc[i][1] + bn[1]);
    v0.z = tanhf(acc[i][2] + bn[2]);
    v0.w = tanhf(acc[i][3] + bn[3]);
    v1.x = tanhf(acc[i][4] + bn[4]);
    v1.y = tanhf(acc[i][5] + bn[5]);
    v1.z = tanhf(acc[i][6] + bn[6]);
    v1.w = tanhf(acc[i][7] + bn[7]);
    *(float4*)(out + (size_t)m * D_ + n0 + tn * 4) = v0;
    *(float4*)(out + (size_t)m * D_ + n0 + tn * 4 + 64) = v1;
  }
}

__global__ __launch_bounds__(256) void k_scores(const float* __restrict__ words,
                                                const void* __restrict__ mask,
                                                float* __restrict__ pa) {
  __shared__ float Pt[1024][18];
  __shared__ float Ws[64][268];
  const int t = threadIdx.x;
  const int b = blockIdx.x >> 5;
  const int et = blockIdx.x & 31;
  const int e0 = et * 16;
  const int eg = t >> 5;
  const int ng = t & 31;
  const int mask_is_int = g_mask_is_int;
  const float* wbase = words + (size_t)b * WN * D_;

  {
    const int row = t >> 4;
    const int dj = (t & 15) * 4;
    const float* pr = pa + (size_t)(b * E_ + e0 + row) * D_;
#pragma unroll
    for (int rr = 0; rr < 16; ++rr) {
      const float4 v = *(const float4*)(pr + dj + rr * 64);
      Pt[dj + rr * 64 + 0][row] = v.x;
      Pt[dj + rr * 64 + 1][row] = v.y;
      Pt[dj + rr * 64 + 2][row] = v.z;
      Pt[dj + rr * 64 + 3][row] = v.w;
    }
  }

  float s[2][64];
#pragma unroll
  for (int i = 0; i < 2; ++i)
#pragma unroll
    for (int u = 0; u < 64; ++u) s[i][u] = 0.0f;

  const int nl = t >> 3;
  const int d4 = (t & 7) * 4;

  for (int dk = 0; dk < D_; dk += 64) {
#pragma unroll
    for (int nb = 0; nb < 8; ++nb) {
      __syncthreads();
#pragma unroll
      for (int rr = 0; rr < 8; ++rr) {
#pragma unroll
        for (int hh = 0; hh < 2; ++hh) {
          const int n = nl + rr * 32;
          const int d = d4 + hh * 32;
          const float4 v = *(const float4*)(wbase + (size_t)(nb * 256 + n) * D_ + dk + d);
          Ws[d + 0][n] = v.x;
          Ws[d + 1][n] = v.y;
          Ws[d + 2][n] = v.z;
          Ws[d + 3][n] = v.w;
        }
      }
      __syncthreads();
#pragma unroll 2
      for (int k = 0; k < 64; ++k) {
        const float2 a = *(const float2*)&Pt[dk + k][eg * 2];
        const float4 b0 = *(const float4*)&Ws[k][ng * 4];
        const float4 b1 = *(const float4*)&Ws[k][128 + ng * 4];
        const float aa[2] = {a.x, a.y};
        const float bb[8] = {b0.x, b0.y, b0.z, b0.w, b1.x, b1.y, b1.z, b1.w};
#pragma unroll
        for (int i = 0; i < 2; ++i)
#pragma unroll
          for (int u = 0; u < 8; ++u)
            s[i][nb * 8 + u] = fmaf(aa[i], bb[u], s[i][nb * 8 + u]);
      }
    }
  }

#pragma unroll
  for (int i = 0; i < 2; ++i) {
    const int e = e0 + eg * 2 + i;
#pragma unroll
    for (int nb = 0; nb < 8; ++nb)
#pragma unroll
      for (int q = 0; q < 2; ++q) {
        const size_t moff = (size_t)(b * E_ + e) * WN + nb * 256 + q * 128 + ng * 4;
        int mx, my, mz, mw;
        if (mask_is_int) {
          const int4 mv = *(const int4*)((const int*)mask + moff);
          mx = mv.x; my = mv.y; mz = mv.z; mw = mv.w;
        } else {
          const uchar4 mv = *(const uchar4*)((const unsigned char*)mask + moff);
          mx = mv.x; my = mv.y; mz = mv.z; mw = mv.w;
        }
        if (mx) s[i][nb * 8 + q * 4 + 0] = -1e30f;
        if (my) s[i][nb * 8 + q * 4 + 1] = -1e30f;
        if (mz) s[i][nb * 8 + q * 4 + 2] = -1e30f;
        if (mw) s[i][nb * 8 + q * 4 + 3] = -1e30f;
      }
    float m = -1e30f;
#pragma unroll
    for (int u = 0; u < 64; ++u) m = fmaxf(m, s[i][u]);
#pragma unroll
    for (int off = 16; off > 0; off >>= 1) m = fmaxf(m, __shfl_xor(m, off));
    float sum = 0.0f;
#pragma unroll
    for (int u = 0; u < 64; ++u) {
      const float p = __expf(s[i][u] - m);
      s[i][u] = p;
      sum += p;
    }
#pragma unroll
    for (int off = 16; off > 0; off >>= 1) sum += __shfl_xor(sum, off);
    const float rinv = 1.0f / sum;

    unsigned short* ar2 = (unsigned short*)(pa + (size_t)(b * E_ + e) * WN / 2);
#pragma unroll
    for (int nb = 0; nb < 8; ++nb)
#pragma unroll
      for (int q = 0; q < 2; ++q) {
        ushort4 pk;
        pk.x = f2bf(s[i][nb * 8 + q * 4 + 0] * rinv);
        pk.y = f2bf(s[i][nb * 8 + q * 4 + 1] * rinv);
        pk.z = f2bf(s[i][nb * 8 + q * 4 + 2] * rinv);
        pk.w = f2bf(s[i][nb * 8 + q * 4 + 3] * rinv);
        *(ushort4*)(ar2 + nb * 256 + q * 128 + ng * 4) = pk;
      }
  }
}

__global__ __launch_bounds__(256) void k_ctx(const float* __restrict__ words,
                                             float* __restrict__ pa) {
  __shared__ unsigned short att_s[16][2048];
  __shared__ unsigned short Wb[256][132];
  const int t = threadIdx.x;
  const int b = blockIdx.x >> 5;
  const int et = blockIdx.x & 31;
  const int e0 = et * 16;
  const int eg = t >> 5;
  const int wg = t & 31;
  const float* wbase = words + (size_t)b * WN * D_;

  {
    const int row = t >> 4;
    const int cj = t & 15;
    const uint4* pr = (const uint4*)(pa + (size_t)(b * E_ + e0 + row) * D_);
#pragma unroll
    for (int rr = 0; rr < 16; ++rr) {
      const int c = cj + rr * 16;
      const uint4 v = pr[c];
      *(uint4*)&att_s[row][c * 8] = v;
    }
  }

  float acc[2][32];
#pragma unroll
  for (int i = 0; i < 2; ++i)
#pragma unroll
    for (int u = 0; u < 32; ++u) acc[i][u] = 0.0f;

  const int nlg = t >> 5;
  const int w4 = (t & 31) * 4;

  for (int nb = 0; nb < 8; ++nb) {
#pragma unroll
    for (int q = 0; q < 8; ++q) {
      __syncthreads();
#pragma unroll
      for (int rr = 0; rr < 32; ++rr) {
        const int n = nlg + rr * 8;
        const float4 v = *(const float4*)(wbase + (size_t)(nb * 256 + n) * D_ + q * 128 + w4);
        ushort4 pk;
        pk.x = f2bf(v.x);
        pk.y = f2bf(v.y);
        pk.z = f2bf(v.z);
        pk.w = f2bf(v.w);
        *(ushort4*)&Wb[n][w4] = pk;
      }
      __syncthreads();
#pragma unroll 4
      for (int n2 = 0; n2 < 128; ++n2) {
        const int n = n2 * 2;
        const ushort4 r0 = *(const ushort4*)&Wb[n][wg * 4];
        const ushort4 r1 = *(const ushort4*)&Wb[n + 1][wg * 4];
        const float w0[4] = {bf2f(r0.x), bf2f(r0.y), bf2f(r0.z), bf2f(r0.w)};
        const float w1[4] = {bf2f(r1.x), bf2f(r1.y), bf2f(r1.z), bf2f(r1.w)};
#pragma unroll
        for (int i = 0; i < 2; ++i) {
          const unsigned int aw = *(const unsigned int*)&att_s[eg * 2 + i][nb * 256 + n];
          const float a0 = bf2f((unsigned short)(aw & 0xffffu));
          const float a1 = bf2f((unsigned short)(aw >> 16));
#pragma unroll
          for (int j = 0; j < 4; ++j)
            acc[i][q * 4 + j] = fmaf(a0, w0[j], fmaf(a1, w1[j], acc[i][q * 4 + j]));
        }
      }
    }
  }

#pragma unroll
  for (int i = 0; i < 2; ++i) {
    float* orow = pa + (size_t)(b * E_ + e0 + eg * 2 + i) * D_;
#pragma unroll
    for (int q = 0; q < 8; ++q) {
      float4 v;
      v.x = acc[i][q * 4 + 0];
      v.y = acc[i][q * 4 + 1];
      v.z = acc[i][q * 4 + 2];
      v.w = acc[i][q * 4 + 3];
      *(float4*)(orow + q * 128 + wg * 4) = v;
    }
  }
}

extern "C" void kernel_launch(void* const* d_in, const int* in_sizes, int n_in,
                              void* d_out, int out_size, void* d_ws, size_t ws_size,
                              hipStream_t stream) {
  const float* ems = (const float*)d_in[0];
  const float* words = (const float*)d_in[1];
  const void* mask = d_in[2];
  const float* w_weight = (const float*)d_in[3];
  const float* w_bias = (const float*)d_in[4];

  k_detect<<<1, 64, 0, stream>>>((const unsigned char*)mask);

  const size_t ws_need = (size_t)16384 * 2048 * 4;          // 128 MB budget
  const size_t ws_big = ws_need + (size_t)32 * 2097152;     // +64 MB blob
  if (ws_size >= ws_need) {
    unsigned short* pF = (unsigned short*)d_out;    // 32MB f16 proj blob
    unsigned short* scH = (unsigned short*)d_ws;    // 64MB f16 scores
    unsigned short* eF = (unsigned short*)((char*)d_ws + (size_t)67108864);  // 32MB
    unsigned short* wF = eF + (size_t)16384 * 1024;                          // 2MB
    // 0. convert ems (128 tiles) and W (8 tiles) into f16 swizzled blobs
    //    (placed at ws+64MB so the f16 score write below won't touch them;
    //     they are dead after proj anyway)
    k_split_h<<<dim3(2048), 256, 0, stream>>>(ems, eF);
    k_split_h<<<dim3(128), 256, 0, stream>>>(w_weight, wF);
    // 1. proj (single f16 MFMA, XCD-pinned, 64KB LDS) -> f16 blob in d_out
    k_proj_dma<<<dim3(1024), 512, 0, stream>>>(eF, wF, w_bias, pF);
    // 2. scores (single f16 MFMA) -> f16 scores in ws[0..64MB)
    k_scores_mfma<<<dim3(512), 512, 0, stream>>>(pF, words, scH);
    if (ws_size >= ws_big) {
      // big-ws path: att blob in ws; ctx -> d_out direct
      unsigned short* blob = (unsigned short*)((char*)d_ws + ws_need);
      k_softmax<<<dim3(16384), 256, 0, stream>>>(scH, mask, blob);
      k_pv<<<dim3(256), 512, 0, stream>>>(blob, words, (float*)d_out);
    } else {
      // small-ws path: blob in d_out (proj blob dead), ctx -> ws, copy out
      k_softmax<<<dim3(16384), 256, 0, stream>>>(scH, mask, (unsigned short*)d_out);
      k_pv<<<dim3(256), 512, 0, stream>>>((const unsigned short*)d_out, words,
                                          (float*)((char*)d_ws + 67108864));
      k_copy<<<dim3(2048), 256, 0, stream>>>(
          (const float4*)((char*)d_ws + 67108864), (float4*)d_out);
    }
  } else {
    float* out = (float*)d_out;
    k_proj<<<dim3(128, 8), 256, 0, stream>>>(ems, w_weight, w_bias, out);
    k_scores<<<dim3(B_ * (E_ / 16)), 256, 0, stream>>>(words, mask, out);
    k_ctx<<<dim3(B_ * (E_ / 16)), 256, 0, stream>>>(words, out);
  }
}